// Round 10
// baseline (1448.449 us; speedup 1.0000x reference)
//
#include <hip/hip_runtime.h>

#define B_   32
#define N_   716
#define T_   168
#define L_   64
#define NT_  884     // N + T
#define NTP  896     // padded NT for bf16 tiles
#define TE3_ 192     // 3*L
#define TRH_ 716     // tr hidden
#define TR3_ 2148    // 3*TRH
#define TR3P 2176    // padded
#define WSTR 744     // padded bf16 row stride in LDS
#define HSTR 720     // padded bf16 row stride of global h buffers
#define TRBLKS 90    // 45 k-slices x 2 batch halves

typedef unsigned short u16;
typedef unsigned long long u64;
typedef __attribute__((ext_vector_type(8))) short short8;
typedef __attribute__((ext_vector_type(4))) float f32x4;

static __device__ __forceinline__ float eluf(float x){ return x > 0.f ? x : expm1f(x); }
static __device__ __forceinline__ float sigf(float x){ return 1.f/(1.f+expf(-x)); }
static __device__ __forceinline__ u16 f2bf(float f){
  unsigned u = __float_as_uint(f);
  unsigned r = (u + 0x7fffu + ((u >> 16) & 1u)) >> 16;
  return (u16)r;
}
static __device__ __forceinline__ float bf2f(u16 h){
  return __uint_as_float(((unsigned)h) << 16);
}
static __device__ __forceinline__ f32x4 bmfma(short8 a, short8 b, f32x4 c){
  return __builtin_amdgcn_mfma_f32_16x16x32_bf16(a, b, c, 0, 0, 0);
}

// ---------------- weight conversions ----------------
__global__ __launch_bounds__(256) void k_whhbf(const float* __restrict__ in, u16* __restrict__ out, int n4){
  int i = blockIdx.x*256 + threadIdx.x;
  if (i >= n4) return;
  f32x4 v = *(const f32x4*)(in + (size_t)i*4);
  uint2 p;
  p.x = (unsigned)f2bf(v[0]) | ((unsigned)f2bf(v[1])<<16);
  p.y = (unsigned)f2bf(v[2]) | ((unsigned)f2bf(v[3])<<16);
  *(uint2*)(out + (size_t)i*4) = p;
}
__global__ __launch_bounds__(256) void k_wihbf(const float* __restrict__ Wih, u16* __restrict__ WihB){
  int idx = blockIdx.x*256 + threadIdx.x;
  if (idx >= TR3P*L_) return;
  int r = idx >> 6;
  WihB[idx] = (r < TR3_) ? f2bf(Wih[idx]) : (u16)0;
}
// gcn W -> transposed bf16 hi/lo: WT[g][f] = W[f][g]
__global__ __launch_bounds__(256) void k_wtb(const float* __restrict__ W,
                                             u16* __restrict__ WTh, u16* __restrict__ WTl){
  int l = blockIdx.x;
  for (int e = threadIdx.x; e < 4096; e += 256){
    int g = e >> 6, f = e & 63;
    float v = W[(size_t)l*4096 + f*64 + g];
    u16 hi = f2bf(v);
    WTh[(size_t)l*4096 + e] = hi;
    WTl[(size_t)l*4096 + e] = f2bf(v - bf2f(hi));
  }
}
// se weights: W1T (64x224) and W2T (64x64), hi/lo
__global__ __launch_bounds__(256) void k_sew(const float* __restrict__ W1, const float* __restrict__ W2,
    u16* __restrict__ w1h, u16* __restrict__ w1l, u16* __restrict__ w2h, u16* __restrict__ w2l){
  int tid = threadIdx.x;
  for (int e = tid; e < 64*224; e += 256){
    int g = e / 224, k = e % 224;
    float v = (k < 200) ? W1[k*64 + g] : 0.f;
    u16 hi = f2bf(v); w1h[e] = hi; w1l[e] = f2bf(v - bf2f(hi));
  }
  for (int e = tid; e < 4096; e += 256){
    int g = e >> 6, f = e & 63;
    float v = W2[f*64 + g];
    u16 hi = f2bf(v); w2h[e] = hi; w2l[e] = f2bf(v - bf2f(hi));
  }
}
// fr weights: W1T (176x64), W2cols (16x192), hi/lo
__global__ __launch_bounds__(256) void k_frw(const float* __restrict__ W1, const float* __restrict__ W2,
    u16* __restrict__ w1h, u16* __restrict__ w1l, u16* __restrict__ w2h, u16* __restrict__ w2l){
  int tid = threadIdx.x;
  for (int e = tid; e < 176*64; e += 256){
    int n = e >> 6, k = e & 63;
    float v = (n < 168) ? W1[k*168 + n] : 0.f;
    u16 hi = f2bf(v); w1h[e] = hi; w1l[e] = f2bf(v - bf2f(hi));
  }
  for (int e = tid; e < 16*192; e += 256){
    int c = e / 192, k = e % 192;
    float v = (c < 8 && k < 168) ? W2[k*168 + 160 + c] : 0.f;
    u16 hi = f2bf(v); w2h[e] = hi; w2l[e] = f2bf(v - bf2f(hi));
  }
}
// te Wih (192x752) -> hi/lo padded (192x768)
__global__ __launch_bounds__(256) void k_wte(const float* __restrict__ W, u16* __restrict__ wh, u16* __restrict__ wl){
  int idx = blockIdx.x*256 + threadIdx.x;
  if (idx >= 192*768) return;
  int g = idx / 768, k = idx % 768;
  float v = (k < 752) ? W[(size_t)g*752 + k] : 0.f;
  u16 hi = f2bf(v); wh[idx] = hi; wl[idx] = f2bf(v - bf2f(hi));
}

// ---------------- se MFMA (fused se_in build): X[:, :716, :] = elu(se_in@W1+b1)@W2+b2 ----------------
__global__ __launch_bounds__(256) void k_sem(const float* __restrict__ x, const float* __restrict__ se_emb,
    const u16* __restrict__ w1h, const u16* __restrict__ w1l,
    const u16* __restrict__ w2h, const u16* __restrict__ w2l,
    const float* __restrict__ b1, const float* __restrict__ b2, float* __restrict__ X){
  __shared__ u16 Sh[64*232], Sl[64*232];
  __shared__ u16 Tlh[64*72], Tll[64*72];
  int m0 = blockIdx.x*64;
  int tid = threadIdx.x, wv = tid >> 6, lane = tid & 63;
  // stage se_in rows (hi/lo) into LDS; cols 224, padded stride 232
  for (int o = tid; o < 64*224; o += 256){
    int r = o / 224, k = o - (o/224)*224;
    int m = m0 + r; int b = m / N_, n = m - b*N_;
    float v = 0.f;
    if (k < 168) v = x[((size_t)b*N_ + n)*T_ + k];
    else if (k < 200) v = se_emb[n*32 + (k - 168)];
    u16 hi = f2bf(v);
    Sh[r*232 + k] = hi; Sl[r*232 + k] = f2bf(v - bf2f(hi));
  }
  __syncthreads();
  const u16* Ah = Sh + (16*wv + (lane & 15))*232 + (lane >> 4)*8;
  const u16* Al = Sl + (16*wv + (lane & 15))*232 + (lane >> 4)*8;
  const u16* Bh = w1h + (lane & 15)*224 + (lane >> 4)*8;
  const u16* Bl = w1l + (lane & 15)*224 + (lane >> 4)*8;
  f32x4 hh[4], hl[4], lh[4];
  #pragma unroll
  for (int q = 0; q < 4; ++q){ hh[q]=(f32x4){0,0,0,0}; hl[q]=(f32x4){0,0,0,0}; lh[q]=(f32x4){0,0,0,0}; }
  #pragma unroll
  for (int kt = 0; kt < 7; ++kt){
    short8 ah = *(const short8*)(Ah + kt*32);
    short8 al = *(const short8*)(Al + kt*32);
    #pragma unroll
    for (int q = 0; q < 4; ++q){
      short8 bh = *(const short8*)(Bh + q*16*224 + kt*32);
      short8 bl = *(const short8*)(Bl + q*16*224 + kt*32);
      hh[q] = bmfma(ah, bh, hh[q]);
      hl[q] = bmfma(ah, bl, hl[q]);
      lh[q] = bmfma(al, bh, lh[q]);
    }
  }
  int mrow = 16*wv + (lane >> 4)*4;
  #pragma unroll
  for (int q = 0; q < 4; ++q){
    int g = q*16 + (lane & 15);
    float bv = b1[g];
    #pragma unroll
    for (int r = 0; r < 4; ++r){
      float v = eluf(hh[q][r] + hl[q][r] + lh[q][r] + bv);
      u16 hi = f2bf(v);
      Tlh[(mrow + r)*72 + g] = hi;
      Tll[(mrow + r)*72 + g] = f2bf(v - bf2f(hi));
    }
  }
  __syncthreads();
  const u16* A2h = Tlh + (16*wv + (lane & 15))*72 + (lane >> 4)*8;
  const u16* A2l = Tll + (16*wv + (lane & 15))*72 + (lane >> 4)*8;
  const u16* B2h = w2h + (lane & 15)*64 + (lane >> 4)*8;
  const u16* B2l = w2l + (lane & 15)*64 + (lane >> 4)*8;
  f32x4 ohh[4], ohl[4], olh[4];
  #pragma unroll
  for (int q = 0; q < 4; ++q){ ohh[q]=(f32x4){0,0,0,0}; ohl[q]=(f32x4){0,0,0,0}; olh[q]=(f32x4){0,0,0,0}; }
  #pragma unroll
  for (int kt = 0; kt < 2; ++kt){
    short8 a2h = *(const short8*)(A2h + kt*32);
    short8 a2l = *(const short8*)(A2l + kt*32);
    #pragma unroll
    for (int q = 0; q < 4; ++q){
      short8 b2h = *(const short8*)(B2h + q*16*64 + kt*32);
      short8 b2l = *(const short8*)(B2l + q*16*64 + kt*32);
      ohh[q] = bmfma(a2h, b2h, ohh[q]);
      ohl[q] = bmfma(a2h, b2l, ohl[q]);
      olh[q] = bmfma(a2l, b2h, olh[q]);
    }
  }
  #pragma unroll
  for (int q = 0; q < 4; ++q){
    int g = q*16 + (lane & 15);
    float bv = b2[g];
    #pragma unroll
    for (int r = 0; r < 4; ++r){
      int m = m0 + mrow + r;
      int b = m / N_, n = m - b*N_;
      X[((size_t)b*NT_ + n)*L_ + g] = ohh[q][r] + ohl[q][r] + olh[q][r] + bv;
    }
  }
}

// ---------------- te_in build (hi/lo, 5376 x 768) ----------------
__global__ __launch_bounds__(256) void k_teinx_b(const float* __restrict__ x,
                                                 u16* __restrict__ th_, u16* __restrict__ tl_){
  __shared__ float tile[32][33];
  int b = blockIdx.z; int n0 = blockIdx.x*32, t0 = blockIdx.y*32;
  int tx = threadIdx.x & 31, ty = threadIdx.x >> 5;
  for (int i = ty; i < 32; i += 8){
    int n = n0 + i, t = t0 + tx;
    if (n < N_ && t < T_) tile[i][tx] = x[((size_t)b*N_ + n)*T_ + t];
  }
  __syncthreads();
  for (int i = ty; i < 32; i += 8){
    int t = t0 + i, n = n0 + tx;
    if (t < T_ && n < N_){
      float v = tile[tx][i];
      u16 hi = f2bf(v);
      size_t o = ((size_t)b*T_ + t)*768 + n;
      th_[o] = hi; tl_[o] = f2bf(v - bf2f(hi));
    }
  }
}
__global__ __launch_bounds__(256) void k_teinr_b(const float* __restrict__ mark, const float* __restrict__ te_emb,
                                                 u16* __restrict__ th_, u16* __restrict__ tl_){
  int idx = blockIdx.x*256 + threadIdx.x;
  if (idx >= B_*T_*52) return;
  int c = idx % 52; int row = idx / 52; int b = row / T_, t = row % T_;
  float v = 0.f;
  if (c < 4) v = mark[((size_t)b*T_ + t)*4 + c];
  else if (c < 36) v = te_emb[t*32 + (c - 4)];
  u16 hi = f2bf(v);
  size_t o = (size_t)row*768 + 716 + c;
  th_[o] = hi; tl_[o] = f2bf(v - bf2f(hi));
}

// ---------------- te xw MFMA: te_xw = te_in @ te_Wih^T + bih ----------------
__global__ __launch_bounds__(256) void k_texw(const u16* __restrict__ teh, const u16* __restrict__ tel,
    const u16* __restrict__ wh, const u16* __restrict__ wl,
    const float* __restrict__ bih, float* __restrict__ xwte){
  int m0 = blockIdx.x*64, n0 = blockIdx.y*64;
  int tid = threadIdx.x, wv = tid >> 6, lane = tid & 63;
  const u16* Ah = teh + (size_t)(m0 + 16*wv + (lane & 15))*768 + (lane >> 4)*8;
  const u16* Al = tel + (size_t)(m0 + 16*wv + (lane & 15))*768 + (lane >> 4)*8;
  const u16* Bh = wh + (size_t)(n0 + (lane & 15))*768 + (lane >> 4)*8;
  const u16* Bl = wl + (size_t)(n0 + (lane & 15))*768 + (lane >> 4)*8;
  f32x4 hh[4], hl[4], lh[4];
  #pragma unroll
  for (int q = 0; q < 4; ++q){ hh[q]=(f32x4){0,0,0,0}; hl[q]=(f32x4){0,0,0,0}; lh[q]=(f32x4){0,0,0,0}; }
  #pragma unroll 4
  for (int kt = 0; kt < 24; ++kt){
    short8 ah = *(const short8*)(Ah + kt*32);
    short8 al = *(const short8*)(Al + kt*32);
    #pragma unroll
    for (int q = 0; q < 4; ++q){
      short8 bh = *(const short8*)(Bh + q*16*768 + kt*32);
      short8 bl = *(const short8*)(Bl + q*16*768 + kt*32);
      hh[q] = bmfma(ah, bh, hh[q]);
      hl[q] = bmfma(ah, bl, hl[q]);
      lh[q] = bmfma(al, bh, lh[q]);
    }
  }
  int mb = m0 + 16*wv + (lane >> 4)*4;
  #pragma unroll
  for (int q = 0; q < 4; ++q){
    int g = n0 + q*16 + (lane & 15);
    float bv = bih[g];
    #pragma unroll
    for (int r = 0; r < 4; ++r)
      xwte[(size_t)(mb + r)*TE3_ + g] = hh[q][r] + hl[q][r] + lh[q][r] + bv;
  }
}

// ---------------- te GRU scan (ILP-split inner product) ----------------
__global__ __launch_bounds__(192) void k_te_scan(const float* __restrict__ xw, const float* __restrict__ Whh,
                 const float* __restrict__ bhh, float* __restrict__ X){
  int b = blockIdx.x; int tid = threadIdx.x;
  __shared__ float Wsh[TE3_*65];
  __shared__ float hs[64];
  __shared__ float gh[TE3_];
  for (int l = tid; l < TE3_*64; l += 192){ int j = l >> 6, f = l & 63; Wsh[j*65+f] = Whh[l]; }
  if (tid < 64) hs[tid] = 0.f;
  __syncthreads();
  for (int t = 0; t < T_; ++t){
    const float* xr = xw + ((size_t)b*T_ + t)*TE3_;
    float g0 = bhh[tid], g1 = 0.f, g2 = 0.f, g3 = 0.f;
    #pragma unroll
    for (int f = 0; f < 64; f += 4){
      g0 = fmaf(hs[f],   Wsh[tid*65+f],   g0);
      g1 = fmaf(hs[f+1], Wsh[tid*65+f+1], g1);
      g2 = fmaf(hs[f+2], Wsh[tid*65+f+2], g2);
      g3 = fmaf(hs[f+3], Wsh[tid*65+f+3], g3);
    }
    gh[tid] = (g0 + g1) + (g2 + g3);
    __syncthreads();
    if (tid < 64){
      float r = sigf(xr[tid] + gh[tid]);
      float z = sigf(xr[64+tid] + gh[64+tid]);
      float n = tanhf(xr[128+tid] + r*gh[128+tid]);
      float hn = (1.f - z)*n + z*hs[tid];
      hs[tid] = hn;
      X[((size_t)b*NT_ + N_ + t)*L_ + tid] = hn;
    }
    __syncthreads();
  }
}

// ---------------- X -> bf16 hi/lo (row-major + optional transposed) ----------------
__global__ __launch_bounds__(256) void k_xbf(const float* __restrict__ X,
                 u16* __restrict__ Xbh, u16* __restrict__ Xbl,
                 u16* __restrict__ XTh, u16* __restrict__ XTl){
  __shared__ u16 th[32][33], tl[32][33];
  int b = blockIdx.z, i0 = blockIdx.x*32, f0 = blockIdx.y*32;
  int tx = threadIdx.x & 31, ty = threadIdx.x >> 5;
  for (int rr = ty; rr < 32; rr += 8){
    int i = i0 + rr, f = f0 + tx;
    float v = (i < NT_) ? X[((size_t)b*NT_ + i)*L_ + f] : 0.f;
    u16 hi = f2bf(v);
    u16 lo = f2bf(v - bf2f(hi));
    th[rr][tx] = hi; tl[rr][tx] = lo;
    Xbh[((size_t)b*NTP + i)*L_ + f] = hi;
    Xbl[((size_t)b*NTP + i)*L_ + f] = lo;
  }
  if (!XTh) return;
  __syncthreads();
  for (int rr = ty; rr < 32; rr += 8){
    XTh[((size_t)b*L_ + f0 + rr)*NTP + i0 + tx] = th[tx][rr];
    XTl[((size_t)b*L_ + f0 + rr)*NTP + i0 + tx] = tl[tx][rr];
  }
}

// ---------------- fused flash-GCN layer: Y = elu((adj@h)@W + b), adj computed in LDS ----------------
// adj band (64 x 896) computed chunk-by-chunk (64x64) from Xb and consumed immediately.
__global__ __launch_bounds__(256) void k_gcnf(
    const u16* __restrict__ Xbh, const u16* __restrict__ Xbl,   // adjacency operands (B,NTP,64)
    const u16* __restrict__ hTh, const u16* __restrict__ hTl,   // stage1 B (B,64,NTP)
    const u16* __restrict__ WTh, const u16* __restrict__ WTl,
    const float* __restrict__ bias,
    float* __restrict__ Y, u16* __restrict__ YTh, u16* __restrict__ YTl){
  __shared__ u16 AJh[64*72], AJl[64*72];
  __shared__ u16 Tlh[64*72], Tll[64*72];
  int b = blockIdx.y, i0 = blockIdx.x*64;
  int tid = threadIdx.x, wv = tid >> 6, lane = tid & 63;
  const u16* XAh = Xbh + ((size_t)b*NTP + i0 + 16*wv + (lane & 15))*L_ + (lane >> 4)*8;
  const u16* XAl = Xbl + ((size_t)b*NTP + i0 + 16*wv + (lane & 15))*L_ + (lane >> 4)*8;
  const int ib = i0 + 16*wv + (lane >> 4)*4;
  const int mrow = 16*wv + (lane >> 4)*4;
  f32x4 thh[4], thl[4], tlh[4];
  #pragma unroll
  for (int q = 0; q < 4; ++q){ thh[q] = (f32x4){0,0,0,0}; thl[q] = (f32x4){0,0,0,0}; tlh[q] = (f32x4){0,0,0,0}; }
  for (int jt = 0; jt < 14; ++jt){
    int j0 = jt*64;
    // --- adjacency chunk: rows i0..i0+63, cols j0..j0+63 (k_adjb core) ---
    {
      const u16* XBh = Xbh + ((size_t)b*NTP + j0 + (lane & 15))*L_ + (lane >> 4)*8;
      const u16* XBl = Xbl + ((size_t)b*NTP + j0 + (lane & 15))*L_ + (lane >> 4)*8;
      f32x4 chh[4], chl[4], clh[4];
      #pragma unroll
      for (int q = 0; q < 4; ++q){ chh[q] = (f32x4){0,0,0,0}; chl[q] = (f32x4){0,0,0,0}; clh[q] = (f32x4){0,0,0,0}; }
      #pragma unroll
      for (int kt = 0; kt < 2; ++kt){
        short8 ah = *(const short8*)(XAh + kt*32);
        short8 al = *(const short8*)(XAl + kt*32);
        #pragma unroll
        for (int q = 0; q < 4; ++q){
          short8 bh = *(const short8*)(XBh + q*16*L_ + kt*32);
          short8 bl = *(const short8*)(XBl + q*16*L_ + kt*32);
          chh[q] = bmfma(ah, bh, chh[q]);
          chl[q] = bmfma(ah, bl, chl[q]);
          clh[q] = bmfma(al, bh, clh[q]);
        }
      }
      int jb = j0 + (lane & 15);
      #pragma unroll
      for (int q = 0; q < 4; ++q){
        int j = jb + q*16;
        #pragma unroll
        for (int r = 0; r < 4; ++r){
          int i = ib + r;
          u16 hi = 0, lo = 0;
          if (i < NT_ && j < NT_){
            float v = tanhf(fmaxf(chh[q][r] + chl[q][r] + clh[q][r], 0.f) + (i == j ? 1.f : 0.f));
            hi = f2bf(v); lo = f2bf(v - bf2f(hi));
          }
          AJh[(mrow + r)*72 + q*16 + (lane & 15)] = hi;
          AJl[(mrow + r)*72 + q*16 + (lane & 15)] = lo;
        }
      }
    }
    __syncthreads();
    // --- stage1 partial: T += adj_chunk @ h[j-chunk] ---
    {
      const u16* A1h = AJh + (16*wv + (lane & 15))*72 + (lane >> 4)*8;
      const u16* A1l = AJl + (16*wv + (lane & 15))*72 + (lane >> 4)*8;
      const u16* B1h = hTh + ((size_t)b*L_ + (lane & 15))*NTP + j0 + (lane >> 4)*8;
      const u16* B1l = hTl + ((size_t)b*L_ + (lane & 15))*NTP + j0 + (lane >> 4)*8;
      #pragma unroll
      for (int kt = 0; kt < 2; ++kt){
        short8 ah = *(const short8*)(A1h + kt*32);
        short8 al = *(const short8*)(A1l + kt*32);
        #pragma unroll
        for (int q = 0; q < 4; ++q){
          short8 bh = *(const short8*)(B1h + q*16*NTP + kt*32);
          short8 bl = *(const short8*)(B1l + q*16*NTP + kt*32);
          thh[q] = bmfma(ah, bh, thh[q]);
          thl[q] = bmfma(ah, bl, thl[q]);
          tlh[q] = bmfma(al, bh, tlh[q]);
        }
      }
    }
    __syncthreads();   // AJ consumed; safe to overwrite next chunk
  }
  // --- T -> LDS hi/lo ---
  #pragma unroll
  for (int q = 0; q < 4; ++q)
    #pragma unroll
    for (int r = 0; r < 4; ++r){
      float v = thh[q][r] + thl[q][r] + tlh[q][r];
      u16 hi = f2bf(v);
      Tlh[(mrow + r)*72 + q*16 + (lane & 15)] = hi;
      Tll[(mrow + r)*72 + q*16 + (lane & 15)] = f2bf(v - bf2f(hi));
    }
  __syncthreads();
  // --- stage2: D = T @ W^T ---
  const u16* A2h = Tlh + (16*wv + (lane & 15))*72 + (lane >> 4)*8;
  const u16* A2l = Tll + (16*wv + (lane & 15))*72 + (lane >> 4)*8;
  const u16* B2h = WTh + (lane & 15)*L_ + (lane >> 4)*8;
  const u16* B2l = WTl + (lane & 15)*L_ + (lane >> 4)*8;
  f32x4 ohh[4], ohl[4], olh[4];
  #pragma unroll
  for (int q = 0; q < 4; ++q){ ohh[q] = (f32x4){0,0,0,0}; ohl[q] = (f32x4){0,0,0,0}; olh[q] = (f32x4){0,0,0,0}; }
  #pragma unroll
  for (int kt = 0; kt < 2; ++kt){
    short8 a2h = *(const short8*)(A2h + kt*32);
    short8 a2l = *(const short8*)(A2l + kt*32);
    #pragma unroll
    for (int q = 0; q < 4; ++q){
      short8 b2h = *(const short8*)(B2h + q*16*L_ + kt*32);
      short8 b2l = *(const short8*)(B2l + q*16*L_ + kt*32);
      ohh[q] = bmfma(a2h, b2h, ohh[q]);
      ohl[q] = bmfma(a2h, b2l, ohl[q]);
      olh[q] = bmfma(a2l, b2h, olh[q]);
    }
  }
  __syncthreads();
  #pragma unroll
  for (int q = 0; q < 4; ++q){
    int g = q*16 + (lane & 15);
    float bv = bias[g];
    #pragma unroll
    for (int r = 0; r < 4; ++r){
      int i = i0 + mrow + r;
      float v = eluf(ohh[q][r] + ohl[q][r] + olh[q][r] + bv);
      if (i < NT_ && Y) Y[((size_t)b*NT_ + i)*L_ + g] = v;
      u16 hi = 0, lo = 0;
      if (i < NT_){ hi = f2bf(v); lo = f2bf(v - bf2f(hi)); }
      Tlh[g*72 + mrow + r] = hi;
      Tll[g*72 + mrow + r] = lo;
    }
  }
  __syncthreads();
  {
    int g = tid >> 2, c = tid & 3;
    uint4* dh = (uint4*)(YTh + ((size_t)b*L_ + g)*NTP + i0 + c*16);
    uint4* dl = (uint4*)(YTl + ((size_t)b*L_ + g)*NTP + i0 + c*16);
    const uint4* sh = (const uint4*)(Tlh + g*72 + c*16);
    const uint4* sl = (const uint4*)(Tll + g*72 + c*16);
    dh[0] = sh[0]; dh[1] = sh[1];
    dl[0] = sl[0]; dl[1] = sl[1];
  }
}

// ---------------- fr MFMA: nout8 = (elu(Xs@W1+b1)@W2+b2)[:,160:168] ----------------
__global__ __launch_bounds__(256) void k_frm(const u16* __restrict__ Xbh, const u16* __restrict__ Xbl,
    const u16* __restrict__ w1h, const u16* __restrict__ w1l,
    const u16* __restrict__ w2h, const u16* __restrict__ w2l,
    const float* __restrict__ b1, const float* __restrict__ b2, float* __restrict__ nout8){
  __shared__ u16 T1h[64*192], T1l[64*192];
  __shared__ u16 B2hl[16*192], B2ll[16*192];
  int m0 = blockIdx.x*64;
  int tid = threadIdx.x, wv = tid >> 6, lane = tid & 63;
  for (int o = tid; o < 768; o += 256){
    ((u64*)B2hl)[o] = ((const u64*)w2h)[o];
    ((u64*)B2ll)[o] = ((const u64*)w2l)[o];
  }
  for (int o = tid; o < 1024; o += 256){
    int rr = o >> 4, cc = o & 15;
    T1h[rr*192 + 176 + cc] = 0; T1l[rr*192 + 176 + cc] = 0;
  }
  int ar = m0 + 16*wv + (lane & 15);
  int ab = ar / N_, an = ar - ab*N_;
  const u16* Ah = Xbh + ((size_t)ab*NTP + an)*L_ + (lane >> 4)*8;
  const u16* Al = Xbl + ((size_t)ab*NTP + an)*L_ + (lane >> 4)*8;
  int mrow = 16*wv + (lane >> 4)*4;
  for (int tile = 0; tile < 11; ++tile){
    const u16* Bh = w1h + (tile*16 + (lane & 15))*64 + (lane >> 4)*8;
    const u16* Bl = w1l + (tile*16 + (lane & 15))*64 + (lane >> 4)*8;
    f32x4 shh={0,0,0,0}, shl={0,0,0,0}, slh={0,0,0,0};
    #pragma unroll
    for (int kt = 0; kt < 2; ++kt){
      short8 ah = *(const short8*)(Ah + kt*32);
      short8 al = *(const short8*)(Al + kt*32);
      short8 bh = *(const short8*)(Bh + kt*32);
      short8 bl = *(const short8*)(Bl + kt*32);
      shh = bmfma(ah, bh, shh);
      shl = bmfma(ah, bl, shl);
      slh = bmfma(al, bh, slh);
    }
    int col = tile*16 + (lane & 15);
    float bb = (col < 168) ? b1[col] : 0.f;
    #pragma unroll
    for (int r = 0; r < 4; ++r){
      float v = (col < 168) ? eluf(shh[r] + shl[r] + slh[r] + bb) : 0.f;
      u16 hi = f2bf(v);
      T1h[(mrow + r)*192 + col] = hi;
      T1l[(mrow + r)*192 + col] = f2bf(v - bf2f(hi));
    }
  }
  __syncthreads();
  const u16* A2h = T1h + (16*wv + (lane & 15))*192 + (lane >> 4)*8;
  const u16* A2l = T1l + (16*wv + (lane & 15))*192 + (lane >> 4)*8;
  const u16* Bh2 = B2hl + (lane & 15)*192 + (lane >> 4)*8;
  const u16* Bl2 = B2ll + (lane & 15)*192 + (lane >> 4)*8;
  f32x4 ohh={0,0,0,0}, ohl={0,0,0,0}, olh={0,0,0,0};
  #pragma unroll
  for (int kt = 0; kt < 6; ++kt){
    short8 a2h = *(const short8*)(A2h + kt*32);
    short8 a2l = *(const short8*)(A2l + kt*32);
    short8 b2h = *(const short8*)(Bh2 + kt*32);
    short8 b2l = *(const short8*)(Bl2 + kt*32);
    ohh = bmfma(a2h, b2h, ohh);
    ohl = bmfma(a2h, b2l, ohl);
    olh = bmfma(a2l, b2h, olh);
  }
  int c = lane & 15;
  if (c < 8){
    float bv = b2[160 + c];
    #pragma unroll
    for (int r = 0; r < 4; ++r){
      int m = m0 + mrow + r;
      nout8[(size_t)m*8 + c] = ohh[r] + ohl[r] + olh[r] + bv;
    }
  }
}

// ---------------- gather Xt into (T, B, 64) layout, bf16 ----------------
__global__ __launch_bounds__(256) void k_xtbufb(const float* __restrict__ X, u16* __restrict__ XtB){
  int idx = blockIdx.x*256 + threadIdx.x;
  if (idx >= T_*B_*L_) return;
  int f = idx & 63; int tb = idx >> 6; int bb = tb & 31; int t = tb >> 5;
  XtB[idx] = f2bf(X[((size_t)bb*NT_ + N_ + t)*L_ + f]);
}

// ---------------- xw = XtB @ Wih^T + bih (MFMA bf16) ----------------
__global__ __launch_bounds__(256) void k_xwm(const u16* __restrict__ XtB, const u16* __restrict__ WihB,
                                             const float* __restrict__ bih, float* __restrict__ xw){
  int m0 = blockIdx.x*64, n0 = blockIdx.y*64;
  int tid = threadIdx.x, wv = tid >> 6, lane = tid & 63;
  const u16* Ab = XtB + (size_t)(m0 + 16*wv + (lane & 15))*L_ + (lane >> 4)*8;
  const u16* Bb = WihB + (size_t)(n0 + (lane & 15))*L_ + (lane >> 4)*8;
  f32x4 c0={0,0,0,0}, c1={0,0,0,0}, c2={0,0,0,0}, c3={0,0,0,0};
  #pragma unroll
  for (int kt = 0; kt < 2; ++kt){
    short8 a = *(const short8*)(Ab + kt*32);
    c0 = bmfma(a, *(const short8*)(Bb + kt*32), c0);
    c1 = bmfma(a, *(const short8*)(Bb + 16*L_ + kt*32), c1);
    c2 = bmfma(a, *(const short8*)(Bb + 32*L_ + kt*32), c2);
    c3 = bmfma(a, *(const short8*)(Bb + 48*L_ + kt*32), c3);
  }
  int mb = m0 + 16*wv + (lane >> 4)*4;
  int nb = n0 + (lane & 15);
  f32x4 cc[4] = {c0, c1, c2, c3};
  #pragma unroll
  for (int q = 0; q < 4; ++q){
    int n = nb + q*16;
    if (n >= TR3_) continue;
    float bv = bih[n];
    #pragma unroll
    for (int r = 0; r < 4; ++r)
      xw[(size_t)(mb + r)*TR3_ + n] = cc[q][r] + bv;
  }
}

// ---------------- persistent MFMA tr-GRU scan (batched staging + early prefetch) ----------------
__global__ __launch_bounds__(192) void k_tr_scan(
    const u16* __restrict__ WhhB,  // (2148, 716) bf16
    const float* __restrict__ bhh,
    const float* __restrict__ xw,  // (5376, 2148) incl. bih
    u16* __restrict__ hb0, u16* __restrict__ hb1,  // (32, 720) bf16
    float* __restrict__ tout8,
    int* __restrict__ flags){
  __shared__ u16 w_lds[48*WSTR];
  __shared__ u16 h_lds[16*WSTR];
  __shared__ float g_lds[2*256];
  __shared__ float xw_lds[2][16*48];
  const int tid = threadIdx.x;
  const int wv = tid >> 6, lane = tid & 63;
  const int cb = blockIdx.x >> 1, hhalf = blockIdx.x & 1;
  const int k0 = cb*16, b0 = hhalf*16;
  const int prow = tid / 12, pc = tid % 12;
  const int pg = pc >> 2, pkoff = (pc & 3)*4;

  *(f32x4*)(&xw_lds[0][prow*48 + pg*16 + pkoff]) =
    *(const f32x4*)(xw + (size_t)(b0 + prow)*TR3_ + pg*TRH_ + k0 + pkoff);
  for (int o = tid; o < 16*24; o += 192){
    int n = o / 24, c = o - n*24;
    h_lds[n*WSTR + 720 + c] = 0;
  }
  for (int r = 0; r < 48; ++r){
    int g = r >> 4, m = r & 15, k = k0 + m;
    bool kv = (k < TRH_);
    const uint2* src = (const uint2*)(WhhB + (size_t)(g*TRH_ + (kv ? k : 0))*TRH_);
    uint2* dst = (uint2*)(w_lds + r*WSTR);
    uint2 zz; zz.x = 0; zz.y = 0;
    for (int o = tid; o < 186; o += 192)
      dst[o] = (kv && o < 179) ? src[o] : zz;
  }
  const u16* arow = w_lds + (size_t)(wv*16 + (lane & 15))*WSTR + (lane >> 4)*8;
  const u16* brow = h_lds + (size_t)(lane & 15)*WSTR + (lane >> 4)*8;

  const int mb = (lane >> 4)*4;
  const int kx = k0 + mb;
  const bool kval = (kx < TRH_);
  const int bx = b0 + (lane & 15);
  f32x4 hp = {0.f, 0.f, 0.f, 0.f};
  f32x4 br4 = {0,0,0,0}, bz4 = {0,0,0,0}, bn4 = {0,0,0,0};
  if (wv == 0){
    int kc = kval ? kx : 0;
    br4 = *(const f32x4*)(bhh + kc);
    bz4 = *(const f32x4*)(bhh + TRH_ + kc);
    bn4 = *(const f32x4*)(bhh + 2*TRH_ + kc);
  }
  const int sn = tid / 12, sj = tid % 12;
  __syncthreads();

  for (int t = 0; t < T_; ++t){
    const u16* hcur = (t & 1) ? hb1 : hb0;
    u16* hnxt = (t & 1) ? hb0 : hb1;
    if (tid < 45){
      const int* fp = flags + (tid*2 + hhalf)*16;
      while (__hip_atomic_load(fp, __ATOMIC_RELAXED, __HIP_MEMORY_SCOPE_AGENT) < t){}
    }
    __syncthreads();
    // stage h: issue all 15 loads (independent), drain once, then LDS writes
    {
      const u64* srow = (const u64*)(hcur + (size_t)(b0 + sn)*HSTR) + sj;
      u64 v0  = __hip_atomic_load(srow +   0, __ATOMIC_RELAXED, __HIP_MEMORY_SCOPE_AGENT);
      u64 v1  = __hip_atomic_load(srow +  12, __ATOMIC_RELAXED, __HIP_MEMORY_SCOPE_AGENT);
      u64 v2  = __hip_atomic_load(srow +  24, __ATOMIC_RELAXED, __HIP_MEMORY_SCOPE_AGENT);
      u64 v3  = __hip_atomic_load(srow +  36, __ATOMIC_RELAXED, __HIP_MEMORY_SCOPE_AGENT);
      u64 v4  = __hip_atomic_load(srow +  48, __ATOMIC_RELAXED, __HIP_MEMORY_SCOPE_AGENT);
      u64 v5  = __hip_atomic_load(srow +  60, __ATOMIC_RELAXED, __HIP_MEMORY_SCOPE_AGENT);
      u64 v6  = __hip_atomic_load(srow +  72, __ATOMIC_RELAXED, __HIP_MEMORY_SCOPE_AGENT);
      u64 v7  = __hip_atomic_load(srow +  84, __ATOMIC_RELAXED, __HIP_MEMORY_SCOPE_AGENT);
      u64 v8  = __hip_atomic_load(srow +  96, __ATOMIC_RELAXED, __HIP_MEMORY_SCOPE_AGENT);
      u64 v9  = __hip_atomic_load(srow + 108, __ATOMIC_RELAXED, __HIP_MEMORY_SCOPE_AGENT);
      u64 v10 = __hip_atomic_load(srow + 120, __ATOMIC_RELAXED, __HIP_MEMORY_SCOPE_AGENT);
      u64 v11 = __hip_atomic_load(srow + 132, __ATOMIC_RELAXED, __HIP_MEMORY_SCOPE_AGENT);
      u64 v12 = __hip_atomic_load(srow + 144, __ATOMIC_RELAXED, __HIP_MEMORY_SCOPE_AGENT);
      u64 v13 = __hip_atomic_load(srow + 156, __ATOMIC_RELAXED, __HIP_MEMORY_SCOPE_AGENT);
      u64 v14 = __hip_atomic_load(srow + 168, __ATOMIC_RELAXED, __HIP_MEMORY_SCOPE_AGENT);
      u64* d = (u64*)(h_lds + sn*WSTR) + sj;
      d[0]      = v0;   d[12]     = v1;   d[24]     = v2;   d[36]     = v3;
      d[48]     = v4;   d[60]     = v5;   d[72]     = v6;   d[84]     = v7;
      d[96]     = v8;   d[108]    = v9;   d[120]    = v10;  d[132]    = v11;
      d[144]    = v12;  d[156]    = v13;  d[168]    = v14;
    }
    __syncthreads();
    // early-issue xw prefetch for t+1 (register-buffered; ds_write at loop end)
    f32x4 pf;
    const bool haspf = (t + 1 < T_);
    if (haspf)
      pf = *(const f32x4*)(xw + (size_t)((t+1)*32 + b0 + prow)*TR3_ + pg*TRH_ + k0 + pkoff);
    f32x4 a0={0,0,0,0}, a1={0,0,0,0}, a2={0,0,0,0}, a3={0,0,0,0};
    for (int kt = 0; kt < 20; kt += 4){
      a0 = bmfma(*(const short8*)(arow + kt*32),     *(const short8*)(brow + kt*32),     a0);
      a1 = bmfma(*(const short8*)(arow + (kt+1)*32), *(const short8*)(brow + (kt+1)*32), a1);
      a2 = bmfma(*(const short8*)(arow + (kt+2)*32), *(const short8*)(brow + (kt+2)*32), a2);
      a3 = bmfma(*(const short8*)(arow + (kt+3)*32), *(const short8*)(brow + (kt+3)*32), a3);
    }
    a0 = bmfma(*(const short8*)(arow + 20*32), *(const short8*)(brow + 20*32), a0);
    a1 = bmfma(*(const short8*)(arow + 21*32), *(const short8*)(brow + 21*32), a1);
    a2 = bmfma(*(const short8*)(arow + 22*32), *(const short8*)(brow + 22*32), a2);
    f32x4 acc = (a0 + a1) + (a2 + a3);
    if (wv){
      #pragma unroll
      for (int r = 0; r < 4; ++r) g_lds[(wv-1)*256 + lane*4 + r] = acc[r];
    }
    __syncthreads();
    if (wv == 0 && kval){
      const float* xb = &xw_lds[t & 1][(lane & 15)*48];
      float hnew[4];
      #pragma unroll
      for (int r = 0; r < 4; ++r){
        float rg = sigf(xb[mb + r] + acc[r] + br4[r]);
        float zg = sigf(xb[16 + mb + r] + g_lds[lane*4 + r] + bz4[r]);
        float ng = tanhf(xb[32 + mb + r] + rg*(g_lds[256 + lane*4 + r] + bn4[r]));
        hnew[r] = (1.f - zg)*ng + zg*hp[r];
        hp[r] = hnew[r];
      }
      u64 pk = (u64)((unsigned)f2bf(hnew[0]) | ((unsigned)f2bf(hnew[1]) << 16))
             | ((u64)((unsigned)f2bf(hnew[2]) | ((unsigned)f2bf(hnew[3]) << 16)) << 32);
      __hip_atomic_store((u64*)(hnxt + (size_t)bx*HSTR + kx), pk,
                         __ATOMIC_RELAXED, __HIP_MEMORY_SCOPE_AGENT);
      if (t >= 160){
        #pragma unroll
        for (int r = 0; r < 4; ++r)
          tout8[(size_t)(bx*TRH_ + kx + r)*8 + (t - 160)] = hnew[r];
      }
    }
    if (wv == 0){
      asm volatile("s_waitcnt vmcnt(0)" ::: "memory");
      if (lane == 0)
        __hip_atomic_store(flags + blockIdx.x*16, t + 1,
                           __ATOMIC_RELAXED, __HIP_MEMORY_SCOPE_AGENT);
    }
    if (haspf)
      *(f32x4*)(&xw_lds[(t + 1) & 1][prow*48 + pg*16 + pkoff]) = pf;
  }
}

// ---------------- fused TCN tail ----------------
__global__ __launch_bounds__(256) void k_tcn(const float* __restrict__ nout8, const float* __restrict__ tout8,
                 const float* __restrict__ x,
                 const float* __restrict__ W0, const float* __restrict__ b0,
                 const float* __restrict__ W1, const float* __restrict__ b1,
                 const float* __restrict__ W2, const float* __restrict__ b2,
                 const float* __restrict__ oW, const float* __restrict__ ob,
                 float* __restrict__ out){
  __shared__ float w0s[96], b0s[16], w1s[512], b1s[16], w2s[512], b2s[16], ows[16], obs;
  int tid = threadIdx.x;
  for (int l = tid; l < 96; l += 256) w0s[l] = W0[l];
  for (int l = tid; l < 512; l += 256){ w1s[l] = W1[l]; w2s[l] = W2[l]; }
  if (tid < 16){ b0s[tid]=b0[tid]; b1s[tid]=b1[tid]; b2s[tid]=b2[tid]; ows[tid]=oW[tid]; }
  if (tid == 0) obs = ob[0];
  __syncthreads();
  int idx = blockIdx.x*256 + tid;
  if (idx >= B_*N_) return;
  int b = idx / N_, n = idx % N_;
  float s0[8], s1[8], s2[8];
  #pragma unroll
  for (int i = 0; i < 8; ++i){
    s0[i] = nout8[(size_t)idx*8 + i];
    s1[i] = tout8[(size_t)idx*8 + i];
    s2[i] = x[((size_t)b*N_ + n)*T_ + 160 + i];
  }
  float h1[16][4];
  #pragma unroll
  for (int c = 0; c < 16; ++c)
    #pragma unroll
    for (int q = 0; q < 4; ++q){
      int tt = 2*q + 1;
      float v = b0s[c]
        + w0s[c*6+0]*s0[tt-1] + w0s[c*6+1]*s0[tt]
        + w0s[c*6+2]*s1[tt-1] + w0s[c*6+3]*s1[tt]
        + w0s[c*6+4]*s2[tt-1] + w0s[c*6+5]*s2[tt];
      h1[c][q] = eluf(v);
    }
  float h2[16][2];
  #pragma unroll
  for (int c = 0; c < 16; ++c){
    float v3 = b1s[c], v7 = b1s[c];
    #pragma unroll
    for (int i2 = 0; i2 < 16; ++i2){
      v3 += w1s[c*32+i2*2]*h1[i2][0] + w1s[c*32+i2*2+1]*h1[i2][1];
      v7 += w1s[c*32+i2*2]*h1[i2][2] + w1s[c*32+i2*2+1]*h1[i2][3];
    }
    h2[c][0] = eluf(v3); h2[c][1] = eluf(v7);
  }
  float o = obs;
  #pragma unroll
  for (int c = 0; c < 16; ++c){
    float v = b2s[c];
    #pragma unroll
    for (int i2 = 0; i2 < 16; ++i2)
      v += w2s[c*32+i2*2]*h2[i2][0] + w2s[c*32+i2*2+1]*h2[i2][1];
    o += ows[c]*eluf(v);
  }
  out[idx] = o;
}

extern "C" void kernel_launch(void* const* d_in, const int* in_sizes, int n_in,
                              void* d_out, int out_size, void* d_ws, size_t ws_size,
                              hipStream_t stream){
  const float* x       = (const float*)d_in[0];
  const float* mark    = (const float*)d_in[1];
  const float* se_emb  = (const float*)d_in[2];
  const float* se_W1   = (const float*)d_in[3];
  const float* se_b1   = (const float*)d_in[4];
  const float* se_W2   = (const float*)d_in[5];
  const float* se_b2   = (const float*)d_in[6];
  const float* te_emb  = (const float*)d_in[7];
  const float* te_Wih  = (const float*)d_in[8];
  const float* te_Whh  = (const float*)d_in[9];
  const float* te_bih  = (const float*)d_in[10];
  const float* te_bhh  = (const float*)d_in[11];
  const float* gcn_W   = (const float*)d_in[12];
  const float* gcn_b   = (const float*)d_in[13];
  const float* fr_W1   = (const float*)d_in[14];
  const float* fr_b1   = (const float*)d_in[15];
  const float* fr_W2   = (const float*)d_in[16];
  const float* fr_b2   = (const float*)d_in[17];
  const float* tr_Wih  = (const float*)d_in[18];
  const float* tr_Whh  = (const float*)d_in[19];
  const float* tr_bih  = (const float*)d_in[20];
  const float* tr_bhh  = (const float*)d_in[21];
  const float* tcn_W0  = (const float*)d_in[22];
  const float* tcn_b0  = (const float*)d_in[23];
  const float* tcn_W1  = (const float*)d_in[24];
  const float* tcn_b1  = (const float*)d_in[25];
  const float* tcn_W2  = (const float*)d_in[26];
  const float* tcn_b2  = (const float*)d_in[27];
  const float* out_W   = (const float*)d_in[28];
  const float* out_b   = (const float*)d_in[29];
  float* out = (float*)d_out;
  (void)in_sizes; (void)n_in; (void)out_size; (void)ws_size;

  char* ws = (char*)d_ws;
  size_t off = 0;
  auto alloc = [&](size_t bytes)->void*{
    void* p = (void*)(ws + off); off += (bytes + 255) & ~(size_t)255; return p; };
  float* X       = (float*)alloc((size_t)B_*NT_*L_*4);
  u16*   adjh    = (u16*)  alloc((size_t)B_*NTP*NTP*2);   // hosts te aliases (adj no longer materialized)
  u16*   adjl    = (u16*)  alloc((size_t)B_*NTP*NTP*2);   // hosts xw alias
  u16*   XtB     = (u16*)  alloc((size_t)T_*B_*L_*2);
  u16*   WihB    = (u16*)  alloc((size_t)TR3P*L_*2);
  u16*   WhhB    = (u16*)  alloc((size_t)TR3_*TRH_*2);
  u16*   Xbh     = (u16*)  alloc((size_t)B_*NTP*L_*2);
  u16*   Xbl     = (u16*)  alloc((size_t)B_*NTP*L_*2);
  u16*   hTah    = (u16*)  alloc((size_t)B_*L_*NTP*2);
  u16*   hTal    = (u16*)  alloc((size_t)B_*L_*NTP*2);
  u16*   hTbh    = (u16*)  alloc((size_t)B_*L_*NTP*2);
  u16*   hTbl    = (u16*)  alloc((size_t)B_*L_*NTP*2);
  u16*   WTh     = (u16*)  alloc((size_t)4*4096*2);
  u16*   WTl     = (u16*)  alloc((size_t)4*4096*2);
  u16*   w1seh   = (u16*)  alloc((size_t)64*224*2);
  u16*   w1sel   = (u16*)  alloc((size_t)64*224*2);
  u16*   w2seh   = (u16*)  alloc((size_t)4096*2);
  u16*   w2sel   = (u16*)  alloc((size_t)4096*2);
  u16*   w1frh   = (u16*)  alloc((size_t)176*64*2);
  u16*   w1frl   = (u16*)  alloc((size_t)176*64*2);
  u16*   w2frh   = (u16*)  alloc((size_t)16*192*2);
  u16*   w2frl   = (u16*)  alloc((size_t)16*192*2);
  u16*   wteh    = (u16*)  alloc((size_t)192*768*2);
  u16*   wtel    = (u16*)  alloc((size_t)192*768*2);
  u16*   hb0     = (u16*)  alloc((size_t)B_*HSTR*2);      // contiguous hb0|hb1|flags
  u16*   hb1     = (u16*)  alloc((size_t)B_*HSTR*2);
  int*   flags   = (int*)  alloc(8192);
  float* nout8   = (float*)alloc((size_t)B_*N_*8*4);
  float* tout8   = (float*)alloc((size_t)B_*N_*8*4);
  // aliases inside adjh (te buffers, dead before tr path) and adjl (xw):
  u16*   teinh   = (u16*)adjh;                              //  8,257,536 B
  u16*   teinl   = (u16*)((char*)adjh +  8257536);          //  8,257,536 B
  float* te_xw   = (float*)((char*)adjh + 16515072);        //  4,128,768 B
  float* xw      = (float*)adjl;                            // 46,190,592 B

  hipMemsetAsync(hb0, 0, (size_t)B_*HSTR*2*2 + 8192, stream);

  // weight prep
  k_whhbf<<<(TR3_*TRH_/4 + 255)/256, 256, 0, stream>>>(tr_Whh, WhhB, TR3_*TRH_/4);
  k_wihbf<<<(TR3P*L_ + 255)/256, 256, 0, stream>>>(tr_Wih, WihB);
  k_wtb<<<4, 256, 0, stream>>>(gcn_W, WTh, WTl);
  k_sew<<<1, 256, 0, stream>>>(se_W1, se_W2, w1seh, w1sel, w2seh, w2sel);
  k_frw<<<1, 256, 0, stream>>>(fr_W1, fr_W2, w1frh, w1frl, w2frh, w2frl);
  k_wte<<<(192*768 + 255)/256, 256, 0, stream>>>(te_Wih, wteh, wtel);
  // SE path (fused staging + MFMA hi/lo)
  k_sem<<<358, 256, 0, stream>>>(x, se_emb, w1seh, w1sel, w2seh, w2sel, se_b1, se_b2, X);
  // te path (MFMA hi/lo projection + LDS scan)
  k_teinx_b<<<dim3(23,6,B_), 256, 0, stream>>>(x, teinh, teinl);
  k_teinr_b<<<(B_*T_*52 + 255)/256, 256, 0, stream>>>(mark, te_emb, teinh, teinl);
  k_texw<<<dim3(84,3), 256, 0, stream>>>(teinh, teinl, wteh, wtel, te_bih, te_xw);
  k_te_scan<<<B_, 192, 0, stream>>>(te_xw, te_Whh, te_bhh, X);
  // GCN (fused flash-GCN, adj in LDS)
  for (int i = 0; i < 2; ++i){
    k_xbf<<<dim3(28,2,B_),256,0,stream>>>(X, Xbh, Xbl, hTah, hTal);
    k_gcnf<<<dim3(14,B_),256,0,stream>>>(Xbh, Xbl, hTah, hTal,
        WTh + (i*2+0)*4096, WTl + (i*2+0)*4096, gcn_b + (i*2+0)*64, nullptr, hTbh, hTbl);
    k_gcnf<<<dim3(14,B_),256,0,stream>>>(Xbh, Xbl, hTbh, hTbl,
        WTh + (i*2+1)*4096, WTl + (i*2+1)*4096, gcn_b + (i*2+1)*64, X, hTah, hTal);
  }
  // refresh Xb hi/lo from final X (row-major only), then fr path
  k_xbf<<<dim3(28,2,B_),256,0,stream>>>(X, Xbh, Xbl, nullptr, nullptr);
  k_frm<<<358, 256, 0, stream>>>(Xbh, Xbl, w1frh, w1frl, w2frh, w2frl, fr_b1, fr_b2, nout8);
  // tr GRU: bf16 input gather, MFMA input projection, persistent scan
  k_xtbufb<<<(T_*B_*L_+255)/256,256,0,stream>>>(X, XtB);
  k_xwm<<<dim3(84,34),256,0,stream>>>(XtB, WihB, tr_bih, xw);
  k_tr_scan<<<TRBLKS,192,0,stream>>>(WhhB, tr_bhh, xw, hb0, hb1, tout8, flags);
  // fused TCN tail
  k_tcn<<<(B_*N_+255)/256,256,0,stream>>>(nout8, tout8, x,
      tcn_W0, tcn_b0, tcn_W1, tcn_b1, tcn_W2, tcn_b2, out_W, out_b, out);
}

// Round 11
// 1434.752 us; speedup vs baseline: 1.0095x; 1.0095x over previous
//
#include <hip/hip_runtime.h>

#define B_   32
#define N_   716
#define T_   168
#define L_   64
#define NT_  884     // N + T
#define NTP  896     // padded NT for bf16 tiles
#define TE3_ 192     // 3*L
#define TRH_ 716     // tr hidden
#define TR3_ 2148    // 3*TRH
#define TR3P 2176    // padded
#define WSTR 744     // padded bf16 row stride in LDS
#define HSTR 720     // padded bf16 row stride of global h buffers
#define TRBLKS 90    // 45 k-slices x 2 batch halves

typedef unsigned short u16;
typedef unsigned long long u64;
typedef __attribute__((ext_vector_type(8))) short short8;
typedef __attribute__((ext_vector_type(4))) float f32x4;

static __device__ __forceinline__ float eluf(float x){ return x > 0.f ? x : expm1f(x); }
static __device__ __forceinline__ float sigf(float x){ return 1.f/(1.f+expf(-x)); }
static __device__ __forceinline__ u16 f2bf(float f){
  unsigned u = __float_as_uint(f);
  unsigned r = (u + 0x7fffu + ((u >> 16) & 1u)) >> 16;
  return (u16)r;
}
static __device__ __forceinline__ float bf2f(u16 h){
  return __uint_as_float(((unsigned)h) << 16);
}
static __device__ __forceinline__ f32x4 bmfma(short8 a, short8 b, f32x4 c){
  return __builtin_amdgcn_mfma_f32_16x16x32_bf16(a, b, c, 0, 0, 0);
}

// ---------------- big weight conversions ----------------
__global__ __launch_bounds__(256) void k_whhbf(const float* __restrict__ in, u16* __restrict__ out, int n4){
  int i = blockIdx.x*256 + threadIdx.x;
  if (i >= n4) return;
  f32x4 v = *(const f32x4*)(in + (size_t)i*4);
  uint2 p;
  p.x = (unsigned)f2bf(v[0]) | ((unsigned)f2bf(v[1])<<16);
  p.y = (unsigned)f2bf(v[2]) | ((unsigned)f2bf(v[3])<<16);
  *(uint2*)(out + (size_t)i*4) = p;
}
__global__ __launch_bounds__(256) void k_wihbf(const float* __restrict__ Wih, u16* __restrict__ WihB){
  int idx = blockIdx.x*256 + threadIdx.x;
  if (idx >= TR3P*L_) return;
  int r = idx >> 6;
  WihB[idx] = (r < TR3_) ? f2bf(Wih[idx]) : (u16)0;
}
// merged small weight prep: blocks 0-3 gcn WT, 4 se, 5 fr, 6..581 te Wih (single bf16)
__global__ __launch_bounds__(256) void k_wsmall(
    const float* __restrict__ gW, const float* __restrict__ sW1, const float* __restrict__ sW2,
    const float* __restrict__ fW1, const float* __restrict__ fW2, const float* __restrict__ tW,
    u16* __restrict__ WTh, u16* __restrict__ WTl,
    u16* __restrict__ w1seh, u16* __restrict__ w1sel, u16* __restrict__ w2seh, u16* __restrict__ w2sel,
    u16* __restrict__ w1frh, u16* __restrict__ w1frl, u16* __restrict__ w2frh, u16* __restrict__ w2frl,
    u16* __restrict__ wteB){
  int bid = blockIdx.x, tid = threadIdx.x;
  if (bid < 4){
    int l = bid;
    for (int e = tid; e < 4096; e += 256){
      int g = e >> 6, f = e & 63;
      float v = gW[(size_t)l*4096 + f*64 + g];
      u16 hi = f2bf(v);
      WTh[(size_t)l*4096 + e] = hi;
      WTl[(size_t)l*4096 + e] = f2bf(v - bf2f(hi));
    }
  } else if (bid == 4){
    for (int e = tid; e < 64*224; e += 256){
      int g = e / 224, k = e % 224;
      float v = (k < 200) ? sW1[k*64 + g] : 0.f;
      u16 hi = f2bf(v); w1seh[e] = hi; w1sel[e] = f2bf(v - bf2f(hi));
    }
    for (int e = tid; e < 4096; e += 256){
      int g = e >> 6, f = e & 63;
      float v = sW2[f*64 + g];
      u16 hi = f2bf(v); w2seh[e] = hi; w2sel[e] = f2bf(v - bf2f(hi));
    }
  } else if (bid == 5){
    for (int e = tid; e < 176*64; e += 256){
      int n = e >> 6, k = e & 63;
      float v = (n < 168) ? fW1[k*168 + n] : 0.f;
      u16 hi = f2bf(v); w1frh[e] = hi; w1frl[e] = f2bf(v - bf2f(hi));
    }
    for (int e = tid; e < 16*192; e += 256){
      int c = e / 192, k = e % 192;
      float v = (c < 8 && k < 168) ? fW2[k*168 + 160 + c] : 0.f;
      u16 hi = f2bf(v); w2frh[e] = hi; w2frl[e] = f2bf(v - bf2f(hi));
    }
  } else {
    int idx = (bid - 6)*256 + tid;   // [0, 192*768)
    int k = idx % 768;
    float v = (k < 752) ? tW[(size_t)(idx/768)*752 + k] : 0.f;
    wteB[idx] = f2bf(v);
  }
}

// ---------------- se MFMA (fused se_in build): X[:, :716, :] = elu(se_in@W1+b1)@W2+b2 ----------------
__global__ __launch_bounds__(256) void k_sem(const float* __restrict__ x, const float* __restrict__ se_emb,
    const u16* __restrict__ w1h, const u16* __restrict__ w1l,
    const u16* __restrict__ w2h, const u16* __restrict__ w2l,
    const float* __restrict__ b1, const float* __restrict__ b2, float* __restrict__ X){
  __shared__ u16 Sh[64*232], Sl[64*232];
  __shared__ u16 Tlh[64*72], Tll[64*72];
  int m0 = blockIdx.x*64;
  int tid = threadIdx.x, wv = tid >> 6, lane = tid & 63;
  for (int o = tid; o < 64*224; o += 256){
    int r = o / 224, k = o - (o/224)*224;
    int m = m0 + r; int b = m / N_, n = m - b*N_;
    float v = 0.f;
    if (k < 168) v = x[((size_t)b*N_ + n)*T_ + k];
    else if (k < 200) v = se_emb[n*32 + (k - 168)];
    u16 hi = f2bf(v);
    Sh[r*232 + k] = hi; Sl[r*232 + k] = f2bf(v - bf2f(hi));
  }
  __syncthreads();
  const u16* Ah = Sh + (16*wv + (lane & 15))*232 + (lane >> 4)*8;
  const u16* Al = Sl + (16*wv + (lane & 15))*232 + (lane >> 4)*8;
  const u16* Bh = w1h + (lane & 15)*224 + (lane >> 4)*8;
  const u16* Bl = w1l + (lane & 15)*224 + (lane >> 4)*8;
  f32x4 hh[4], hl[4], lh[4];
  #pragma unroll
  for (int q = 0; q < 4; ++q){ hh[q]=(f32x4){0,0,0,0}; hl[q]=(f32x4){0,0,0,0}; lh[q]=(f32x4){0,0,0,0}; }
  #pragma unroll
  for (int kt = 0; kt < 7; ++kt){
    short8 ah = *(const short8*)(Ah + kt*32);
    short8 al = *(const short8*)(Al + kt*32);
    #pragma unroll
    for (int q = 0; q < 4; ++q){
      short8 bh = *(const short8*)(Bh + q*16*224 + kt*32);
      short8 bl = *(const short8*)(Bl + q*16*224 + kt*32);
      hh[q] = bmfma(ah, bh, hh[q]);
      hl[q] = bmfma(ah, bl, hl[q]);
      lh[q] = bmfma(al, bh, lh[q]);
    }
  }
  int mrow = 16*wv + (lane >> 4)*4;
  #pragma unroll
  for (int q = 0; q < 4; ++q){
    int g = q*16 + (lane & 15);
    float bv = b1[g];
    #pragma unroll
    for (int r = 0; r < 4; ++r){
      float v = eluf(hh[q][r] + hl[q][r] + lh[q][r] + bv);
      u16 hi = f2bf(v);
      Tlh[(mrow + r)*72 + g] = hi;
      Tll[(mrow + r)*72 + g] = f2bf(v - bf2f(hi));
    }
  }
  __syncthreads();
  const u16* A2h = Tlh + (16*wv + (lane & 15))*72 + (lane >> 4)*8;
  const u16* A2l = Tll + (16*wv + (lane & 15))*72 + (lane >> 4)*8;
  const u16* B2h = w2h + (lane & 15)*64 + (lane >> 4)*8;
  const u16* B2l = w2l + (lane & 15)*64 + (lane >> 4)*8;
  f32x4 ohh[4], ohl[4], olh[4];
  #pragma unroll
  for (int q = 0; q < 4; ++q){ ohh[q]=(f32x4){0,0,0,0}; ohl[q]=(f32x4){0,0,0,0}; olh[q]=(f32x4){0,0,0,0}; }
  #pragma unroll
  for (int kt = 0; kt < 2; ++kt){
    short8 a2h = *(const short8*)(A2h + kt*32);
    short8 a2l = *(const short8*)(A2l + kt*32);
    #pragma unroll
    for (int q = 0; q < 4; ++q){
      short8 b2h = *(const short8*)(B2h + q*16*64 + kt*32);
      short8 b2l = *(const short8*)(B2l + q*16*64 + kt*32);
      ohh[q] = bmfma(a2h, b2h, ohh[q]);
      ohl[q] = bmfma(a2h, b2l, ohl[q]);
      olh[q] = bmfma(a2l, b2h, olh[q]);
    }
  }
  #pragma unroll
  for (int q = 0; q < 4; ++q){
    int g = q*16 + (lane & 15);
    float bv = b2[g];
    #pragma unroll
    for (int r = 0; r < 4; ++r){
      int m = m0 + mrow + r;
      int b = m / N_, n = m - b*N_;
      X[((size_t)b*NT_ + n)*L_ + g] = ohh[q][r] + ohl[q][r] + olh[q][r] + bv;
    }
  }
}

// ---------------- te_in build (single bf16, 5376 x 768) ----------------
__global__ __launch_bounds__(256) void k_teinx_b(const float* __restrict__ x, u16* __restrict__ teB){
  __shared__ float tile[32][33];
  int b = blockIdx.z; int n0 = blockIdx.x*32, t0 = blockIdx.y*32;
  int tx = threadIdx.x & 31, ty = threadIdx.x >> 5;
  for (int i = ty; i < 32; i += 8){
    int n = n0 + i, t = t0 + tx;
    if (n < N_ && t < T_) tile[i][tx] = x[((size_t)b*N_ + n)*T_ + t];
  }
  __syncthreads();
  for (int i = ty; i < 32; i += 8){
    int t = t0 + i, n = n0 + tx;
    if (t < T_ && n < N_)
      teB[((size_t)b*T_ + t)*768 + n] = f2bf(tile[tx][i]);
  }
}
__global__ __launch_bounds__(256) void k_teinr_b(const float* __restrict__ mark, const float* __restrict__ te_emb,
                                                 u16* __restrict__ teB){
  int idx = blockIdx.x*256 + threadIdx.x;
  if (idx >= B_*T_*52) return;
  int c = idx % 52; int row = idx / 52; int b = row / T_, t = row % T_;
  float v = 0.f;
  if (c < 4) v = mark[((size_t)b*T_ + t)*4 + c];
  else if (c < 36) v = te_emb[t*32 + (c - 4)];
  teB[(size_t)row*768 + 716 + c] = f2bf(v);
}

// ---------------- te xw MFMA (single bf16): te_xw = te_in @ te_Wih^T + bih ----------------
__global__ __launch_bounds__(256) void k_texw(const u16* __restrict__ teB, const u16* __restrict__ wteB,
    const float* __restrict__ bih, float* __restrict__ xwte){
  int m0 = blockIdx.x*64, n0 = blockIdx.y*64;
  int tid = threadIdx.x, wv = tid >> 6, lane = tid & 63;
  const u16* Ah = teB + (size_t)(m0 + 16*wv + (lane & 15))*768 + (lane >> 4)*8;
  const u16* Bh = wteB + (size_t)(n0 + (lane & 15))*768 + (lane >> 4)*8;
  f32x4 hh[4];
  #pragma unroll
  for (int q = 0; q < 4; ++q) hh[q]=(f32x4){0,0,0,0};
  #pragma unroll 4
  for (int kt = 0; kt < 24; ++kt){
    short8 ah = *(const short8*)(Ah + kt*32);
    #pragma unroll
    for (int q = 0; q < 4; ++q)
      hh[q] = bmfma(ah, *(const short8*)(Bh + q*16*768 + kt*32), hh[q]);
  }
  int mb = m0 + 16*wv + (lane >> 4)*4;
  #pragma unroll
  for (int q = 0; q < 4; ++q){
    int g = n0 + q*16 + (lane & 15);
    float bv = bih[g];
    #pragma unroll
    for (int r = 0; r < 4; ++r)
      xwte[(size_t)(mb + r)*TE3_ + g] = hh[q][r] + bv;
  }
}

// ---------------- te GRU scan (ILP-split inner product) ----------------
__global__ __launch_bounds__(192) void k_te_scan(const float* __restrict__ xw, const float* __restrict__ Whh,
                 const float* __restrict__ bhh, float* __restrict__ X){
  int b = blockIdx.x; int tid = threadIdx.x;
  __shared__ float Wsh[TE3_*65];
  __shared__ float hs[64];
  __shared__ float gh[TE3_];
  for (int l = tid; l < TE3_*64; l += 192){ int j = l >> 6, f = l & 63; Wsh[j*65+f] = Whh[l]; }
  if (tid < 64) hs[tid] = 0.f;
  __syncthreads();
  for (int t = 0; t < T_; ++t){
    const float* xr = xw + ((size_t)b*T_ + t)*TE3_;
    float g0 = bhh[tid], g1 = 0.f, g2 = 0.f, g3 = 0.f;
    #pragma unroll
    for (int f = 0; f < 64; f += 4){
      g0 = fmaf(hs[f],   Wsh[tid*65+f],   g0);
      g1 = fmaf(hs[f+1], Wsh[tid*65+f+1], g1);
      g2 = fmaf(hs[f+2], Wsh[tid*65+f+2], g2);
      g3 = fmaf(hs[f+3], Wsh[tid*65+f+3], g3);
    }
    gh[tid] = (g0 + g1) + (g2 + g3);
    __syncthreads();
    if (tid < 64){
      float r = sigf(xr[tid] + gh[tid]);
      float z = sigf(xr[64+tid] + gh[64+tid]);
      float n = tanhf(xr[128+tid] + r*gh[128+tid]);
      float hn = (1.f - z)*n + z*hs[tid];
      hs[tid] = hn;
      X[((size_t)b*NT_ + N_ + t)*L_ + tid] = hn;
    }
    __syncthreads();
  }
}

// ---------------- X -> bf16 hi/lo (row-major + transposed) ----------------
__global__ __launch_bounds__(256) void k_xbf(const float* __restrict__ X,
                 u16* __restrict__ Xbh, u16* __restrict__ Xbl,
                 u16* __restrict__ XTh, u16* __restrict__ XTl){
  __shared__ u16 th[32][33], tl[32][33];
  int b = blockIdx.z, i0 = blockIdx.x*32, f0 = blockIdx.y*32;
  int tx = threadIdx.x & 31, ty = threadIdx.x >> 5;
  for (int rr = ty; rr < 32; rr += 8){
    int i = i0 + rr, f = f0 + tx;
    float v = (i < NT_) ? X[((size_t)b*NT_ + i)*L_ + f] : 0.f;
    u16 hi = f2bf(v);
    u16 lo = f2bf(v - bf2f(hi));
    th[rr][tx] = hi; tl[rr][tx] = lo;
    Xbh[((size_t)b*NTP + i)*L_ + f] = hi;
    Xbl[((size_t)b*NTP + i)*L_ + f] = lo;
  }
  __syncthreads();
  for (int rr = ty; rr < 32; rr += 8){
    XTh[((size_t)b*L_ + f0 + rr)*NTP + i0 + tx] = th[tx][rr];
    XTl[((size_t)b*L_ + f0 + rr)*NTP + i0 + tx] = tl[tx][rr];
  }
}

// ---------------- fused flash-GCN layer: Y = elu((adj@h)@W + b), adj computed in LDS ----------------
__global__ __launch_bounds__(256) void k_gcnf(
    const u16* __restrict__ Xbh, const u16* __restrict__ Xbl,
    const u16* __restrict__ hTh, const u16* __restrict__ hTl,
    const u16* __restrict__ WTh, const u16* __restrict__ WTl,
    const float* __restrict__ bias,
    float* __restrict__ Y, u16* __restrict__ YTh, u16* __restrict__ YTl){
  __shared__ u16 AJh[64*72], AJl[64*72];
  __shared__ u16 Tlh[64*72], Tll[64*72];
  int b = blockIdx.y, i0 = blockIdx.x*64;
  int tid = threadIdx.x, wv = tid >> 6, lane = tid & 63;
  const u16* XAh = Xbh + ((size_t)b*NTP + i0 + 16*wv + (lane & 15))*L_ + (lane >> 4)*8;
  const u16* XAl = Xbl + ((size_t)b*NTP + i0 + 16*wv + (lane & 15))*L_ + (lane >> 4)*8;
  const int ib = i0 + 16*wv + (lane >> 4)*4;
  const int mrow = 16*wv + (lane >> 4)*4;
  f32x4 thh[4], thl[4], tlh[4];
  #pragma unroll
  for (int q = 0; q < 4; ++q){ thh[q] = (f32x4){0,0,0,0}; thl[q] = (f32x4){0,0,0,0}; tlh[q] = (f32x4){0,0,0,0}; }
  for (int jt = 0; jt < 14; ++jt){
    int j0 = jt*64;
    {
      const u16* XBh = Xbh + ((size_t)b*NTP + j0 + (lane & 15))*L_ + (lane >> 4)*8;
      const u16* XBl = Xbl + ((size_t)b*NTP + j0 + (lane & 15))*L_ + (lane >> 4)*8;
      f32x4 chh[4], chl[4], clh[4];
      #pragma unroll
      for (int q = 0; q < 4; ++q){ chh[q] = (f32x4){0,0,0,0}; chl[q] = (f32x4){0,0,0,0}; clh[q] = (f32x4){0,0,0,0}; }
      #pragma unroll
      for (int kt = 0; kt < 2; ++kt){
        short8 ah = *(const short8*)(XAh + kt*32);
        short8 al = *(const short8*)(XAl + kt*32);
        #pragma unroll
        for (int q = 0; q < 4; ++q){
          short8 bh = *(const short8*)(XBh + q*16*L_ + kt*32);
          short8 bl = *(const short8*)(XBl + q*16*L_ + kt*32);
          chh[q] = bmfma(ah, bh, chh[q]);
          chl[q] = bmfma(ah, bl, chl[q]);
          clh[q] = bmfma(al, bh, clh[q]);
        }
      }
      int jb = j0 + (lane & 15);
      #pragma unroll
      for (int q = 0; q < 4; ++q){
        int j = jb + q*16;
        #pragma unroll
        for (int r = 0; r < 4; ++r){
          int i = ib + r;
          u16 hi = 0, lo = 0;
          if (i < NT_ && j < NT_){
            float v = tanhf(fmaxf(chh[q][r] + chl[q][r] + clh[q][r], 0.f) + (i == j ? 1.f : 0.f));
            hi = f2bf(v); lo = f2bf(v - bf2f(hi));
          }
          AJh[(mrow + r)*72 + q*16 + (lane & 15)] = hi;
          AJl[(mrow + r)*72 + q*16 + (lane & 15)] = lo;
        }
      }
    }
    __syncthreads();
    {
      const u16* A1h = AJh + (16*wv + (lane & 15))*72 + (lane >> 4)*8;
      const u16* A1l = AJl + (16*wv + (lane & 15))*72 + (lane >> 4)*8;
      const u16* B1h = hTh + ((size_t)b*L_ + (lane & 15))*NTP + j0 + (lane >> 4)*8;
      const u16* B1l = hTl + ((size_t)b*L_ + (lane & 15))*NTP + j0 + (lane >> 4)*8;
      #pragma unroll
      for (int kt = 0; kt < 2; ++kt){
        short8 ah = *(const short8*)(A1h + kt*32);
        short8 al = *(const short8*)(A1l + kt*32);
        #pragma unroll
        for (int q = 0; q < 4; ++q){
          short8 bh = *(const short8*)(B1h + q*16*NTP + kt*32);
          short8 bl = *(const short8*)(B1l + q*16*NTP + kt*32);
          thh[q] = bmfma(ah, bh, thh[q]);
          thl[q] = bmfma(ah, bl, thl[q]);
          tlh[q] = bmfma(al, bh, tlh[q]);
        }
      }
    }
    __syncthreads();
  }
  #pragma unroll
  for (int q = 0; q < 4; ++q)
    #pragma unroll
    for (int r = 0; r < 4; ++r){
      float v = thh[q][r] + thl[q][r] + tlh[q][r];
      u16 hi = f2bf(v);
      Tlh[(mrow + r)*72 + q*16 + (lane & 15)] = hi;
      Tll[(mrow + r)*72 + q*16 + (lane & 15)] = f2bf(v - bf2f(hi));
    }
  __syncthreads();
  const u16* A2h = Tlh + (16*wv + (lane & 15))*72 + (lane >> 4)*8;
  const u16* A2l = Tll + (16*wv + (lane & 15))*72 + (lane >> 4)*8;
  const u16* B2h = WTh + (lane & 15)*L_ + (lane >> 4)*8;
  const u16* B2l = WTl + (lane & 15)*L_ + (lane >> 4)*8;
  f32x4 ohh[4], ohl[4], olh[4];
  #pragma unroll
  for (int q = 0; q < 4; ++q){ ohh[q] = (f32x4){0,0,0,0}; ohl[q] = (f32x4){0,0,0,0}; olh[q] = (f32x4){0,0,0,0}; }
  #pragma unroll
  for (int kt = 0; kt < 2; ++kt){
    short8 a2h = *(const short8*)(A2h + kt*32);
    short8 a2l = *(const short8*)(A2l + kt*32);
    #pragma unroll
    for (int q = 0; q < 4; ++q){
      short8 b2h = *(const short8*)(B2h + q*16*L_ + kt*32);
      short8 b2l = *(const short8*)(B2l + q*16*L_ + kt*32);
      ohh[q] = bmfma(a2h, b2h, ohh[q]);
      ohl[q] = bmfma(a2h, b2l, ohl[q]);
      olh[q] = bmfma(a2l, b2h, olh[q]);
    }
  }
  __syncthreads();
  #pragma unroll
  for (int q = 0; q < 4; ++q){
    int g = q*16 + (lane & 15);
    float bv = bias[g];
    #pragma unroll
    for (int r = 0; r < 4; ++r){
      int i = i0 + mrow + r;
      float v = eluf(ohh[q][r] + ohl[q][r] + olh[q][r] + bv);
      if (i < NT_ && Y) Y[((size_t)b*NT_ + i)*L_ + g] = v;
      u16 hi = 0, lo = 0;
      if (i < NT_){ hi = f2bf(v); lo = f2bf(v - bf2f(hi)); }
      Tlh[g*72 + mrow + r] = hi;
      Tll[g*72 + mrow + r] = lo;
    }
  }
  __syncthreads();
  {
    int g = tid >> 2, c = tid & 3;
    uint4* dh = (uint4*)(YTh + ((size_t)b*L_ + g)*NTP + i0 + c*16);
    uint4* dl = (uint4*)(YTl + ((size_t)b*L_ + g)*NTP + i0 + c*16);
    const uint4* sh = (const uint4*)(Tlh + g*72 + c*16);
    const uint4* sl = (const uint4*)(Tll + g*72 + c*16);
    dh[0] = sh[0]; dh[1] = sh[1];
    dl[0] = sl[0]; dl[1] = sl[1];
  }
}

// ---------------- fr MFMA (stages X fp32 directly): nout8 = (elu(Xs@W1+b1)@W2+b2)[:,160:168] ----------------
__global__ __launch_bounds__(256) void k_frm(const float* __restrict__ X,
    const u16* __restrict__ w1h, const u16* __restrict__ w1l,
    const u16* __restrict__ w2h, const u16* __restrict__ w2l,
    const float* __restrict__ b1, const float* __restrict__ b2, float* __restrict__ nout8){
  __shared__ u16 Sh[64*72], Sl[64*72];
  __shared__ u16 T1h[64*192], T1l[64*192];
  __shared__ u16 B2hl[16*192], B2ll[16*192];
  int m0 = blockIdx.x*64;
  int tid = threadIdx.x, wv = tid >> 6, lane = tid & 63;
  for (int o = tid; o < 768; o += 256){
    ((u64*)B2hl)[o] = ((const u64*)w2h)[o];
    ((u64*)B2ll)[o] = ((const u64*)w2l)[o];
  }
  for (int o = tid; o < 1024; o += 256){
    int rr = o >> 4, cc = o & 15;
    T1h[rr*192 + 176 + cc] = 0; T1l[rr*192 + 176 + cc] = 0;
  }
  for (int o = tid; o < 4096; o += 256){
    int r = o >> 6, k = o & 63;
    int m = m0 + r; int ab = m / N_, an = m - ab*N_;
    float v = X[((size_t)ab*NT_ + an)*L_ + k];
    u16 hi = f2bf(v);
    Sh[r*72 + k] = hi; Sl[r*72 + k] = f2bf(v - bf2f(hi));
  }
  __syncthreads();
  const u16* Ah = Sh + (16*wv + (lane & 15))*72 + (lane >> 4)*8;
  const u16* Al = Sl + (16*wv + (lane & 15))*72 + (lane >> 4)*8;
  int mrow = 16*wv + (lane >> 4)*4;
  for (int tile = 0; tile < 11; ++tile){
    const u16* Bh = w1h + (tile*16 + (lane & 15))*64 + (lane >> 4)*8;
    const u16* Bl = w1l + (tile*16 + (lane & 15))*64 + (lane >> 4)*8;
    f32x4 shh={0,0,0,0}, shl={0,0,0,0}, slh={0,0,0,0};
    #pragma unroll
    for (int kt = 0; kt < 2; ++kt){
      short8 ah = *(const short8*)(Ah + kt*32);
      short8 al = *(const short8*)(Al + kt*32);
      short8 bh = *(const short8*)(Bh + kt*32);
      short8 bl = *(const short8*)(Bl + kt*32);
      shh = bmfma(ah, bh, shh);
      shl = bmfma(ah, bl, shl);
      slh = bmfma(al, bh, slh);
    }
    int col = tile*16 + (lane & 15);
    float bb = (col < 168) ? b1[col] : 0.f;
    #pragma unroll
    for (int r = 0; r < 4; ++r){
      float v = (col < 168) ? eluf(shh[r] + shl[r] + slh[r] + bb) : 0.f;
      u16 hi = f2bf(v);
      T1h[(mrow + r)*192 + col] = hi;
      T1l[(mrow + r)*192 + col] = f2bf(v - bf2f(hi));
    }
  }
  __syncthreads();
  const u16* A2h = T1h + (16*wv + (lane & 15))*192 + (lane >> 4)*8;
  const u16* A2l = T1l + (16*wv + (lane & 15))*192 + (lane >> 4)*8;
  const u16* Bh2 = B2hl + (lane & 15)*192 + (lane >> 4)*8;
  const u16* Bl2 = B2ll + (lane & 15)*192 + (lane >> 4)*8;
  f32x4 ohh={0,0,0,0}, ohl={0,0,0,0}, olh={0,0,0,0};
  #pragma unroll
  for (int kt = 0; kt < 6; ++kt){
    short8 a2h = *(const short8*)(A2h + kt*32);
    short8 a2l = *(const short8*)(A2l + kt*32);
    short8 b2h = *(const short8*)(Bh2 + kt*32);
    short8 b2l = *(const short8*)(Bl2 + kt*32);
    ohh = bmfma(a2h, b2h, ohh);
    ohl = bmfma(a2h, b2l, ohl);
    olh = bmfma(a2l, b2h, olh);
  }
  int c = lane & 15;
  if (c < 8){
    float bv = b2[160 + c];
    #pragma unroll
    for (int r = 0; r < 4; ++r){
      int m = m0 + mrow + r;
      nout8[(size_t)m*8 + c] = ohh[r] + ohl[r] + olh[r] + bv;
    }
  }
}

// ---------------- xw = Xt @ Wih^T + bih, reading X fp32 directly, bf16 out ----------------
__global__ __launch_bounds__(256) void k_xwm2(const float* __restrict__ X, const u16* __restrict__ WihB,
                                              const float* __restrict__ bih, u16* __restrict__ xwB){
  int m0 = blockIdx.x*64, n0 = blockIdx.y*64;
  int tid = threadIdx.x, wv = tid >> 6, lane = tid & 63;
  int am = m0 + 16*wv + (lane & 15);
  int t = am >> 5, b = am & 31;
  const float* Arow = X + ((size_t)b*NT_ + N_ + t)*L_ + (lane >> 4)*8;
  const u16* Bb = WihB + (size_t)(n0 + (lane & 15))*L_ + (lane >> 4)*8;
  f32x4 c0={0,0,0,0}, c1={0,0,0,0}, c2={0,0,0,0}, c3={0,0,0,0};
  #pragma unroll
  for (int kt = 0; kt < 2; ++kt){
    f32x4 f0 = *(const f32x4*)(Arow + kt*32);
    f32x4 f1 = *(const f32x4*)(Arow + kt*32 + 4);
    short8 a;
    a[0]=(short)f2bf(f0[0]); a[1]=(short)f2bf(f0[1]); a[2]=(short)f2bf(f0[2]); a[3]=(short)f2bf(f0[3]);
    a[4]=(short)f2bf(f1[0]); a[5]=(short)f2bf(f1[1]); a[6]=(short)f2bf(f1[2]); a[7]=(short)f2bf(f1[3]);
    c0 = bmfma(a, *(const short8*)(Bb + kt*32), c0);
    c1 = bmfma(a, *(const short8*)(Bb + 16*L_ + kt*32), c1);
    c2 = bmfma(a, *(const short8*)(Bb + 32*L_ + kt*32), c2);
    c3 = bmfma(a, *(const short8*)(Bb + 48*L_ + kt*32), c3);
  }
  int mb = m0 + 16*wv + (lane >> 4)*4;
  int nb = n0 + (lane & 15);
  f32x4 cc[4] = {c0, c1, c2, c3};
  #pragma unroll
  for (int q = 0; q < 4; ++q){
    int n = nb + q*16;
    if (n >= TR3_) continue;
    float bv = bih[n];
    #pragma unroll
    for (int r = 0; r < 4; ++r)
      xwB[(size_t)(mb + r)*TR3_ + n] = f2bf(cc[q][r] + bv);
  }
}

// ---------------- persistent MFMA tr-GRU scan (bf16 xw, wave-1 end-of-iter poll) ----------------
__global__ __launch_bounds__(192) void k_tr_scan(
    const u16* __restrict__ WhhB,  // (2148, 716) bf16
    const float* __restrict__ bhh,
    const u16* __restrict__ xwB,   // (5376, 2148) bf16, incl. bih
    u16* __restrict__ hb0, u16* __restrict__ hb1,  // (32, 720) bf16
    float* __restrict__ tout8,
    int* __restrict__ flags){
  __shared__ u16 w_lds[48*WSTR];
  __shared__ u16 h_lds[16*WSTR];
  __shared__ float g_lds[2*256];
  __shared__ u64 xw_ldsq[2][192];   // 16 rows x 12 u64 (48 bf16) per buffer
  const int tid = threadIdx.x;
  const int wv = tid >> 6, lane = tid & 63;
  const int cb = blockIdx.x >> 1, hhalf = blockIdx.x & 1;
  const int k0 = cb*16, b0 = hhalf*16;
  const int prow = tid / 12, pc = tid % 12;
  const int pg = pc >> 2, pko = (pc & 3)*4;

  // prologue xw prefetch (t=0)
  xw_ldsq[0][prow*12 + pc] =
    *(const u64*)(xwB + (size_t)(b0 + prow)*TR3_ + pg*TRH_ + k0 + pko);
  for (int o = tid; o < 16*24; o += 192){
    int n = o / 24, c = o - n*24;
    h_lds[n*WSTR + 720 + c] = 0;
  }
  for (int r = 0; r < 48; ++r){
    int g = r >> 4, m = r & 15, k = k0 + m;
    bool kv = (k < TRH_);
    const uint2* src = (const uint2*)(WhhB + (size_t)(g*TRH_ + (kv ? k : 0))*TRH_);
    uint2* dst = (uint2*)(w_lds + r*WSTR);
    uint2 zz; zz.x = 0; zz.y = 0;
    for (int o = tid; o < 186; o += 192)
      dst[o] = (kv && o < 179) ? src[o] : zz;
  }
  const u16* arow = w_lds + (size_t)(wv*16 + (lane & 15))*WSTR + (lane >> 4)*8;
  const u16* brow = h_lds + (size_t)(lane & 15)*WSTR + (lane >> 4)*8;

  const int mb = (lane >> 4)*4;
  const int kx = k0 + mb;
  const bool kval = (kx < TRH_);
  const int bx = b0 + (lane & 15);
  f32x4 hp = {0.f, 0.f, 0.f, 0.f};
  f32x4 br4 = {0,0,0,0}, bz4 = {0,0,0,0}, bn4 = {0,0,0,0};
  if (wv == 0){
    int kc = kval ? kx : 0;
    br4 = *(const f32x4*)(bhh + kc);
    bz4 = *(const f32x4*)(bhh + TRH_ + kc);
    bn4 = *(const f32x4*)(bhh + 2*TRH_ + kc);
  }
  const int sn = tid / 12, sj = tid % 12;
  __syncthreads();

  for (int t = 0; t < T_; ++t){
    const u16* hcur = (t & 1) ? hb1 : hb0;
    u16* hnxt = (t & 1) ? hb0 : hb1;
    // entry: flags for step t verified (end of prev iteration; t=0 trivial)
    {
      const u64* srow = (const u64*)(hcur + (size_t)(b0 + sn)*HSTR) + sj;
      u64 v0  = __hip_atomic_load(srow +   0, __ATOMIC_RELAXED, __HIP_MEMORY_SCOPE_AGENT);
      u64 v1  = __hip_atomic_load(srow +  12, __ATOMIC_RELAXED, __HIP_MEMORY_SCOPE_AGENT);
      u64 v2  = __hip_atomic_load(srow +  24, __ATOMIC_RELAXED, __HIP_MEMORY_SCOPE_AGENT);
      u64 v3  = __hip_atomic_load(srow +  36, __ATOMIC_RELAXED, __HIP_MEMORY_SCOPE_AGENT);
      u64 v4  = __hip_atomic_load(srow +  48, __ATOMIC_RELAXED, __HIP_MEMORY_SCOPE_AGENT);
      u64 v5  = __hip_atomic_load(srow +  60, __ATOMIC_RELAXED, __HIP_MEMORY_SCOPE_AGENT);
      u64 v6  = __hip_atomic_load(srow +  72, __ATOMIC_RELAXED, __HIP_MEMORY_SCOPE_AGENT);
      u64 v7  = __hip_atomic_load(srow +  84, __ATOMIC_RELAXED, __HIP_MEMORY_SCOPE_AGENT);
      u64 v8  = __hip_atomic_load(srow +  96, __ATOMIC_RELAXED, __HIP_MEMORY_SCOPE_AGENT);
      u64 v9  = __hip_atomic_load(srow + 108, __ATOMIC_RELAXED, __HIP_MEMORY_SCOPE_AGENT);
      u64 v10 = __hip_atomic_load(srow + 120, __ATOMIC_RELAXED, __HIP_MEMORY_SCOPE_AGENT);
      u64 v11 = __hip_atomic_load(srow + 132, __ATOMIC_RELAXED, __HIP_MEMORY_SCOPE_AGENT);
      u64 v12 = __hip_atomic_load(srow + 144, __ATOMIC_RELAXED, __HIP_MEMORY_SCOPE_AGENT);
      u64 v13 = __hip_atomic_load(srow + 156, __ATOMIC_RELAXED, __HIP_MEMORY_SCOPE_AGENT);
      u64 v14 = __hip_atomic_load(srow + 168, __ATOMIC_RELAXED, __HIP_MEMORY_SCOPE_AGENT);
      u64* d = (u64*)(h_lds + sn*WSTR) + sj;
      d[0]   = v0;   d[12]  = v1;   d[24]  = v2;   d[36]  = v3;
      d[48]  = v4;   d[60]  = v5;   d[72]  = v6;   d[84]  = v7;
      d[96]  = v8;   d[108] = v9;   d[120] = v10;  d[132] = v11;
      d[144] = v12;  d[156] = v13;  d[168] = v14;
    }
    __syncthreads();   // B: h_lds ready
    // early-issue xw prefetch for t+1 (register-buffered)
    u64 pf = 0;
    const bool haspf = (t + 1 < T_);
    if (haspf)
      pf = *(const u64*)(xwB + (size_t)((t+1)*32 + b0 + prow)*TR3_ + pg*TRH_ + k0 + pko);
    f32x4 a0={0,0,0,0}, a1={0,0,0,0}, a2={0,0,0,0}, a3={0,0,0,0};
    for (int kt = 0; kt < 20; kt += 4){
      a0 = bmfma(*(const short8*)(arow + kt*32),     *(const short8*)(brow + kt*32),     a0);
      a1 = bmfma(*(const short8*)(arow + (kt+1)*32), *(const short8*)(brow + (kt+1)*32), a1);
      a2 = bmfma(*(const short8*)(arow + (kt+2)*32), *(const short8*)(brow + (kt+2)*32), a2);
      a3 = bmfma(*(const short8*)(arow + (kt+3)*32), *(const short8*)(brow + (kt+3)*32), a3);
    }
    a0 = bmfma(*(const short8*)(arow + 20*32), *(const short8*)(brow + 20*32), a0);
    a1 = bmfma(*(const short8*)(arow + 21*32), *(const short8*)(brow + 21*32), a1);
    a2 = bmfma(*(const short8*)(arow + 22*32), *(const short8*)(brow + 22*32), a2);
    f32x4 acc = (a0 + a1) + (a2 + a3);
    if (wv){
      #pragma unroll
      for (int r = 0; r < 4; ++r) g_lds[(wv-1)*256 + lane*4 + r] = acc[r];
    }
    __syncthreads();   // C: gate partials exchanged
    if (wv == 0){
      if (kval){
        const u16* xb = ((const u16*)&xw_ldsq[t & 1][0]) + (lane & 15)*48;
        float hnew[4];
        #pragma unroll
        for (int r = 0; r < 4; ++r){
          float rg = sigf(bf2f(xb[mb + r]) + acc[r] + br4[r]);
          float zg = sigf(bf2f(xb[16 + mb + r]) + g_lds[lane*4 + r] + bz4[r]);
          float ng = tanhf(bf2f(xb[32 + mb + r]) + rg*(g_lds[256 + lane*4 + r] + bn4[r]));
          hnew[r] = (1.f - zg)*ng + zg*hp[r];
          hp[r] = hnew[r];
        }
        u64 pk = (u64)((unsigned)f2bf(hnew[0]) | ((unsigned)f2bf(hnew[1]) << 16))
               | ((u64)((unsigned)f2bf(hnew[2]) | ((unsigned)f2bf(hnew[3]) << 16)) << 32);
        __hip_atomic_store((u64*)(hnxt + (size_t)bx*HSTR + kx), pk,
                           __ATOMIC_RELAXED, __HIP_MEMORY_SCOPE_AGENT);
        if (t >= 160){
          #pragma unroll
          for (int r = 0; r < 4; ++r)
            tout8[(size_t)(bx*TRH_ + kx + r)*8 + (t - 160)] = hnew[r];
        }
      }
      asm volatile("s_waitcnt vmcnt(0)" ::: "memory");
      if (lane == 0)
        __hip_atomic_store(flags + blockIdx.x*16, t + 1,
                           __ATOMIC_RELAXED, __HIP_MEMORY_SCOPE_AGENT);
    }
    // wave 1 polls for step t+1 while wave 0 does ack+flag
    if (wv == 1 && lane < 45 && t + 1 < T_){
      const int* fp = flags + (lane*2 + hhalf)*16;
      while (__hip_atomic_load(fp, __ATOMIC_RELAXED, __HIP_MEMORY_SCOPE_AGENT) < t + 1){}
    }
    if (haspf) xw_ldsq[(t + 1) & 1][prow*12 + pc] = pf;
    __syncthreads();   // A: join poll + ack + prefetch; entry barrier of t+1
  }
}

// ---------------- fused TCN tail ----------------
__global__ __launch_bounds__(256) void k_tcn(const float* __restrict__ nout8, const float* __restrict__ tout8,
                 const float* __restrict__ x,
                 const float* __restrict__ W0, const float* __restrict__ b0,
                 const float* __restrict__ W1, const float* __restrict__ b1,
                 const float* __restrict__ W2, const float* __restrict__ b2,
                 const float* __restrict__ oW, const float* __restrict__ ob,
                 float* __restrict__ out){
  __shared__ float w0s[96], b0s[16], w1s[512], b1s[16], w2s[512], b2s[16], ows[16], obs;
  int tid = threadIdx.x;
  for (int l = tid; l < 96; l += 256) w0s[l] = W0[l];
  for (int l = tid; l < 512; l += 256){ w1s[l] = W1[l]; w2s[l] = W2[l]; }
  if (tid < 16){ b0s[tid]=b0[tid]; b1s[tid]=b1[tid]; b2s[tid]=b2[tid]; ows[tid]=oW[tid]; }
  if (tid == 0) obs = ob[0];
  __syncthreads();
  int idx = blockIdx.x*256 + tid;
  if (idx >= B_*N_) return;
  int b = idx / N_, n = idx % N_;
  float s0[8], s1[8], s2[8];
  #pragma unroll
  for (int i = 0; i < 8; ++i){
    s0[i] = nout8[(size_t)idx*8 + i];
    s1[i] = tout8[(size_t)idx*8 + i];
    s2[i] = x[((size_t)b*N_ + n)*T_ + 160 + i];
  }
  float h1[16][4];
  #pragma unroll
  for (int c = 0; c < 16; ++c)
    #pragma unroll
    for (int q = 0; q < 4; ++q){
      int tt = 2*q + 1;
      float v = b0s[c]
        + w0s[c*6+0]*s0[tt-1] + w0s[c*6+1]*s0[tt]
        + w0s[c*6+2]*s1[tt-1] + w0s[c*6+3]*s1[tt]
        + w0s[c*6+4]*s2[tt-1] + w0s[c*6+5]*s2[tt];
      h1[c][q] = eluf(v);
    }
  float h2[16][2];
  #pragma unroll
  for (int c = 0; c < 16; ++c){
    float v3 = b1s[c], v7 = b1s[c];
    #pragma unroll
    for (int i2 = 0; i2 < 16; ++i2){
      v3 += w1s[c*32+i2*2]*h1[i2][0] + w1s[c*32+i2*2+1]*h1[i2][1];
      v7 += w1s[c*32+i2*2]*h1[i2][2] + w1s[c*32+i2*2+1]*h1[i2][3];
    }
    h2[c][0] = eluf(v3); h2[c][1] = eluf(v7);
  }
  float o = obs;
  #pragma unroll
  for (int c = 0; c < 16; ++c){
    float v = b2s[c];
    #pragma unroll
    for (int i2 = 0; i2 < 16; ++i2)
      v += w2s[c*32+i2*2]*h2[i2][0] + w2s[c*32+i2*2+1]*h2[i2][1];
    o += ows[c]*eluf(v);
  }
  out[idx] = o;
}

extern "C" void kernel_launch(void* const* d_in, const int* in_sizes, int n_in,
                              void* d_out, int out_size, void* d_ws, size_t ws_size,
                              hipStream_t stream){
  const float* x       = (const float*)d_in[0];
  const float* mark    = (const float*)d_in[1];
  const float* se_emb  = (const float*)d_in[2];
  const float* se_W1   = (const float*)d_in[3];
  const float* se_b1   = (const float*)d_in[4];
  const float* se_W2   = (const float*)d_in[5];
  const float* se_b2   = (const float*)d_in[6];
  const float* te_emb  = (const float*)d_in[7];
  const float* te_Wih  = (const float*)d_in[8];
  const float* te_Whh  = (const float*)d_in[9];
  const float* te_bih  = (const float*)d_in[10];
  const float* te_bhh  = (const float*)d_in[11];
  const float* gcn_W   = (const float*)d_in[12];
  const float* gcn_b   = (const float*)d_in[13];
  const float* fr_W1   = (const float*)d_in[14];
  const float* fr_b1   = (const float*)d_in[15];
  const float* fr_W2   = (const float*)d_in[16];
  const float* fr_b2   = (const float*)d_in[17];
  const float* tr_Wih  = (const float*)d_in[18];
  const float* tr_Whh  = (const float*)d_in[19];
  const float* tr_bih  = (const float*)d_in[20];
  const float* tr_bhh  = (const float*)d_in[21];
  const float* tcn_W0  = (const float*)d_in[22];
  const float* tcn_b0  = (const float*)d_in[23];
  const float* tcn_W1  = (const float*)d_in[24];
  const float* tcn_b1  = (const float*)d_in[25];
  const float* tcn_W2  = (const float*)d_in[26];
  const float* tcn_b2  = (const float*)d_in[27];
  const float* out_W   = (const float*)d_in[28];
  const float* out_b   = (const float*)d_in[29];
  float* out = (float*)d_out;
  (void)in_sizes; (void)n_in; (void)out_size; (void)ws_size;

  char* ws = (char*)d_ws;
  size_t off = 0;
  auto alloc = [&](size_t bytes)->void*{
    void* p = (void*)(ws + off); off += (bytes + 255) & ~(size_t)255; return p; };
  float* X       = (float*)alloc((size_t)B_*NT_*L_*4);
  u16*   teinB   = (u16*)  alloc((size_t)B_*T_*768*2);     //  8.3MB
  float* te_xw   = (float*)alloc((size_t)B_*T_*TE3_*4);    //  4.1MB
  u16*   xwB     = (u16*)  alloc((size_t)B_*T_*TR3_*2);    // 23.1MB
  u16*   WihB    = (u16*)  alloc((size_t)TR3P*L_*2);
  u16*   WhhB    = (u16*)  alloc((size_t)TR3_*TRH_*2);
  u16*   Xbh     = (u16*)  alloc((size_t)B_*NTP*L_*2);
  u16*   Xbl     = (u16*)  alloc((size_t)B_*NTP*L_*2);
  u16*   hTah    = (u16*)  alloc((size_t)B_*L_*NTP*2);
  u16*   hTal    = (u16*)  alloc((size_t)B_*L_*NTP*2);
  u16*   hTbh    = (u16*)  alloc((size_t)B_*L_*NTP*2);
  u16*   hTbl    = (u16*)  alloc((size_t)B_*L_*NTP*2);
  u16*   WTh     = (u16*)  alloc((size_t)4*4096*2);
  u16*   WTl     = (u16*)  alloc((size_t)4*4096*2);
  u16*   w1seh   = (u16*)  alloc((size_t)64*224*2);
  u16*   w1sel   = (u16*)  alloc((size_t)64*224*2);
  u16*   w2seh   = (u16*)  alloc((size_t)4096*2);
  u16*   w2sel   = (u16*)  alloc((size_t)4096*2);
  u16*   w1frh   = (u16*)  alloc((size_t)176*64*2);
  u16*   w1frl   = (u16*)  alloc((size_t)176*64*2);
  u16*   w2frh   = (u16*)  alloc((size_t)16*192*2);
  u16*   w2frl   = (u16*)  alloc((size_t)16*192*2);
  u16*   wteB    = (u16*)  alloc((size_t)192*768*2);
  u16*   hb0     = (u16*)  alloc((size_t)B_*HSTR*2);      // contiguous hb0|hb1|flags
  u16*   hb1     = (u16*)  alloc((size_t)B_*HSTR*2);
  int*   flags   = (int*)  alloc(8192);
  float* nout8   = (float*)alloc((size_t)B_*N_*8*4);
  float* tout8   = (float*)alloc((size_t)B_*N_*8*4);

  hipMemsetAsync(hb0, 0, (size_t)B_*HSTR*2*2 + 8192, stream);

  // weight prep
  k_whhbf<<<(TR3_*TRH_/4 + 255)/256, 256, 0, stream>>>(tr_Whh, WhhB, TR3_*TRH_/4);
  k_wihbf<<<(TR3P*L_ + 255)/256, 256, 0, stream>>>(tr_Wih, WihB);
  k_wsmall<<<582, 256, 0, stream>>>(gcn_W, se_W1, se_W2, fr_W1, fr_W2, te_Wih,
      WTh, WTl, w1seh, w1sel, w2seh, w2sel, w1frh, w1frl, w2frh, w2frl, wteB);
  // SE path (fused staging + MFMA hi/lo)
  k_sem<<<358, 256, 0, stream>>>(x, se_emb, w1seh, w1sel, w2seh, w2sel, se_b1, se_b2, X);
  // te path (single bf16 projection + LDS scan)
  k_teinx_b<<<dim3(23,6,B_), 256, 0, stream>>>(x, teinB);
  k_teinr_b<<<(B_*T_*52 + 255)/256, 256, 0, stream>>>(mark, te_emb, teinB);
  k_texw<<<dim3(84,3), 256, 0, stream>>>(teinB, wteB, te_bih, te_xw);
  k_te_scan<<<B_, 192, 0, stream>>>(te_xw, te_Whh, te_bhh, X);
  // GCN (fused flash-GCN, adj in LDS)
  for (int i = 0; i < 2; ++i){
    k_xbf<<<dim3(28,2,B_),256,0,stream>>>(X, Xbh, Xbl, hTah, hTal);
    k_gcnf<<<dim3(14,B_),256,0,stream>>>(Xbh, Xbl, hTah, hTal,
        WTh + (i*2+0)*4096, WTl + (i*2+0)*4096, gcn_b + (i*2+0)*64, nullptr, hTbh, hTbl);
    k_gcnf<<<dim3(14,B_),256,0,stream>>>(Xbh, Xbl, hTbh, hTbl,
        WTh + (i*2+1)*4096, WTl + (i*2+1)*4096, gcn_b + (i*2+1)*64, X, hTah, hTal);
  }
  // fr path (stages X fp32 directly)
  k_frm<<<358, 256, 0, stream>>>(X, w1frh, w1frl, w2frh, w2frl, fr_b1, fr_b2, nout8);
  // tr GRU: direct-X input projection (bf16 out), persistent scan
  k_xwm2<<<dim3(84,34),256,0,stream>>>(X, WihB, tr_bih, xwB);
  k_tr_scan<<<TRBLKS,192,0,stream>>>(WhhB, tr_bhh, xwB, hb0, hb1, tout8, flags);
  // fused TCN tail
  k_tcn<<<(B_*N_+255)/256,256,0,stream>>>(nout8, tout8, x,
      tcn_W0, tcn_b0, tcn_W1, tcn_b1, tcn_W2, tcn_b2, out_W, out_b, out);
}

// Round 12
// 1419.021 us; speedup vs baseline: 1.0207x; 1.0111x over previous
//
#include <hip/hip_runtime.h>

#define B_   32
#define N_   716
#define T_   168
#define L_   64
#define NT_  884     // N + T
#define NTP  896     // padded NT for bf16 tiles
#define TE3_ 192     // 3*L
#define TRH_ 716     // tr hidden
#define TR3_ 2148    // 3*TRH
#define TR3P 2176    // padded
#define WSTR 744     // padded bf16 row stride in LDS
#define HSTR 720     // padded bf16 row stride of global h buffers
#define TRBLKS 90    // 45 k-slices x 2 batch halves

typedef unsigned short u16;
typedef unsigned long long u64;
typedef __attribute__((ext_vector_type(8))) short short8;
typedef __attribute__((ext_vector_type(4))) float f32x4;

static __device__ __forceinline__ float eluf(float x){ return x > 0.f ? x : expm1f(x); }
static __device__ __forceinline__ float sigf(float x){ return 1.f/(1.f+expf(-x)); }
static __device__ __forceinline__ u16 f2bf(float f){
  unsigned u = __float_as_uint(f);
  unsigned r = (u + 0x7fffu + ((u >> 16) & 1u)) >> 16;
  return (u16)r;
}
static __device__ __forceinline__ float bf2f(u16 h){
  return __uint_as_float(((unsigned)h) << 16);
}
static __device__ __forceinline__ f32x4 bmfma(short8 a, short8 b, f32x4 c){
  return __builtin_amdgcn_mfma_f32_16x16x32_bf16(a, b, c, 0, 0, 0);
}

// ---------------- merged weight prep ----------------
// blocks [0,1502): tr_Whh->bf16 ; [1502,2046): tr_Wih->bf16 padded ;
// [2046,2050): gcn WT hi/lo ; 2050: se ; 2051: fr ; [2052,2628): te Wih bf16
__global__ __launch_bounds__(256) void k_prep(
    const float* __restrict__ whh, u16* __restrict__ WhhB,
    const float* __restrict__ wih, u16* __restrict__ WihB,
    const float* __restrict__ gW, const float* __restrict__ sW1, const float* __restrict__ sW2,
    const float* __restrict__ fW1, const float* __restrict__ fW2, const float* __restrict__ tW,
    u16* __restrict__ WTh, u16* __restrict__ WTl,
    u16* __restrict__ w1seh, u16* __restrict__ w1sel, u16* __restrict__ w2seh, u16* __restrict__ w2sel,
    u16* __restrict__ w1frh, u16* __restrict__ w1frl, u16* __restrict__ w2frh, u16* __restrict__ w2frl,
    u16* __restrict__ wteB){
  int bid = blockIdx.x, tid = threadIdx.x;
  if (bid < 1502){
    int i = bid*256 + tid;
    if (i < TR3_*TRH_/4){
      f32x4 v = *(const f32x4*)(whh + (size_t)i*4);
      uint2 p;
      p.x = (unsigned)f2bf(v[0]) | ((unsigned)f2bf(v[1])<<16);
      p.y = (unsigned)f2bf(v[2]) | ((unsigned)f2bf(v[3])<<16);
      *(uint2*)(WhhB + (size_t)i*4) = p;
    }
  } else if (bid < 2046){
    int idx = (bid - 1502)*256 + tid;
    int r = idx >> 6;
    WihB[idx] = (r < TR3_) ? f2bf(wih[idx]) : (u16)0;
  } else if (bid < 2050){
    int l = bid - 2046;
    for (int e = tid; e < 4096; e += 256){
      int g = e >> 6, f = e & 63;
      float v = gW[(size_t)l*4096 + f*64 + g];
      u16 hi = f2bf(v);
      WTh[(size_t)l*4096 + e] = hi;
      WTl[(size_t)l*4096 + e] = f2bf(v - bf2f(hi));
    }
  } else if (bid == 2050){
    for (int e = tid; e < 64*224; e += 256){
      int g = e / 224, k = e % 224;
      float v = (k < 200) ? sW1[k*64 + g] : 0.f;
      u16 hi = f2bf(v); w1seh[e] = hi; w1sel[e] = f2bf(v - bf2f(hi));
    }
    for (int e = tid; e < 4096; e += 256){
      int g = e >> 6, f = e & 63;
      float v = sW2[f*64 + g];
      u16 hi = f2bf(v); w2seh[e] = hi; w2sel[e] = f2bf(v - bf2f(hi));
    }
  } else if (bid == 2051){
    for (int e = tid; e < 176*64; e += 256){
      int n = e >> 6, k = e & 63;
      float v = (n < 168) ? fW1[k*168 + n] : 0.f;
      u16 hi = f2bf(v); w1frh[e] = hi; w1frl[e] = f2bf(v - bf2f(hi));
    }
    for (int e = tid; e < 16*192; e += 256){
      int c = e / 192, k = e % 192;
      float v = (c < 8 && k < 168) ? fW2[k*168 + 160 + c] : 0.f;
      u16 hi = f2bf(v); w2frh[e] = hi; w2frl[e] = f2bf(v - bf2f(hi));
    }
  } else {
    int idx = (bid - 2052)*256 + tid;   // [0, 192*768)
    int k = idx % 768;
    float v = (k < 752) ? tW[(size_t)(idx/768)*752 + k] : 0.f;
    wteB[idx] = f2bf(v);
  }
}

// ---------------- se MFMA (fused se_in build): X[:, :716, :] = elu(se_in@W1+b1)@W2+b2 ----------------
__global__ __launch_bounds__(256) void k_sem(const float* __restrict__ x, const float* __restrict__ se_emb,
    const u16* __restrict__ w1h, const u16* __restrict__ w1l,
    const u16* __restrict__ w2h, const u16* __restrict__ w2l,
    const float* __restrict__ b1, const float* __restrict__ b2, float* __restrict__ X){
  __shared__ u16 Sh[64*232], Sl[64*232];
  __shared__ u16 Tlh[64*72], Tll[64*72];
  int m0 = blockIdx.x*64;
  int tid = threadIdx.x, wv = tid >> 6, lane = tid & 63;
  for (int o = tid; o < 64*224; o += 256){
    int r = o / 224, k = o - (o/224)*224;
    int m = m0 + r; int b = m / N_, n = m - b*N_;
    float v = 0.f;
    if (k < 168) v = x[((size_t)b*N_ + n)*T_ + k];
    else if (k < 200) v = se_emb[n*32 + (k - 168)];
    u16 hi = f2bf(v);
    Sh[r*232 + k] = hi; Sl[r*232 + k] = f2bf(v - bf2f(hi));
  }
  __syncthreads();
  const u16* Ah = Sh + (16*wv + (lane & 15))*232 + (lane >> 4)*8;
  const u16* Al = Sl + (16*wv + (lane & 15))*232 + (lane >> 4)*8;
  const u16* Bh = w1h + (lane & 15)*224 + (lane >> 4)*8;
  const u16* Bl = w1l + (lane & 15)*224 + (lane >> 4)*8;
  f32x4 hh[4], hl[4], lh[4];
  #pragma unroll
  for (int q = 0; q < 4; ++q){ hh[q]=(f32x4){0,0,0,0}; hl[q]=(f32x4){0,0,0,0}; lh[q]=(f32x4){0,0,0,0}; }
  #pragma unroll
  for (int kt = 0; kt < 7; ++kt){
    short8 ah = *(const short8*)(Ah + kt*32);
    short8 al = *(const short8*)(Al + kt*32);
    #pragma unroll
    for (int q = 0; q < 4; ++q){
      short8 bh = *(const short8*)(Bh + q*16*224 + kt*32);
      short8 bl = *(const short8*)(Bl + q*16*224 + kt*32);
      hh[q] = bmfma(ah, bh, hh[q]);
      hl[q] = bmfma(ah, bl, hl[q]);
      lh[q] = bmfma(al, bh, lh[q]);
    }
  }
  int mrow = 16*wv + (lane >> 4)*4;
  #pragma unroll
  for (int q = 0; q < 4; ++q){
    int g = q*16 + (lane & 15);
    float bv = b1[g];
    #pragma unroll
    for (int r = 0; r < 4; ++r){
      float v = eluf(hh[q][r] + hl[q][r] + lh[q][r] + bv);
      u16 hi = f2bf(v);
      Tlh[(mrow + r)*72 + g] = hi;
      Tll[(mrow + r)*72 + g] = f2bf(v - bf2f(hi));
    }
  }
  __syncthreads();
  const u16* A2h = Tlh + (16*wv + (lane & 15))*72 + (lane >> 4)*8;
  const u16* A2l = Tll + (16*wv + (lane & 15))*72 + (lane >> 4)*8;
  const u16* B2h = w2h + (lane & 15)*64 + (lane >> 4)*8;
  const u16* B2l = w2l + (lane & 15)*64 + (lane >> 4)*8;
  f32x4 ohh[4], ohl[4], olh[4];
  #pragma unroll
  for (int q = 0; q < 4; ++q){ ohh[q]=(f32x4){0,0,0,0}; ohl[q]=(f32x4){0,0,0,0}; olh[q]=(f32x4){0,0,0,0}; }
  #pragma unroll
  for (int kt = 0; kt < 2; ++kt){
    short8 a2h = *(const short8*)(A2h + kt*32);
    short8 a2l = *(const short8*)(A2l + kt*32);
    #pragma unroll
    for (int q = 0; q < 4; ++q){
      short8 b2h = *(const short8*)(B2h + q*16*64 + kt*32);
      short8 b2l = *(const short8*)(B2l + q*16*64 + kt*32);
      ohh[q] = bmfma(a2h, b2h, ohh[q]);
      ohl[q] = bmfma(a2h, b2l, ohl[q]);
      olh[q] = bmfma(a2l, b2h, olh[q]);
    }
  }
  #pragma unroll
  for (int q = 0; q < 4; ++q){
    int g = q*16 + (lane & 15);
    float bv = b2[g];
    #pragma unroll
    for (int r = 0; r < 4; ++r){
      int m = m0 + mrow + r;
      int b = m / N_, n = m - b*N_;
      X[((size_t)b*NT_ + n)*L_ + g] = ohh[q][r] + ohl[q][r] + olh[q][r] + bv;
    }
  }
}

// ---------------- te_in build (single bf16, 5376 x 768) ----------------
__global__ __launch_bounds__(256) void k_teinx_b(const float* __restrict__ x, u16* __restrict__ teB){
  __shared__ float tile[32][33];
  int b = blockIdx.z; int n0 = blockIdx.x*32, t0 = blockIdx.y*32;
  int tx = threadIdx.x & 31, ty = threadIdx.x >> 5;
  for (int i = ty; i < 32; i += 8){
    int n = n0 + i, t = t0 + tx;
    if (n < N_ && t < T_) tile[i][tx] = x[((size_t)b*N_ + n)*T_ + t];
  }
  __syncthreads();
  for (int i = ty; i < 32; i += 8){
    int t = t0 + i, n = n0 + tx;
    if (t < T_ && n < N_)
      teB[((size_t)b*T_ + t)*768 + n] = f2bf(tile[tx][i]);
  }
}
__global__ __launch_bounds__(256) void k_teinr_b(const float* __restrict__ mark, const float* __restrict__ te_emb,
                                                 u16* __restrict__ teB){
  int idx = blockIdx.x*256 + threadIdx.x;
  if (idx >= B_*T_*52) return;
  int c = idx % 52; int row = idx / 52; int b = row / T_, t = row % T_;
  float v = 0.f;
  if (c < 4) v = mark[((size_t)b*T_ + t)*4 + c];
  else if (c < 36) v = te_emb[t*32 + (c - 4)];
  teB[(size_t)row*768 + 716 + c] = f2bf(v);
}

// ---------------- te xw MFMA (single bf16): te_xw = te_in @ te_Wih^T + bih ----------------
__global__ __launch_bounds__(256) void k_texw(const u16* __restrict__ teB, const u16* __restrict__ wteB,
    const float* __restrict__ bih, float* __restrict__ xwte){
  int m0 = blockIdx.x*64, n0 = blockIdx.y*64;
  int tid = threadIdx.x, wv = tid >> 6, lane = tid & 63;
  const u16* Ah = teB + (size_t)(m0 + 16*wv + (lane & 15))*768 + (lane >> 4)*8;
  const u16* Bh = wteB + (size_t)(n0 + (lane & 15))*768 + (lane >> 4)*8;
  f32x4 hh[4];
  #pragma unroll
  for (int q = 0; q < 4; ++q) hh[q]=(f32x4){0,0,0,0};
  #pragma unroll 4
  for (int kt = 0; kt < 24; ++kt){
    short8 ah = *(const short8*)(Ah + kt*32);
    #pragma unroll
    for (int q = 0; q < 4; ++q)
      hh[q] = bmfma(ah, *(const short8*)(Bh + q*16*768 + kt*32), hh[q]);
  }
  int mb = m0 + 16*wv + (lane >> 4)*4;
  #pragma unroll
  for (int q = 0; q < 4; ++q){
    int g = n0 + q*16 + (lane & 15);
    float bv = bih[g];
    #pragma unroll
    for (int r = 0; r < 4; ++r)
      xwte[(size_t)(mb + r)*TE3_ + g] = hh[q][r] + bv;
  }
}

// ---------------- te GRU scan (ILP-split inner product) ----------------
__global__ __launch_bounds__(192) void k_te_scan(const float* __restrict__ xw, const float* __restrict__ Whh,
                 const float* __restrict__ bhh, float* __restrict__ X){
  int b = blockIdx.x; int tid = threadIdx.x;
  __shared__ float Wsh[TE3_*65];
  __shared__ float hs[64];
  __shared__ float gh[TE3_];
  for (int l = tid; l < TE3_*64; l += 192){ int j = l >> 6, f = l & 63; Wsh[j*65+f] = Whh[l]; }
  if (tid < 64) hs[tid] = 0.f;
  __syncthreads();
  for (int t = 0; t < T_; ++t){
    const float* xr = xw + ((size_t)b*T_ + t)*TE3_;
    float g0 = bhh[tid], g1 = 0.f, g2 = 0.f, g3 = 0.f;
    #pragma unroll
    for (int f = 0; f < 64; f += 4){
      g0 = fmaf(hs[f],   Wsh[tid*65+f],   g0);
      g1 = fmaf(hs[f+1], Wsh[tid*65+f+1], g1);
      g2 = fmaf(hs[f+2], Wsh[tid*65+f+2], g2);
      g3 = fmaf(hs[f+3], Wsh[tid*65+f+3], g3);
    }
    gh[tid] = (g0 + g1) + (g2 + g3);
    __syncthreads();
    if (tid < 64){
      float r = sigf(xr[tid] + gh[tid]);
      float z = sigf(xr[64+tid] + gh[64+tid]);
      float n = tanhf(xr[128+tid] + r*gh[128+tid]);
      float hn = (1.f - z)*n + z*hs[tid];
      hs[tid] = hn;
      X[((size_t)b*NT_ + N_ + t)*L_ + tid] = hn;
    }
    __syncthreads();
  }
}

// ---------------- X -> bf16 hi/lo (row-major + transposed) ----------------
__global__ __launch_bounds__(256) void k_xbf(const float* __restrict__ X,
                 u16* __restrict__ Xbh, u16* __restrict__ Xbl,
                 u16* __restrict__ XTh, u16* __restrict__ XTl){
  __shared__ u16 th[32][33], tl[32][33];
  int b = blockIdx.z, i0 = blockIdx.x*32, f0 = blockIdx.y*32;
  int tx = threadIdx.x & 31, ty = threadIdx.x >> 5;
  for (int rr = ty; rr < 32; rr += 8){
    int i = i0 + rr, f = f0 + tx;
    float v = (i < NT_) ? X[((size_t)b*NT_ + i)*L_ + f] : 0.f;
    u16 hi = f2bf(v);
    u16 lo = f2bf(v - bf2f(hi));
    th[rr][tx] = hi; tl[rr][tx] = lo;
    Xbh[((size_t)b*NTP + i)*L_ + f] = hi;
    Xbl[((size_t)b*NTP + i)*L_ + f] = lo;
  }
  __syncthreads();
  for (int rr = ty; rr < 32; rr += 8){
    XTh[((size_t)b*L_ + f0 + rr)*NTP + i0 + tx] = th[tx][rr];
    XTl[((size_t)b*L_ + f0 + rr)*NTP + i0 + tx] = tl[tx][rr];
  }
}

// ---------------- fused flash-GCN layer: Y = elu((adj@h)@W + b), adj computed in LDS ----------------
__global__ __launch_bounds__(256) void k_gcnf(
    const u16* __restrict__ Xbh, const u16* __restrict__ Xbl,
    const u16* __restrict__ hTh, const u16* __restrict__ hTl,
    const u16* __restrict__ WTh, const u16* __restrict__ WTl,
    const float* __restrict__ bias,
    float* __restrict__ Y, u16* __restrict__ YTh, u16* __restrict__ YTl){
  __shared__ u16 AJh[64*72], AJl[64*72];
  __shared__ u16 Tlh[64*72], Tll[64*72];
  int b = blockIdx.y, i0 = blockIdx.x*64;
  int tid = threadIdx.x, wv = tid >> 6, lane = tid & 63;
  const u16* XAh = Xbh + ((size_t)b*NTP + i0 + 16*wv + (lane & 15))*L_ + (lane >> 4)*8;
  const u16* XAl = Xbl + ((size_t)b*NTP + i0 + 16*wv + (lane & 15))*L_ + (lane >> 4)*8;
  const int ib = i0 + 16*wv + (lane >> 4)*4;
  const int mrow = 16*wv + (lane >> 4)*4;
  f32x4 thh[4], thl[4], tlh[4];
  #pragma unroll
  for (int q = 0; q < 4; ++q){ thh[q] = (f32x4){0,0,0,0}; thl[q] = (f32x4){0,0,0,0}; tlh[q] = (f32x4){0,0,0,0}; }
  for (int jt = 0; jt < 14; ++jt){
    int j0 = jt*64;
    {
      const u16* XBh = Xbh + ((size_t)b*NTP + j0 + (lane & 15))*L_ + (lane >> 4)*8;
      const u16* XBl = Xbl + ((size_t)b*NTP + j0 + (lane & 15))*L_ + (lane >> 4)*8;
      f32x4 chh[4], chl[4], clh[4];
      #pragma unroll
      for (int q = 0; q < 4; ++q){ chh[q] = (f32x4){0,0,0,0}; chl[q] = (f32x4){0,0,0,0}; clh[q] = (f32x4){0,0,0,0}; }
      #pragma unroll
      for (int kt = 0; kt < 2; ++kt){
        short8 ah = *(const short8*)(XAh + kt*32);
        short8 al = *(const short8*)(XAl + kt*32);
        #pragma unroll
        for (int q = 0; q < 4; ++q){
          short8 bh = *(const short8*)(XBh + q*16*L_ + kt*32);
          short8 bl = *(const short8*)(XBl + q*16*L_ + kt*32);
          chh[q] = bmfma(ah, bh, chh[q]);
          chl[q] = bmfma(ah, bl, chl[q]);
          clh[q] = bmfma(al, bh, clh[q]);
        }
      }
      int jb = j0 + (lane & 15);
      #pragma unroll
      for (int q = 0; q < 4; ++q){
        int j = jb + q*16;
        #pragma unroll
        for (int r = 0; r < 4; ++r){
          int i = ib + r;
          u16 hi = 0, lo = 0;
          if (i < NT_ && j < NT_){
            float v = tanhf(fmaxf(chh[q][r] + chl[q][r] + clh[q][r], 0.f) + (i == j ? 1.f : 0.f));
            hi = f2bf(v); lo = f2bf(v - bf2f(hi));
          }
          AJh[(mrow + r)*72 + q*16 + (lane & 15)] = hi;
          AJl[(mrow + r)*72 + q*16 + (lane & 15)] = lo;
        }
      }
    }
    __syncthreads();
    {
      const u16* A1h = AJh + (16*wv + (lane & 15))*72 + (lane >> 4)*8;
      const u16* A1l = AJl + (16*wv + (lane & 15))*72 + (lane >> 4)*8;
      const u16* B1h = hTh + ((size_t)b*L_ + (lane & 15))*NTP + j0 + (lane >> 4)*8;
      const u16* B1l = hTl + ((size_t)b*L_ + (lane & 15))*NTP + j0 + (lane >> 4)*8;
      #pragma unroll
      for (int kt = 0; kt < 2; ++kt){
        short8 ah = *(const short8*)(A1h + kt*32);
        short8 al = *(const short8*)(A1l + kt*32);
        #pragma unroll
        for (int q = 0; q < 4; ++q){
          short8 bh = *(const short8*)(B1h + q*16*NTP + kt*32);
          short8 bl = *(const short8*)(B1l + q*16*NTP + kt*32);
          thh[q] = bmfma(ah, bh, thh[q]);
          thl[q] = bmfma(ah, bl, thl[q]);
          tlh[q] = bmfma(al, bh, tlh[q]);
        }
      }
    }
    __syncthreads();
  }
  #pragma unroll
  for (int q = 0; q < 4; ++q)
    #pragma unroll
    for (int r = 0; r < 4; ++r){
      float v = thh[q][r] + thl[q][r] + tlh[q][r];
      u16 hi = f2bf(v);
      Tlh[(mrow + r)*72 + q*16 + (lane & 15)] = hi;
      Tll[(mrow + r)*72 + q*16 + (lane & 15)] = f2bf(v - bf2f(hi));
    }
  __syncthreads();
  const u16* A2h = Tlh + (16*wv + (lane & 15))*72 + (lane >> 4)*8;
  const u16* A2l = Tll + (16*wv + (lane & 15))*72 + (lane >> 4)*8;
  const u16* B2h = WTh + (lane & 15)*L_ + (lane >> 4)*8;
  const u16* B2l = WTl + (lane & 15)*L_ + (lane >> 4)*8;
  f32x4 ohh[4], ohl[4], olh[4];
  #pragma unroll
  for (int q = 0; q < 4; ++q){ ohh[q] = (f32x4){0,0,0,0}; ohl[q] = (f32x4){0,0,0,0}; olh[q] = (f32x4){0,0,0,0}; }
  #pragma unroll
  for (int kt = 0; kt < 2; ++kt){
    short8 a2h = *(const short8*)(A2h + kt*32);
    short8 a2l = *(const short8*)(A2l + kt*32);
    #pragma unroll
    for (int q = 0; q < 4; ++q){
      short8 b2h = *(const short8*)(B2h + q*16*L_ + kt*32);
      short8 b2l = *(const short8*)(B2l + q*16*L_ + kt*32);
      ohh[q] = bmfma(a2h, b2h, ohh[q]);
      ohl[q] = bmfma(a2h, b2l, ohl[q]);
      olh[q] = bmfma(a2l, b2h, olh[q]);
    }
  }
  __syncthreads();
  #pragma unroll
  for (int q = 0; q < 4; ++q){
    int g = q*16 + (lane & 15);
    float bv = bias[g];
    #pragma unroll
    for (int r = 0; r < 4; ++r){
      int i = i0 + mrow + r;
      float v = eluf(ohh[q][r] + ohl[q][r] + olh[q][r] + bv);
      if (i < NT_ && Y) Y[((size_t)b*NT_ + i)*L_ + g] = v;
      u16 hi = 0, lo = 0;
      if (i < NT_){ hi = f2bf(v); lo = f2bf(v - bf2f(hi)); }
      Tlh[g*72 + mrow + r] = hi;
      Tll[g*72 + mrow + r] = lo;
    }
  }
  __syncthreads();
  {
    int g = tid >> 2, c = tid & 3;
    uint4* dh = (uint4*)(YTh + ((size_t)b*L_ + g)*NTP + i0 + c*16);
    uint4* dl = (uint4*)(YTl + ((size_t)b*L_ + g)*NTP + i0 + c*16);
    const uint4* sh = (const uint4*)(Tlh + g*72 + c*16);
    const uint4* sl = (const uint4*)(Tll + g*72 + c*16);
    dh[0] = sh[0]; dh[1] = sh[1];
    dl[0] = sl[0]; dl[1] = sl[1];
  }
}

// ---------------- merged back-end: blocks [0,358) fr path; [358,3214) xw projection ----------------
__global__ __launch_bounds__(256) void k_back(const float* __restrict__ X,
    const u16* __restrict__ w1h, const u16* __restrict__ w1l,
    const u16* __restrict__ w2h, const u16* __restrict__ w2l,
    const float* __restrict__ b1, const float* __restrict__ b2, float* __restrict__ nout8,
    const u16* __restrict__ WihB, const float* __restrict__ bih, u16* __restrict__ xwB){
  __shared__ u16 Sh[64*72], Sl[64*72];
  __shared__ u16 T1h[64*192], T1l[64*192];
  __shared__ u16 B2hl[16*192], B2ll[16*192];
  int tid = threadIdx.x, wv = tid >> 6, lane = tid & 63;
  if (blockIdx.x >= 358){
    // ---- xw = Xt @ Wih^T + bih (reads X fp32 directly, bf16 out) ----
    int r = blockIdx.x - 358;
    int m0 = (r % 84)*64, n0 = (r / 84)*64;
    int am = m0 + 16*wv + (lane & 15);
    int t = am >> 5, b = am & 31;
    const float* Arow = X + ((size_t)b*NT_ + N_ + t)*L_ + (lane >> 4)*8;
    const u16* Bb = WihB + (size_t)(n0 + (lane & 15))*L_ + (lane >> 4)*8;
    f32x4 c0={0,0,0,0}, c1={0,0,0,0}, c2={0,0,0,0}, c3={0,0,0,0};
    #pragma unroll
    for (int kt = 0; kt < 2; ++kt){
      f32x4 f0 = *(const f32x4*)(Arow + kt*32);
      f32x4 f1 = *(const f32x4*)(Arow + kt*32 + 4);
      short8 a;
      a[0]=(short)f2bf(f0[0]); a[1]=(short)f2bf(f0[1]); a[2]=(short)f2bf(f0[2]); a[3]=(short)f2bf(f0[3]);
      a[4]=(short)f2bf(f1[0]); a[5]=(short)f2bf(f1[1]); a[6]=(short)f2bf(f1[2]); a[7]=(short)f2bf(f1[3]);
      c0 = bmfma(a, *(const short8*)(Bb + kt*32), c0);
      c1 = bmfma(a, *(const short8*)(Bb + 16*L_ + kt*32), c1);
      c2 = bmfma(a, *(const short8*)(Bb + 32*L_ + kt*32), c2);
      c3 = bmfma(a, *(const short8*)(Bb + 48*L_ + kt*32), c3);
    }
    int mb = m0 + 16*wv + (lane >> 4)*4;
    int nb = n0 + (lane & 15);
    f32x4 cc[4] = {c0, c1, c2, c3};
    #pragma unroll
    for (int q = 0; q < 4; ++q){
      int n = nb + q*16;
      if (n >= TR3_) continue;
      float bv = bih[n];
      #pragma unroll
      for (int rr = 0; rr < 4; ++rr)
        xwB[(size_t)(mb + rr)*TR3_ + n] = f2bf(cc[q][rr] + bv);
    }
    return;
  }
  // ---- fr path ----
  int m0 = blockIdx.x*64;
  for (int o = tid; o < 768; o += 256){
    ((u64*)B2hl)[o] = ((const u64*)w2h)[o];
    ((u64*)B2ll)[o] = ((const u64*)w2l)[o];
  }
  for (int o = tid; o < 1024; o += 256){
    int rr = o >> 4, cc = o & 15;
    T1h[rr*192 + 176 + cc] = 0; T1l[rr*192 + 176 + cc] = 0;
  }
  for (int o = tid; o < 4096; o += 256){
    int r = o >> 6, k = o & 63;
    int m = m0 + r; int ab = m / N_, an = m - ab*N_;
    float v = X[((size_t)ab*NT_ + an)*L_ + k];
    u16 hi = f2bf(v);
    Sh[r*72 + k] = hi; Sl[r*72 + k] = f2bf(v - bf2f(hi));
  }
  __syncthreads();
  const u16* Ah = Sh + (16*wv + (lane & 15))*72 + (lane >> 4)*8;
  const u16* Al = Sl + (16*wv + (lane & 15))*72 + (lane >> 4)*8;
  int mrow = 16*wv + (lane >> 4)*4;
  for (int tile = 0; tile < 11; ++tile){
    const u16* Bh = w1h + (tile*16 + (lane & 15))*64 + (lane >> 4)*8;
    const u16* Bl = w1l + (tile*16 + (lane & 15))*64 + (lane >> 4)*8;
    f32x4 shh={0,0,0,0}, shl={0,0,0,0}, slh={0,0,0,0};
    #pragma unroll
    for (int kt = 0; kt < 2; ++kt){
      short8 ah = *(const short8*)(Ah + kt*32);
      short8 al = *(const short8*)(Al + kt*32);
      short8 bh = *(const short8*)(Bh + kt*32);
      short8 bl = *(const short8*)(Bl + kt*32);
      shh = bmfma(ah, bh, shh);
      shl = bmfma(ah, bl, shl);
      slh = bmfma(al, bh, slh);
    }
    int col = tile*16 + (lane & 15);
    float bb = (col < 168) ? b1[col] : 0.f;
    #pragma unroll
    for (int r = 0; r < 4; ++r){
      float v = (col < 168) ? eluf(shh[r] + shl[r] + slh[r] + bb) : 0.f;
      u16 hi = f2bf(v);
      T1h[(mrow + r)*192 + col] = hi;
      T1l[(mrow + r)*192 + col] = f2bf(v - bf2f(hi));
    }
  }
  __syncthreads();
  const u16* A2h = T1h + (16*wv + (lane & 15))*192 + (lane >> 4)*8;
  const u16* A2l = T1l + (16*wv + (lane & 15))*192 + (lane >> 4)*8;
  const u16* Bh2 = B2hl + (lane & 15)*192 + (lane >> 4)*8;
  const u16* Bl2 = B2ll + (lane & 15)*192 + (lane >> 4)*8;
  f32x4 ohh={0,0,0,0}, ohl={0,0,0,0}, olh={0,0,0,0};
  #pragma unroll
  for (int kt = 0; kt < 6; ++kt){
    short8 a2h = *(const short8*)(A2h + kt*32);
    short8 a2l = *(const short8*)(A2l + kt*32);
    short8 b2h = *(const short8*)(Bh2 + kt*32);
    short8 b2l = *(const short8*)(Bl2 + kt*32);
    ohh = bmfma(a2h, b2h, ohh);
    ohl = bmfma(a2h, b2l, ohl);
    olh = bmfma(a2l, b2h, olh);
  }
  int c = lane & 15;
  if (c < 8){
    float bv = b2[160 + c];
    #pragma unroll
    for (int r = 0; r < 4; ++r){
      int m = m0 + mrow + r;
      nout8[(size_t)m*8 + c] = ohh[r] + ohl[r] + olh[r] + bv;
    }
  }
}

// ---------------- persistent MFMA tr-GRU scan (bf16 xw, entry-top poll) ----------------
__global__ __launch_bounds__(192) void k_tr_scan(
    const u16* __restrict__ WhhB,  // (2148, 716) bf16
    const float* __restrict__ bhh,
    const u16* __restrict__ xwB,   // (5376, 2148) bf16, incl. bih
    u16* __restrict__ hb0, u16* __restrict__ hb1,  // (32, 720) bf16
    float* __restrict__ tout8,
    int* __restrict__ flags){
  __shared__ u16 w_lds[48*WSTR];
  __shared__ u16 h_lds[16*WSTR];
  __shared__ float g_lds[2*256];
  __shared__ u64 xw_ldsq[2][192];   // 16 rows x 12 u64 (48 bf16) per buffer
  const int tid = threadIdx.x;
  const int wv = tid >> 6, lane = tid & 63;
  const int cb = blockIdx.x >> 1, hhalf = blockIdx.x & 1;
  const int k0 = cb*16, b0 = hhalf*16;
  const int prow = tid / 12, pc = tid % 12;
  const int pg = pc >> 2, pko = (pc & 3)*4;

  xw_ldsq[0][prow*12 + pc] =
    *(const u64*)(xwB + (size_t)(b0 + prow)*TR3_ + pg*TRH_ + k0 + pko);
  for (int o = tid; o < 16*24; o += 192){
    int n = o / 24, c = o - n*24;
    h_lds[n*WSTR + 720 + c] = 0;
  }
  for (int r = 0; r < 48; ++r){
    int g = r >> 4, m = r & 15, k = k0 + m;
    bool kv = (k < TRH_);
    const uint2* src = (const uint2*)(WhhB + (size_t)(g*TRH_ + (kv ? k : 0))*TRH_);
    uint2* dst = (uint2*)(w_lds + r*WSTR);
    uint2 zz; zz.x = 0; zz.y = 0;
    for (int o = tid; o < 186; o += 192)
      dst[o] = (kv && o < 179) ? src[o] : zz;
  }
  const u16* arow = w_lds + (size_t)(wv*16 + (lane & 15))*WSTR + (lane >> 4)*8;
  const u16* brow = h_lds + (size_t)(lane & 15)*WSTR + (lane >> 4)*8;

  const int mb = (lane >> 4)*4;
  const int kx = k0 + mb;
  const bool kval = (kx < TRH_);
  const int bx = b0 + (lane & 15);
  f32x4 hp = {0.f, 0.f, 0.f, 0.f};
  f32x4 br4 = {0,0,0,0}, bz4 = {0,0,0,0}, bn4 = {0,0,0,0};
  if (wv == 0){
    int kc = kval ? kx : 0;
    br4 = *(const f32x4*)(bhh + kc);
    bz4 = *(const f32x4*)(bhh + TRH_ + kc);
    bn4 = *(const f32x4*)(bhh + 2*TRH_ + kc);
  }
  const int sn = tid / 12, sj = tid % 12;
  __syncthreads();

  for (int t = 0; t < T_; ++t){
    const u16* hcur = (t & 1) ? hb1 : hb0;
    u16* hnxt = (t & 1) ? hb0 : hb1;
    if (tid < 45){
      const int* fp = flags + (tid*2 + hhalf)*16;
      while (__hip_atomic_load(fp, __ATOMIC_RELAXED, __HIP_MEMORY_SCOPE_AGENT) < t){}
    }
    __syncthreads();
    // stage h: issue all 15 loads (independent), drain once, then LDS writes
    {
      const u64* srow = (const u64*)(hcur + (size_t)(b0 + sn)*HSTR) + sj;
      u64 v0  = __hip_atomic_load(srow +   0, __ATOMIC_RELAXED, __HIP_MEMORY_SCOPE_AGENT);
      u64 v1  = __hip_atomic_load(srow +  12, __ATOMIC_RELAXED, __HIP_MEMORY_SCOPE_AGENT);
      u64 v2  = __hip_atomic_load(srow +  24, __ATOMIC_RELAXED, __HIP_MEMORY_SCOPE_AGENT);
      u64 v3  = __hip_atomic_load(srow +  36, __ATOMIC_RELAXED, __HIP_MEMORY_SCOPE_AGENT);
      u64 v4  = __hip_atomic_load(srow +  48, __ATOMIC_RELAXED, __HIP_MEMORY_SCOPE_AGENT);
      u64 v5  = __hip_atomic_load(srow +  60, __ATOMIC_RELAXED, __HIP_MEMORY_SCOPE_AGENT);
      u64 v6  = __hip_atomic_load(srow +  72, __ATOMIC_RELAXED, __HIP_MEMORY_SCOPE_AGENT);
      u64 v7  = __hip_atomic_load(srow +  84, __ATOMIC_RELAXED, __HIP_MEMORY_SCOPE_AGENT);
      u64 v8  = __hip_atomic_load(srow +  96, __ATOMIC_RELAXED, __HIP_MEMORY_SCOPE_AGENT);
      u64 v9  = __hip_atomic_load(srow + 108, __ATOMIC_RELAXED, __HIP_MEMORY_SCOPE_AGENT);
      u64 v10 = __hip_atomic_load(srow + 120, __ATOMIC_RELAXED, __HIP_MEMORY_SCOPE_AGENT);
      u64 v11 = __hip_atomic_load(srow + 132, __ATOMIC_RELAXED, __HIP_MEMORY_SCOPE_AGENT);
      u64 v12 = __hip_atomic_load(srow + 144, __ATOMIC_RELAXED, __HIP_MEMORY_SCOPE_AGENT);
      u64 v13 = __hip_atomic_load(srow + 156, __ATOMIC_RELAXED, __HIP_MEMORY_SCOPE_AGENT);
      u64 v14 = __hip_atomic_load(srow + 168, __ATOMIC_RELAXED, __HIP_MEMORY_SCOPE_AGENT);
      u64* d = (u64*)(h_lds + sn*WSTR) + sj;
      d[0]   = v0;   d[12]  = v1;   d[24]  = v2;   d[36]  = v3;
      d[48]  = v4;   d[60]  = v5;   d[72]  = v6;   d[84]  = v7;
      d[96]  = v8;   d[108] = v9;   d[120] = v10;  d[132] = v11;
      d[144] = v12;  d[156] = v13;  d[168] = v14;
    }
    __syncthreads();
    // early-issue xw prefetch for t+1 (register-buffered; LDS write at loop end)
    u64 pf = 0;
    const bool haspf = (t + 1 < T_);
    if (haspf)
      pf = *(const u64*)(xwB + (size_t)((t+1)*32 + b0 + prow)*TR3_ + pg*TRH_ + k0 + pko);
    f32x4 a0={0,0,0,0}, a1={0,0,0,0}, a2={0,0,0,0}, a3={0,0,0,0};
    for (int kt = 0; kt < 20; kt += 4){
      a0 = bmfma(*(const short8*)(arow + kt*32),     *(const short8*)(brow + kt*32),     a0);
      a1 = bmfma(*(const short8*)(arow + (kt+1)*32), *(const short8*)(brow + (kt+1)*32), a1);
      a2 = bmfma(*(const short8*)(arow + (kt+2)*32), *(const short8*)(brow + (kt+2)*32), a2);
      a3 = bmfma(*(const short8*)(arow + (kt+3)*32), *(const short8*)(brow + (kt+3)*32), a3);
    }
    a0 = bmfma(*(const short8*)(arow + 20*32), *(const short8*)(brow + 20*32), a0);
    a1 = bmfma(*(const short8*)(arow + 21*32), *(const short8*)(brow + 21*32), a1);
    a2 = bmfma(*(const short8*)(arow + 22*32), *(const short8*)(brow + 22*32), a2);
    f32x4 acc = (a0 + a1) + (a2 + a3);
    if (wv){
      #pragma unroll
      for (int r = 0; r < 4; ++r) g_lds[(wv-1)*256 + lane*4 + r] = acc[r];
    }
    __syncthreads();
    if (wv == 0){
      if (kval){
        const u16* xb = ((const u16*)&xw_ldsq[t & 1][0]) + (lane & 15)*48;
        float hnew[4];
        #pragma unroll
        for (int r = 0; r < 4; ++r){
          float rg = sigf(bf2f(xb[mb + r]) + acc[r] + br4[r]);
          float zg = sigf(bf2f(xb[16 + mb + r]) + g_lds[lane*4 + r] + bz4[r]);
          float ng = tanhf(bf2f(xb[32 + mb + r]) + rg*(g_lds[256 + lane*4 + r] + bn4[r]));
          hnew[r] = (1.f - zg)*ng + zg*hp[r];
          hp[r] = hnew[r];
        }
        u64 pk = (u64)((unsigned)f2bf(hnew[0]) | ((unsigned)f2bf(hnew[1]) << 16))
               | ((u64)((unsigned)f2bf(hnew[2]) | ((unsigned)f2bf(hnew[3]) << 16)) << 32);
        __hip_atomic_store((u64*)(hnxt + (size_t)bx*HSTR + kx), pk,
                           __ATOMIC_RELAXED, __HIP_MEMORY_SCOPE_AGENT);
        if (t >= 160){
          #pragma unroll
          for (int r = 0; r < 4; ++r)
            tout8[(size_t)(bx*TRH_ + kx + r)*8 + (t - 160)] = hnew[r];
        }
      }
      asm volatile("s_waitcnt vmcnt(0)" ::: "memory");
      if (lane == 0)
        __hip_atomic_store(flags + blockIdx.x*16, t + 1,
                           __ATOMIC_RELAXED, __HIP_MEMORY_SCOPE_AGENT);
    }
    if (haspf) xw_ldsq[(t + 1) & 1][prow*12 + pc] = pf;
  }
}

// ---------------- fused TCN tail ----------------
__global__ __launch_bounds__(256) void k_tcn(const float* __restrict__ nout8, const float* __restrict__ tout8,
                 const float* __restrict__ x,
                 const float* __restrict__ W0, const float* __restrict__ b0,
                 const float* __restrict__ W1, const float* __restrict__ b1,
                 const float* __restrict__ W2, const float* __restrict__ b2,
                 const float* __restrict__ oW, const float* __restrict__ ob,
                 float* __restrict__ out){
  __shared__ float w0s[96], b0s[16], w1s[512], b1s[16], w2s[512], b2s[16], ows[16], obs;
  int tid = threadIdx.x;
  for (int l = tid; l < 96; l += 256) w0s[l] = W0[l];
  for (int l = tid; l < 512; l += 256){ w1s[l] = W1[l]; w2s[l] = W2[l]; }
  if (tid < 16){ b0s[tid]=b0[tid]; b1s[tid]=b1[tid]; b2s[tid]=b2[tid]; ows[tid]=oW[tid]; }
  if (tid == 0) obs = ob[0];
  __syncthreads();
  int idx = blockIdx.x*256 + tid;
  if (idx >= B_*N_) return;
  int b = idx / N_, n = idx % N_;
  float s0[8], s1[8], s2[8];
  #pragma unroll
  for (int i = 0; i < 8; ++i){
    s0[i] = nout8[(size_t)idx*8 + i];
    s1[i] = tout8[(size_t)idx*8 + i];
    s2[i] = x[((size_t)b*N_ + n)*T_ + 160 + i];
  }
  float h1[16][4];
  #pragma unroll
  for (int c = 0; c < 16; ++c)
    #pragma unroll
    for (int q = 0; q < 4; ++q){
      int tt = 2*q + 1;
      float v = b0s[c]
        + w0s[c*6+0]*s0[tt-1] + w0s[c*6+1]*s0[tt]
        + w0s[c*6+2]*s1[tt-1] + w0s[c*6+3]*s1[tt]
        + w0s[c*6+4]*s2[tt-1] + w0s[c*6+5]*s2[tt];
      h1[c][q] = eluf(v);
    }
  float h2[16][2];
  #pragma unroll
  for (int c = 0; c < 16; ++c){
    float v3 = b1s[c], v7 = b1s[c];
    #pragma unroll
    for (int i2 = 0; i2 < 16; ++i2){
      v3 += w1s[c*32+i2*2]*h1[i2][0] + w1s[c*32+i2*2+1]*h1[i2][1];
      v7 += w1s[c*32+i2*2]*h1[i2][2] + w1s[c*32+i2*2+1]*h1[i2][3];
    }
    h2[c][0] = eluf(v3); h2[c][1] = eluf(v7);
  }
  float o = obs;
  #pragma unroll
  for (int c = 0; c < 16; ++c){
    float v = b2s[c];
    #pragma unroll
    for (int i2 = 0; i2 < 16; ++i2)
      v += w2s[c*32+i2*2]*h2[i2][0] + w2s[c*32+i2*2+1]*h2[i2][1];
    o += ows[c]*eluf(v);
  }
  out[idx] = o;
}

extern "C" void kernel_launch(void* const* d_in, const int* in_sizes, int n_in,
                              void* d_out, int out_size, void* d_ws, size_t ws_size,
                              hipStream_t stream){
  const float* x       = (const float*)d_in[0];
  const float* mark    = (const float*)d_in[1];
  const float* se_emb  = (const float*)d_in[2];
  const float* se_W1   = (const float*)d_in[3];
  const float* se_b1   = (const float*)d_in[4];
  const float* se_W2   = (const float*)d_in[5];
  const float* se_b2   = (const float*)d_in[6];
  const float* te_emb  = (const float*)d_in[7];
  const float* te_Wih  = (const float*)d_in[8];
  const float* te_Whh  = (const float*)d_in[9];
  const float* te_bih  = (const float*)d_in[10];
  const float* te_bhh  = (const float*)d_in[11];
  const float* gcn_W   = (const float*)d_in[12];
  const float* gcn_b   = (const float*)d_in[13];
  const float* fr_W1   = (const float*)d_in[14];
  const float* fr_b1   = (const float*)d_in[15];
  const float* fr_W2   = (const float*)d_in[16];
  const float* fr_b2   = (const float*)d_in[17];
  const float* tr_Wih  = (const float*)d_in[18];
  const float* tr_Whh  = (const float*)d_in[19];
  const float* tr_bih  = (const float*)d_in[20];
  const float* tr_bhh  = (const float*)d_in[21];
  const float* tcn_W0  = (const float*)d_in[22];
  const float* tcn_b0  = (const float*)d_in[23];
  const float* tcn_W1  = (const float*)d_in[24];
  const float* tcn_b1  = (const float*)d_in[25];
  const float* tcn_W2  = (const float*)d_in[26];
  const float* tcn_b2  = (const float*)d_in[27];
  const float* out_W   = (const float*)d_in[28];
  const float* out_b   = (const float*)d_in[29];
  float* out = (float*)d_out;
  (void)in_sizes; (void)n_in; (void)out_size; (void)ws_size;

  char* ws = (char*)d_ws;
  size_t off = 0;
  auto alloc = [&](size_t bytes)->void*{
    void* p = (void*)(ws + off); off += (bytes + 255) & ~(size_t)255; return p; };
  float* X       = (float*)alloc((size_t)B_*NT_*L_*4);
  u16*   teinB   = (u16*)  alloc((size_t)B_*T_*768*2);
  float* te_xw   = (float*)alloc((size_t)B_*T_*TE3_*4);
  u16*   xwB     = (u16*)  alloc((size_t)B_*T_*TR3_*2);
  u16*   WihB    = (u16*)  alloc((size_t)TR3P*L_*2);
  u16*   WhhB    = (u16*)  alloc((size_t)TR3_*TRH_*2);
  u16*   Xbh     = (u16*)  alloc((size_t)B_*NTP*L_*2);
  u16*   Xbl     = (u16*)  alloc((size_t)B_*NTP*L_*2);
  u16*   hTah    = (u16*)  alloc((size_t)B_*L_*NTP*2);
  u16*   hTal    = (u16*)  alloc((size_t)B_*L_*NTP*2);
  u16*   hTbh    = (u16*)  alloc((size_t)B_*L_*NTP*2);
  u16*   hTbl    = (u16*)  alloc((size_t)B_*L_*NTP*2);
  u16*   WTh     = (u16*)  alloc((size_t)4*4096*2);
  u16*   WTl     = (u16*)  alloc((size_t)4*4096*2);
  u16*   w1seh   = (u16*)  alloc((size_t)64*224*2);
  u16*   w1sel   = (u16*)  alloc((size_t)64*224*2);
  u16*   w2seh   = (u16*)  alloc((size_t)4096*2);
  u16*   w2sel   = (u16*)  alloc((size_t)4096*2);
  u16*   w1frh   = (u16*)  alloc((size_t)176*64*2);
  u16*   w1frl   = (u16*)  alloc((size_t)176*64*2);
  u16*   w2frh   = (u16*)  alloc((size_t)16*192*2);
  u16*   w2frl   = (u16*)  alloc((size_t)16*192*2);
  u16*   wteB    = (u16*)  alloc((size_t)192*768*2);
  u16*   hb0     = (u16*)  alloc((size_t)B_*HSTR*2);      // contiguous hb0|hb1|flags
  u16*   hb1     = (u16*)  alloc((size_t)B_*HSTR*2);
  int*   flags   = (int*)  alloc(8192);
  float* nout8   = (float*)alloc((size_t)B_*N_*8*4);
  float* tout8   = (float*)alloc((size_t)B_*N_*8*4);

  hipMemsetAsync(hb0, 0, (size_t)B_*HSTR*2*2 + 8192, stream);

  // merged weight prep
  k_prep<<<2628, 256, 0, stream>>>(tr_Whh, WhhB, tr_Wih, WihB,
      gcn_W, se_W1, se_W2, fr_W1, fr_W2, te_Wih,
      WTh, WTl, w1seh, w1sel, w2seh, w2sel, w1frh, w1frl, w2frh, w2frl, wteB);
  // SE path (fused staging + MFMA hi/lo)
  k_sem<<<358, 256, 0, stream>>>(x, se_emb, w1seh, w1sel, w2seh, w2sel, se_b1, se_b2, X);
  // te path (single bf16 projection + LDS scan)
  k_teinx_b<<<dim3(23,6,B_), 256, 0, stream>>>(x, teinB);
  k_teinr_b<<<(B_*T_*52 + 255)/256, 256, 0, stream>>>(mark, te_emb, teinB);
  k_texw<<<dim3(84,3), 256, 0, stream>>>(teinB, wteB, te_bih, te_xw);
  k_te_scan<<<B_, 192, 0, stream>>>(te_xw, te_Whh, te_bhh, X);
  // GCN (fused flash-GCN, adj in LDS)
  for (int i = 0; i < 2; ++i){
    k_xbf<<<dim3(28,2,B_),256,0,stream>>>(X, Xbh, Xbl, hTah, hTal);
    k_gcnf<<<dim3(14,B_),256,0,stream>>>(Xbh, Xbl, hTah, hTal,
        WTh + (i*2+0)*4096, WTl + (i*2+0)*4096, gcn_b + (i*2+0)*64, nullptr, hTbh, hTbl);
    k_gcnf<<<dim3(14,B_),256,0,stream>>>(Xbh, Xbl, hTbh, hTbl,
        WTh + (i*2+1)*4096, WTl + (i*2+1)*4096, gcn_b + (i*2+1)*64, X, hTah, hTal);
  }
  // merged back-end: fr path + tr input projection (both depend only on final X)
  k_back<<<358 + 84*34, 256, 0, stream>>>(X, w1frh, w1frl, w2frh, w2frl, fr_b1, fr_b2, nout8,
      WihB, tr_bih, xwB);
  // persistent tr-GRU scan
  k_tr_scan<<<TRBLKS,192,0,stream>>>(WhhB, tr_bhh, xwB, hb0, hb1, tout8, flags);
  // fused TCN tail
  k_tcn<<<(B_*N_+255)/256,256,0,stream>>>(nout8, tout8, x,
      tcn_W0, tcn_b0, tcn_W1, tcn_b1, tcn_W2, tcn_b2, out_W, out_b, out);
}

// Round 15
// 1393.382 us; speedup vs baseline: 1.0395x; 1.0184x over previous
//
#include <hip/hip_runtime.h>

#define B_   32
#define N_   716
#define T_   168
#define L_   64
#define NT_  884     // N + T
#define NTP  896     // padded NT for bf16 tiles
#define TE3_ 192     // 3*L
#define TRH_ 716     // tr hidden
#define TR3_ 2148    // 3*TRH
#define TR3P 2176    // padded
#define WSTR 744     // padded bf16 row stride in LDS
#define HSTR 720     // padded bf16 row stride of global h buffers
#define TRBLKS 90    // 45 k-slices x 2 batch halves

typedef unsigned short u16;
typedef unsigned long long u64;
typedef __attribute__((ext_vector_type(8))) short short8;
typedef __attribute__((ext_vector_type(4))) float f32x4;

static __device__ __forceinline__ float eluf(float x){ return x > 0.f ? x : expm1f(x); }
static __device__ __forceinline__ float sigf(float x){ return 1.f/(1.f+expf(-x)); }
static __device__ __forceinline__ u16 f2bf(float f){
  unsigned u = __float_as_uint(f);
  unsigned r = (u + 0x7fffu + ((u >> 16) & 1u)) >> 16;
  return (u16)r;
}
static __device__ __forceinline__ float bf2f(u16 h){
  return __uint_as_float(((unsigned)h) << 16);
}
static __device__ __forceinline__ f32x4 bmfma(short8 a, short8 b, f32x4 c){
  return __builtin_amdgcn_mfma_f32_16x16x32_bf16(a, b, c, 0, 0, 0);
}

// ---------------- merged front-end: weight prep + te_in build ONLY ----------------
// (NO intra-launch producer->consumer deps: every block reads only kernel inputs.)
// blocks [0,2628): weight prep ; [2628,7044): te_in x-transpose ; [7044,8136): te_in rest
__global__ __launch_bounds__(256) void k_front(
    const float* __restrict__ x,
    const float* __restrict__ mark, const float* __restrict__ te_emb,
    const float* __restrict__ whh, u16* __restrict__ WhhB,
    const float* __restrict__ wih, u16* __restrict__ WihB,
    const float* __restrict__ gW, const float* __restrict__ sW1, const float* __restrict__ sW2,
    const float* __restrict__ fW1, const float* __restrict__ fW2, const float* __restrict__ tW,
    u16* __restrict__ WTh, u16* __restrict__ WTl,
    u16* __restrict__ w1seh, u16* __restrict__ w1sel, u16* __restrict__ w2seh, u16* __restrict__ w2sel,
    u16* __restrict__ w1frh, u16* __restrict__ w1frl, u16* __restrict__ w2frh, u16* __restrict__ w2frl,
    u16* __restrict__ wteB, u16* __restrict__ teB){
  __shared__ float tile[32][33];
  int bid = blockIdx.x, tid = threadIdx.x;
  if (bid < 2628){
    if (bid < 1502){
      int i = bid*256 + tid;
      if (i < TR3_*TRH_/4){
        f32x4 v = *(const f32x4*)(whh + (size_t)i*4);
        uint2 p;
        p.x = (unsigned)f2bf(v[0]) | ((unsigned)f2bf(v[1])<<16);
        p.y = (unsigned)f2bf(v[2]) | ((unsigned)f2bf(v[3])<<16);
        *(uint2*)(WhhB + (size_t)i*4) = p;
      }
    } else if (bid < 2046){
      int idx = (bid - 1502)*256 + tid;
      int r = idx >> 6;
      WihB[idx] = (r < TR3_) ? f2bf(wih[idx]) : (u16)0;
    } else if (bid < 2050){
      int l = bid - 2046;
      for (int e = tid; e < 4096; e += 256){
        int g = e >> 6, f = e & 63;
        float v = gW[(size_t)l*4096 + f*64 + g];
        u16 hi = f2bf(v);
        WTh[(size_t)l*4096 + e] = hi;
        WTl[(size_t)l*4096 + e] = f2bf(v - bf2f(hi));
      }
    } else if (bid == 2050){
      for (int e = tid; e < 64*224; e += 256){
        int g = e / 224, k = e % 224;
        float v = (k < 200) ? sW1[k*64 + g] : 0.f;
        u16 hi = f2bf(v); w1seh[e] = hi; w1sel[e] = f2bf(v - bf2f(hi));
      }
      for (int e = tid; e < 4096; e += 256){
        int g = e >> 6, f = e & 63;
        float v = sW2[f*64 + g];
        u16 hi = f2bf(v); w2seh[e] = hi; w2sel[e] = f2bf(v - bf2f(hi));
      }
    } else if (bid == 2051){
      for (int e = tid; e < 176*64; e += 256){
        int n = e >> 6, k = e & 63;
        float v = (n < 168) ? fW1[k*168 + n] : 0.f;
        u16 hi = f2bf(v); w1frh[e] = hi; w1frl[e] = f2bf(v - bf2f(hi));
      }
      for (int e = tid; e < 16*192; e += 256){
        int c = e / 192, k = e % 192;
        float v = (c < 8 && k < 168) ? fW2[k*168 + 160 + c] : 0.f;
        u16 hi = f2bf(v); w2frh[e] = hi; w2frl[e] = f2bf(v - bf2f(hi));
      }
    } else {
      int idx = (bid - 2052)*256 + tid;
      int k = idx % 768;
      float v = (k < 752) ? tW[(size_t)(idx/768)*752 + k] : 0.f;
      wteB[idx] = f2bf(v);
    }
    return;
  }
  if (bid < 7044){
    int r = bid - 2628;
    int b = r / 138; int rem = r - b*138;
    int t0 = (rem / 23)*32, n0 = (rem % 23)*32;
    int tx = tid & 31, ty = tid >> 5;
    for (int i = ty; i < 32; i += 8){
      int n = n0 + i, t = t0 + tx;
      if (n < N_ && t < T_) tile[i][tx] = x[((size_t)b*N_ + n)*T_ + t];
    }
    __syncthreads();
    for (int i = ty; i < 32; i += 8){
      int t = t0 + i, n = n0 + tx;
      if (t < T_ && n < N_)
        teB[((size_t)b*T_ + t)*768 + n] = f2bf(tile[tx][i]);
    }
    return;
  }
  {
    int idx = (bid - 7044)*256 + tid;
    if (idx >= B_*T_*52) return;
    int c = idx % 52; int row = idx / 52; int b = row / T_, t = row % T_;
    float v = 0.f;
    if (c < 4) v = mark[((size_t)b*T_ + t)*4 + c];
    else if (c < 36) v = te_emb[t*32 + (c - 4)];
    teB[(size_t)row*768 + 716 + c] = f2bf(v);
  }
}

// ---------------- se MFMA (standalone, round-12 verified): X[:, :716, :] ----------------
__global__ __launch_bounds__(256) void k_sem(const float* __restrict__ x, const float* __restrict__ se_emb,
    const u16* __restrict__ w1h, const u16* __restrict__ w1l,
    const u16* __restrict__ w2h, const u16* __restrict__ w2l,
    const float* __restrict__ b1, const float* __restrict__ b2, float* __restrict__ X){
  __shared__ u16 Sh[64*232], Sl[64*232];
  __shared__ u16 Tlh[64*72], Tll[64*72];
  int m0 = blockIdx.x*64;
  int tid = threadIdx.x, wv = tid >> 6, lane = tid & 63;
  for (int o = tid; o < 64*224; o += 256){
    int r = o / 224, k = o - (o/224)*224;
    int m = m0 + r; int b = m / N_, n = m - b*N_;
    float v = 0.f;
    if (k < 168) v = x[((size_t)b*N_ + n)*T_ + k];
    else if (k < 200) v = se_emb[n*32 + (k - 168)];
    u16 hi = f2bf(v);
    Sh[r*232 + k] = hi; Sl[r*232 + k] = f2bf(v - bf2f(hi));
  }
  __syncthreads();
  const u16* Ah = Sh + (16*wv + (lane & 15))*232 + (lane >> 4)*8;
  const u16* Al = Sl + (16*wv + (lane & 15))*232 + (lane >> 4)*8;
  const u16* Bh = w1h + (lane & 15)*224 + (lane >> 4)*8;
  const u16* Bl = w1l + (lane & 15)*224 + (lane >> 4)*8;
  f32x4 hh[4], hl[4], lh[4];
  #pragma unroll
  for (int q = 0; q < 4; ++q){ hh[q]=(f32x4){0,0,0,0}; hl[q]=(f32x4){0,0,0,0}; lh[q]=(f32x4){0,0,0,0}; }
  #pragma unroll
  for (int kt = 0; kt < 7; ++kt){
    short8 ah = *(const short8*)(Ah + kt*32);
    short8 al = *(const short8*)(Al + kt*32);
    #pragma unroll
    for (int q = 0; q < 4; ++q){
      short8 bh = *(const short8*)(Bh + q*16*224 + kt*32);
      short8 bl = *(const short8*)(Bl + q*16*224 + kt*32);
      hh[q] = bmfma(ah, bh, hh[q]);
      hl[q] = bmfma(ah, bl, hl[q]);
      lh[q] = bmfma(al, bh, lh[q]);
    }
  }
  int mrow = 16*wv + (lane >> 4)*4;
  #pragma unroll
  for (int q = 0; q < 4; ++q){
    int g = q*16 + (lane & 15);
    float bv = b1[g];
    #pragma unroll
    for (int r = 0; r < 4; ++r){
      float v = eluf(hh[q][r] + hl[q][r] + lh[q][r] + bv);
      u16 hi = f2bf(v);
      Tlh[(mrow + r)*72 + g] = hi;
      Tll[(mrow + r)*72 + g] = f2bf(v - bf2f(hi));
    }
  }
  __syncthreads();
  const u16* A2h = Tlh + (16*wv + (lane & 15))*72 + (lane >> 4)*8;
  const u16* A2l = Tll + (16*wv + (lane & 15))*72 + (lane >> 4)*8;
  const u16* B2h = w2h + (lane & 15)*64 + (lane >> 4)*8;
  const u16* B2l = w2l + (lane & 15)*64 + (lane >> 4)*8;
  f32x4 ohh[4], ohl[4], olh[4];
  #pragma unroll
  for (int q = 0; q < 4; ++q){ ohh[q]=(f32x4){0,0,0,0}; ohl[q]=(f32x4){0,0,0,0}; olh[q]=(f32x4){0,0,0,0}; }
  #pragma unroll
  for (int kt = 0; kt < 2; ++kt){
    short8 a2h = *(const short8*)(A2h + kt*32);
    short8 a2l = *(const short8*)(A2l + kt*32);
    #pragma unroll
    for (int q = 0; q < 4; ++q){
      short8 b2h = *(const short8*)(B2h + q*16*64 + kt*32);
      short8 b2l = *(const short8*)(B2l + q*16*64 + kt*32);
      ohh[q] = bmfma(a2h, b2h, ohh[q]);
      ohl[q] = bmfma(a2h, b2l, ohl[q]);
      olh[q] = bmfma(a2l, b2h, olh[q]);
    }
  }
  #pragma unroll
  for (int q = 0; q < 4; ++q){
    int g = q*16 + (lane & 15);
    float bv = b2[g];
    #pragma unroll
    for (int r = 0; r < 4; ++r){
      int m = m0 + mrow + r;
      int b = m / N_, n = m - b*N_;
      X[((size_t)b*NT_ + n)*L_ + g] = ohh[q][r] + ohl[q][r] + olh[q][r] + bv;
    }
  }
}

// ---------------- te xw MFMA (single bf16): te_xw = te_in @ te_Wih^T + bih ----------------
__global__ __launch_bounds__(256) void k_texw(const u16* __restrict__ teB, const u16* __restrict__ wteB,
    const float* __restrict__ bih, float* __restrict__ xwte){
  int m0 = blockIdx.x*64, n0 = blockIdx.y*64;
  int tid = threadIdx.x, wv = tid >> 6, lane = tid & 63;
  const u16* Ah = teB + (size_t)(m0 + 16*wv + (lane & 15))*768 + (lane >> 4)*8;
  const u16* Bh = wteB + (size_t)(n0 + (lane & 15))*768 + (lane >> 4)*8;
  f32x4 hh[4];
  #pragma unroll
  for (int q = 0; q < 4; ++q) hh[q]=(f32x4){0,0,0,0};
  #pragma unroll 4
  for (int kt = 0; kt < 24; ++kt){
    short8 ah = *(const short8*)(Ah + kt*32);
    #pragma unroll
    for (int q = 0; q < 4; ++q)
      hh[q] = bmfma(ah, *(const short8*)(Bh + q*16*768 + kt*32), hh[q]);
  }
  int mb = m0 + 16*wv + (lane >> 4)*4;
  #pragma unroll
  for (int q = 0; q < 4; ++q){
    int g = n0 + q*16 + (lane & 15);
    float bv = bih[g];
    #pragma unroll
    for (int r = 0; r < 4; ++r)
      xwte[(size_t)(mb + r)*TE3_ + g] = hh[q][r] + bv;
  }
}

// ---------------- te GRU scan (ILP-split inner product) ----------------
__global__ __launch_bounds__(192) void k_te_scan(const float* __restrict__ xw, const float* __restrict__ Whh,
                 const float* __restrict__ bhh, float* __restrict__ X){
  int b = blockIdx.x; int tid = threadIdx.x;
  __shared__ float Wsh[TE3_*65];
  __shared__ float hs[64];
  __shared__ float gh[TE3_];
  for (int l = tid; l < TE3_*64; l += 192){ int j = l >> 6, f = l & 63; Wsh[j*65+f] = Whh[l]; }
  if (tid < 64) hs[tid] = 0.f;
  __syncthreads();
  for (int t = 0; t < T_; ++t){
    const float* xr = xw + ((size_t)b*T_ + t)*TE3_;
    float g0 = bhh[tid], g1 = 0.f, g2 = 0.f, g3 = 0.f;
    #pragma unroll
    for (int f = 0; f < 64; f += 4){
      g0 = fmaf(hs[f],   Wsh[tid*65+f],   g0);
      g1 = fmaf(hs[f+1], Wsh[tid*65+f+1], g1);
      g2 = fmaf(hs[f+2], Wsh[tid*65+f+2], g2);
      g3 = fmaf(hs[f+3], Wsh[tid*65+f+3], g3);
    }
    gh[tid] = (g0 + g1) + (g2 + g3);
    __syncthreads();
    if (tid < 64){
      float r = sigf(xr[tid] + gh[tid]);
      float z = sigf(xr[64+tid] + gh[64+tid]);
      float n = tanhf(xr[128+tid] + r*gh[128+tid]);
      float hn = (1.f - z)*n + z*hs[tid];
      hs[tid] = hn;
      X[((size_t)b*NT_ + N_ + t)*L_ + tid] = hn;
    }
    __syncthreads();
  }
}

// ---------------- X -> bf16 hi/lo (row-major + transposed) ----------------
__global__ __launch_bounds__(256) void k_xbf(const float* __restrict__ X,
                 u16* __restrict__ Xbh, u16* __restrict__ Xbl,
                 u16* __restrict__ XTh, u16* __restrict__ XTl){
  __shared__ u16 th[32][33], tl[32][33];
  int b = blockIdx.z, i0 = blockIdx.x*32, f0 = blockIdx.y*32;
  int tx = threadIdx.x & 31, ty = threadIdx.x >> 5;
  for (int rr = ty; rr < 32; rr += 8){
    int i = i0 + rr, f = f0 + tx;
    float v = (i < NT_) ? X[((size_t)b*NT_ + i)*L_ + f] : 0.f;
    u16 hi = f2bf(v);
    u16 lo = f2bf(v - bf2f(hi));
    th[rr][tx] = hi; tl[rr][tx] = lo;
    Xbh[((size_t)b*NTP + i)*L_ + f] = hi;
    Xbl[((size_t)b*NTP + i)*L_ + f] = lo;
  }
  __syncthreads();
  for (int rr = ty; rr < 32; rr += 8){
    XTh[((size_t)b*L_ + f0 + rr)*NTP + i0 + tx] = th[tx][rr];
    XTl[((size_t)b*L_ + f0 + rr)*NTP + i0 + tx] = tl[tx][rr];
  }
}

// ---------------- fused flash-GCN layer: Y = elu((adj@h)@W + b), adj computed in LDS ----------------
// XRh/XRl (optional) MUST NOT alias Xbh/Xbl (blocks read all rows of Xb).
__global__ __launch_bounds__(256) void k_gcnf(
    const u16* __restrict__ Xbh, const u16* __restrict__ Xbl,
    const u16* __restrict__ hTh, const u16* __restrict__ hTl,
    const u16* __restrict__ WTh, const u16* __restrict__ WTl,
    const float* __restrict__ bias,
    float* __restrict__ Y, u16* __restrict__ YTh, u16* __restrict__ YTl,
    u16* __restrict__ XRh, u16* __restrict__ XRl){
  __shared__ u16 AJh[64*72], AJl[64*72];
  __shared__ u16 Tlh[64*72], Tll[64*72];
  int b = blockIdx.y, i0 = blockIdx.x*64;
  int tid = threadIdx.x, wv = tid >> 6, lane = tid & 63;
  const u16* XAh = Xbh + ((size_t)b*NTP + i0 + 16*wv + (lane & 15))*L_ + (lane >> 4)*8;
  const u16* XAl = Xbl + ((size_t)b*NTP + i0 + 16*wv + (lane & 15))*L_ + (lane >> 4)*8;
  const int ib = i0 + 16*wv + (lane >> 4)*4;
  const int mrow = 16*wv + (lane >> 4)*4;
  f32x4 thh[4], thl[4], tlh[4];
  #pragma unroll
  for (int q = 0; q < 4; ++q){ thh[q] = (f32x4){0,0,0,0}; thl[q] = (f32x4){0,0,0,0}; tlh[q] = (f32x4){0,0,0,0}; }
  for (int jt = 0; jt < 14; ++jt){
    int j0 = jt*64;
    {
      const u16* XBh = Xbh + ((size_t)b*NTP + j0 + (lane & 15))*L_ + (lane >> 4)*8;
      const u16* XBl = Xbl + ((size_t)b*NTP + j0 + (lane & 15))*L_ + (lane >> 4)*8;
      f32x4 chh[4], chl[4], clh[4];
      #pragma unroll
      for (int q = 0; q < 4; ++q){ chh[q] = (f32x4){0,0,0,0}; chl[q] = (f32x4){0,0,0,0}; clh[q] = (f32x4){0,0,0,0}; }
      #pragma unroll
      for (int kt = 0; kt < 2; ++kt){
        short8 ah = *(const short8*)(XAh + kt*32);
        short8 al = *(const short8*)(XAl + kt*32);
        #pragma unroll
        for (int q = 0; q < 4; ++q){
          short8 bh = *(const short8*)(XBh + q*16*L_ + kt*32);
          short8 bl = *(const short8*)(XBl + q*16*L_ + kt*32);
          chh[q] = bmfma(ah, bh, chh[q]);
          chl[q] = bmfma(ah, bl, chl[q]);
          clh[q] = bmfma(al, bh, clh[q]);
        }
      }
      int jb = j0 + (lane & 15);
      #pragma unroll
      for (int q = 0; q < 4; ++q){
        int j = jb + q*16;
        #pragma unroll
        for (int r = 0; r < 4; ++r){
          int i = ib + r;
          u16 hi = 0, lo = 0;
          if (i < NT_ && j < NT_){
            float v = tanhf(fmaxf(chh[q][r] + chl[q][r] + clh[q][r], 0.f) + (i == j ? 1.f : 0.f));
            hi = f2bf(v); lo = f2bf(v - bf2f(hi));
          }
          AJh[(mrow + r)*72 + q*16 + (lane & 15)] = hi;
          AJl[(mrow + r)*72 + q*16 + (lane & 15)] = lo;
        }
      }
    }
    __syncthreads();
    {
      const u16* A1h = AJh + (16*wv + (lane & 15))*72 + (lane >> 4)*8;
      const u16* A1l = AJl + (16*wv + (lane & 15))*72 + (lane >> 4)*8;
      const u16* B1h = hTh + ((size_t)b*L_ + (lane & 15))*NTP + j0 + (lane >> 4)*8;
      const u16* B1l = hTl + ((size_t)b*L_ + (lane & 15))*NTP + j0 + (lane >> 4)*8;
      #pragma unroll
      for (int kt = 0; kt < 2; ++kt){
        short8 ah = *(const short8*)(A1h + kt*32);
        short8 al = *(const short8*)(A1l + kt*32);
        #pragma unroll
        for (int q = 0; q < 4; ++q){
          short8 bh = *(const short8*)(B1h + q*16*NTP + kt*32);
          short8 bl = *(const short8*)(B1l + q*16*NTP + kt*32);
          thh[q] = bmfma(ah, bh, thh[q]);
          thl[q] = bmfma(ah, bl, thl[q]);
          tlh[q] = bmfma(al, bh, tlh[q]);
        }
      }
    }
    __syncthreads();
  }
  #pragma unroll
  for (int q = 0; q < 4; ++q)
    #pragma unroll
    for (int r = 0; r < 4; ++r){
      float v = thh[q][r] + thl[q][r] + tlh[q][r];
      u16 hi = f2bf(v);
      Tlh[(mrow + r)*72 + q*16 + (lane & 15)] = hi;
      Tll[(mrow + r)*72 + q*16 + (lane & 15)] = f2bf(v - bf2f(hi));
    }
  __syncthreads();
  const u16* A2h = Tlh + (16*wv + (lane & 15))*72 + (lane >> 4)*8;
  const u16* A2l = Tll + (16*wv + (lane & 15))*72 + (lane >> 4)*8;
  const u16* B2h = WTh + (lane & 15)*L_ + (lane >> 4)*8;
  const u16* B2l = WTl + (lane & 15)*L_ + (lane >> 4)*8;
  f32x4 ohh[4], ohl[4], olh[4];
  #pragma unroll
  for (int q = 0; q < 4; ++q){ ohh[q] = (f32x4){0,0,0,0}; ohl[q] = (f32x4){0,0,0,0}; olh[q] = (f32x4){0,0,0,0}; }
  #pragma unroll
  for (int kt = 0; kt < 2; ++kt){
    short8 a2h = *(const short8*)(A2h + kt*32);
    short8 a2l = *(const short8*)(A2l + kt*32);
    #pragma unroll
    for (int q = 0; q < 4; ++q){
      short8 b2h = *(const short8*)(B2h + q*16*L_ + kt*32);
      short8 b2l = *(const short8*)(B2l + q*16*L_ + kt*32);
      ohh[q] = bmfma(a2h, b2h, ohh[q]);
      ohl[q] = bmfma(a2h, b2l, ohl[q]);
      olh[q] = bmfma(a2l, b2h, olh[q]);
    }
  }
  __syncthreads();
  #pragma unroll
  for (int q = 0; q < 4; ++q){
    int g = q*16 + (lane & 15);
    float bv = bias[g];
    #pragma unroll
    for (int r = 0; r < 4; ++r){
      int i = i0 + mrow + r;
      float v = eluf(ohh[q][r] + ohl[q][r] + olh[q][r] + bv);
      if (i < NT_ && Y) Y[((size_t)b*NT_ + i)*L_ + g] = v;
      u16 hi = 0, lo = 0;
      if (i < NT_){ hi = f2bf(v); lo = f2bf(v - bf2f(hi)); }
      Tlh[g*72 + mrow + r] = hi;
      Tll[g*72 + mrow + r] = lo;
    }
  }
  __syncthreads();
  {
    int g = tid >> 2, c = tid & 3;
    uint4* dh = (uint4*)(YTh + ((size_t)b*L_ + g)*NTP + i0 + c*16);
    uint4* dl = (uint4*)(YTl + ((size_t)b*L_ + g)*NTP + i0 + c*16);
    const uint4* sh = (const uint4*)(Tlh + g*72 + c*16);
    const uint4* sl = (const uint4*)(Tll + g*72 + c*16);
    dh[0] = sh[0]; dh[1] = sh[1];
    dl[0] = sl[0]; dl[1] = sl[1];
  }
  if (XRh){
    int m = tid >> 2, c = tid & 3;
    u16 vh[16], vl[16];
    #pragma unroll
    for (int g = 0; g < 16; ++g){
      vh[g] = Tlh[(c*16 + g)*72 + m];
      vl[g] = Tll[(c*16 + g)*72 + m];
    }
    uint4* dh = (uint4*)(XRh + ((size_t)b*NTP + i0 + m)*L_ + c*16);
    uint4* dl = (uint4*)(XRl + ((size_t)b*NTP + i0 + m)*L_ + c*16);
    dh[0] = ((uint4*)vh)[0]; dh[1] = ((uint4*)vh)[1];
    dl[0] = ((uint4*)vl)[0]; dl[1] = ((uint4*)vl)[1];
  }
}

// ---------------- merged back-end: blocks [0,358) fr path; [358,3214) xw projection ----------------
__global__ __launch_bounds__(256) void k_back(const float* __restrict__ X,
    const u16* __restrict__ w1h, const u16* __restrict__ w1l,
    const u16* __restrict__ w2h, const u16* __restrict__ w2l,
    const float* __restrict__ b1, const float* __restrict__ b2, float* __restrict__ nout8,
    const u16* __restrict__ WihB, const float* __restrict__ bih, u16* __restrict__ xwB){
  __shared__ u16 Sh[64*72], Sl[64*72];
  __shared__ u16 T1h[64*192], T1l[64*192];
  __shared__ u16 B2hl[16*192], B2ll[16*192];
  int tid = threadIdx.x, wv = tid >> 6, lane = tid & 63;
  if (blockIdx.x >= 358){
    int r = blockIdx.x - 358;
    int m0 = (r % 84)*64, n0 = (r / 84)*64;
    int am = m0 + 16*wv + (lane & 15);
    int t = am >> 5, b = am & 31;
    const float* Arow = X + ((size_t)b*NT_ + N_ + t)*L_ + (lane >> 4)*8;
    const u16* Bb = WihB + (size_t)(n0 + (lane & 15))*L_ + (lane >> 4)*8;
    f32x4 c0={0,0,0,0}, c1={0,0,0,0}, c2={0,0,0,0}, c3={0,0,0,0};
    #pragma unroll
    for (int kt = 0; kt < 2; ++kt){
      f32x4 f0 = *(const f32x4*)(Arow + kt*32);
      f32x4 f1 = *(const f32x4*)(Arow + kt*32 + 4);
      short8 a;
      a[0]=(short)f2bf(f0[0]); a[1]=(short)f2bf(f0[1]); a[2]=(short)f2bf(f0[2]); a[3]=(short)f2bf(f0[3]);
      a[4]=(short)f2bf(f1[0]); a[5]=(short)f2bf(f1[1]); a[6]=(short)f2bf(f1[2]); a[7]=(short)f2bf(f1[3]);
      c0 = bmfma(a, *(const short8*)(Bb + kt*32), c0);
      c1 = bmfma(a, *(const short8*)(Bb + 16*L_ + kt*32), c1);
      c2 = bmfma(a, *(const short8*)(Bb + 32*L_ + kt*32), c2);
      c3 = bmfma(a, *(const short8*)(Bb + 48*L_ + kt*32), c3);
    }
    int mb = m0 + 16*wv + (lane >> 4)*4;
    int nb = n0 + (lane & 15);
    f32x4 cc[4] = {c0, c1, c2, c3};
    #pragma unroll
    for (int q = 0; q < 4; ++q){
      int n = nb + q*16;
      if (n >= TR3_) continue;
      float bv = bih[n];
      #pragma unroll
      for (int rr = 0; rr < 4; ++rr)
        xwB[(size_t)(mb + rr)*TR3_ + n] = f2bf(cc[q][rr] + bv);
    }
    return;
  }
  int m0 = blockIdx.x*64;
  for (int o = tid; o < 768; o += 256){
    ((u64*)B2hl)[o] = ((const u64*)w2h)[o];
    ((u64*)B2ll)[o] = ((const u64*)w2l)[o];
  }
  for (int o = tid; o < 1024; o += 256){
    int rr = o >> 4, cc = o & 15;
    T1h[rr*192 + 176 + cc] = 0; T1l[rr*192 + 176 + cc] = 0;
  }
  for (int o = tid; o < 4096; o += 256){
    int r = o >> 6, k = o & 63;
    int m = m0 + r; int ab = m / N_, an = m - ab*N_;
    float v = X[((size_t)ab*NT_ + an)*L_ + k];
    u16 hi = f2bf(v);
    Sh[r*72 + k] = hi; Sl[r*72 + k] = f2bf(v - bf2f(hi));
  }
  __syncthreads();
  const u16* Ah = Sh + (16*wv + (lane & 15))*72 + (lane >> 4)*8;
  const u16* Al = Sl + (16*wv + (lane & 15))*72 + (lane >> 4)*8;
  int mrow = 16*wv + (lane >> 4)*4;
  for (int tile = 0; tile < 11; ++tile){
    const u16* Bh = w1h + (tile*16 + (lane & 15))*64 + (lane >> 4)*8;
    const u16* Bl = w1l + (tile*16 + (lane & 15))*64 + (lane >> 4)*8;
    f32x4 shh={0,0,0,0}, shl={0,0,0,0}, slh={0,0,0,0};
    #pragma unroll
    for (int kt = 0; kt < 2; ++kt){
      short8 ah = *(const short8*)(Ah + kt*32);
      short8 al = *(const short8*)(Al + kt*32);
      short8 bh = *(const short8*)(Bh + kt*32);
      short8 bl = *(const short8*)(Bl + kt*32);
      shh = bmfma(ah, bh, shh);
      shl = bmfma(ah, bl, shl);
      slh = bmfma(al, bh, slh);
    }
    int col = tile*16 + (lane & 15);
    float bb = (col < 168) ? b1[col] : 0.f;
    #pragma unroll
    for (int r = 0; r < 4; ++r){
      float v = (col < 168) ? eluf(shh[r] + shl[r] + slh[r] + bb) : 0.f;
      u16 hi = f2bf(v);
      T1h[(mrow + r)*192 + col] = hi;
      T1l[(mrow + r)*192 + col] = f2bf(v - bf2f(hi));
    }
  }
  __syncthreads();
  const u16* A2h = T1h + (16*wv + (lane & 15))*192 + (lane >> 4)*8;
  const u16* A2l = T1l + (16*wv + (lane & 15))*192 + (lane >> 4)*8;
  const u16* Bh2 = B2hl + (lane & 15)*192 + (lane >> 4)*8;
  const u16* Bl2 = B2ll + (lane & 15)*192 + (lane >> 4)*8;
  f32x4 ohh={0,0,0,0}, ohl={0,0,0,0}, olh={0,0,0,0};
  #pragma unroll
  for (int kt = 0; kt < 6; ++kt){
    short8 a2h = *(const short8*)(A2h + kt*32);
    short8 a2l = *(const short8*)(A2l + kt*32);
    short8 b2h = *(const short8*)(Bh2 + kt*32);
    short8 b2l = *(const short8*)(Bl2 + kt*32);
    ohh = bmfma(a2h, b2h, ohh);
    ohl = bmfma(a2h, b2l, ohl);
    olh = bmfma(a2l, b2h, olh);
  }
  int c = lane & 15;
  if (c < 8){
    float bv = b2[160 + c];
    #pragma unroll
    for (int r = 0; r < 4; ++r){
      int m = m0 + mrow + r;
      nout8[(size_t)m*8 + c] = ohh[r] + ohl[r] + olh[r] + bv;
    }
  }
}

// ---------------- persistent MFMA tr-GRU scan (bf16 xw, entry-top poll) ----------------
__global__ __launch_bounds__(192) void k_tr_scan(
    const u16* __restrict__ WhhB,
    const float* __restrict__ bhh,
    const u16* __restrict__ xwB,
    u16* __restrict__ hb0, u16* __restrict__ hb1,
    float* __restrict__ tout8,
    int* __restrict__ flags){
  __shared__ u16 w_lds[48*WSTR];
  __shared__ u16 h_lds[16*WSTR];
  __shared__ float g_lds[2*256];
  __shared__ u64 xw_ldsq[2][192];
  const int tid = threadIdx.x;
  const int wv = tid >> 6, lane = tid & 63;
  const int cb = blockIdx.x >> 1, hhalf = blockIdx.x & 1;
  const int k0 = cb*16, b0 = hhalf*16;
  const int prow = tid / 12, pc = tid % 12;
  const int pg = pc >> 2, pko = (pc & 3)*4;

  xw_ldsq[0][prow*12 + pc] =
    *(const u64*)(xwB + (size_t)(b0 + prow)*TR3_ + pg*TRH_ + k0 + pko);
  for (int o = tid; o < 16*24; o += 192){
    int n = o / 24, c = o - n*24;
    h_lds[n*WSTR + 720 + c] = 0;
  }
  for (int r = 0; r < 48; ++r){
    int g = r >> 4, m = r & 15, k = k0 + m;
    bool kv = (k < TRH_);
    const uint2* src = (const uint2*)(WhhB + (size_t)(g*TRH_ + (kv ? k : 0))*TRH_);
    uint2* dst = (uint2*)(w_lds + r*WSTR);
    uint2 zz; zz.x = 0; zz.y = 0;
    for (int o = tid; o < 186; o += 192)
      dst[o] = (kv && o < 179) ? src[o] : zz;
  }
  const u16* arow = w_lds + (size_t)(wv*16 + (lane & 15))*WSTR + (lane >> 4)*8;
  const u16* brow = h_lds + (size_t)(lane & 15)*WSTR + (lane >> 4)*8;

  const int mb = (lane >> 4)*4;
  const int kx = k0 + mb;
  const bool kval = (kx < TRH_);
  const int bx = b0 + (lane & 15);
  f32x4 hp = {0.f, 0.f, 0.f, 0.f};
  f32x4 br4 = {0,0,0,0}, bz4 = {0,0,0,0}, bn4 = {0,0,0,0};
  if (wv == 0){
    int kc = kval ? kx : 0;
    br4 = *(const f32x4*)(bhh + kc);
    bz4 = *(const f32x4*)(bhh + TRH_ + kc);
    bn4 = *(const f32x4*)(bhh + 2*TRH_ + kc);
  }
  const int sn = tid / 12, sj = tid % 12;
  __syncthreads();

  for (int t = 0; t < T_; ++t){
    const u16* hcur = (t & 1) ? hb1 : hb0;
    u16* hnxt = (t & 1) ? hb0 : hb1;
    if (tid < 45){
      const int* fp = flags + (tid*2 + hhalf)*16;
      while (__hip_atomic_load(fp, __ATOMIC_RELAXED, __HIP_MEMORY_SCOPE_AGENT) < t){}
    }
    __syncthreads();
    {
      const u64* srow = (const u64*)(hcur + (size_t)(b0 + sn)*HSTR) + sj;
      u64 v0  = __hip_atomic_load(srow +   0, __ATOMIC_RELAXED, __HIP_MEMORY_SCOPE_AGENT);
      u64 v1  = __hip_atomic_load(srow +  12, __ATOMIC_RELAXED, __HIP_MEMORY_SCOPE_AGENT);
      u64 v2  = __hip_atomic_load(srow +  24, __ATOMIC_RELAXED, __HIP_MEMORY_SCOPE_AGENT);
      u64 v3  = __hip_atomic_load(srow +  36, __ATOMIC_RELAXED, __HIP_MEMORY_SCOPE_AGENT);
      u64 v4  = __hip_atomic_load(srow +  48, __ATOMIC_RELAXED, __HIP_MEMORY_SCOPE_AGENT);
      u64 v5  = __hip_atomic_load(srow +  60, __ATOMIC_RELAXED, __HIP_MEMORY_SCOPE_AGENT);
      u64 v6  = __hip_atomic_load(srow +  72, __ATOMIC_RELAXED, __HIP_MEMORY_SCOPE_AGENT);
      u64 v7  = __hip_atomic_load(srow +  84, __ATOMIC_RELAXED, __HIP_MEMORY_SCOPE_AGENT);
      u64 v8  = __hip_atomic_load(srow +  96, __ATOMIC_RELAXED, __HIP_MEMORY_SCOPE_AGENT);
      u64 v9  = __hip_atomic_load(srow + 108, __ATOMIC_RELAXED, __HIP_MEMORY_SCOPE_AGENT);
      u64 v10 = __hip_atomic_load(srow + 120, __ATOMIC_RELAXED, __HIP_MEMORY_SCOPE_AGENT);
      u64 v11 = __hip_atomic_load(srow + 132, __ATOMIC_RELAXED, __HIP_MEMORY_SCOPE_AGENT);
      u64 v12 = __hip_atomic_load(srow + 144, __ATOMIC_RELAXED, __HIP_MEMORY_SCOPE_AGENT);
      u64 v13 = __hip_atomic_load(srow + 156, __ATOMIC_RELAXED, __HIP_MEMORY_SCOPE_AGENT);
      u64 v14 = __hip_atomic_load(srow + 168, __ATOMIC_RELAXED, __HIP_MEMORY_SCOPE_AGENT);
      u64* d = (u64*)(h_lds + sn*WSTR) + sj;
      d[0]   = v0;   d[12]  = v1;   d[24]  = v2;   d[36]  = v3;
      d[48]  = v4;   d[60]  = v5;   d[72]  = v6;   d[84]  = v7;
      d[96]  = v8;   d[108] = v9;   d[120] = v10;  d[132] = v11;
      d[144] = v12;  d[156] = v13;  d[168] = v14;
    }
    __syncthreads();
    u64 pf = 0;
    const bool haspf = (t + 1 < T_);
    if (haspf)
      pf = *(const u64*)(xwB + (size_t)((t+1)*32 + b0 + prow)*TR3_ + pg*TRH_ + k0 + pko);
    f32x4 a0={0,0,0,0}, a1={0,0,0,0}, a2={0,0,0,0}, a3={0,0,0,0};
    for (int kt = 0; kt < 20; kt += 4){
      a0 = bmfma(*(const short8*)(arow + kt*32),     *(const short8*)(brow + kt*32),     a0);
      a1 = bmfma(*(const short8*)(arow + (kt+1)*32), *(const short8*)(brow + (kt+1)*32), a1);
      a2 = bmfma(*(const short8*)(arow + (kt+2)*32), *(const short8*)(brow + (kt+2)*32), a2);
      a3 = bmfma(*(const short8*)(arow + (kt+3)*32), *(const short8*)(brow + (kt+3)*32), a3);
    }
    a0 = bmfma(*(const short8*)(arow + 20*32), *(const short8*)(brow + 20*32), a0);
    a1 = bmfma(*(const short8*)(arow + 21*32), *(const short8*)(brow + 21*32), a1);
    a2 = bmfma(*(const short8*)(arow + 22*32), *(const short8*)(brow + 22*32), a2);
    f32x4 acc = (a0 + a1) + (a2 + a3);
    if (wv){
      #pragma unroll
      for (int r = 0; r < 4; ++r) g_lds[(wv-1)*256 + lane*4 + r] = acc[r];
    }
    __syncthreads();
    if (wv == 0){
      if (kval){
        const u16* xb = ((const u16*)&xw_ldsq[t & 1][0]) + (lane & 15)*48;
        float hnew[4];
        #pragma unroll
        for (int r = 0; r < 4; ++r){
          float rg = sigf(bf2f(xb[mb + r]) + acc[r] + br4[r]);
          float zg = sigf(bf2f(xb[16 + mb + r]) + g_lds[lane*4 + r] + bz4[r]);
          float ng = tanhf(bf2f(xb[32 + mb + r]) + rg*(g_lds[256 + lane*4 + r] + bn4[r]));
          hnew[r] = (1.f - zg)*ng + zg*hp[r];
          hp[r] = hnew[r];
        }
        u64 pk = (u64)((unsigned)f2bf(hnew[0]) | ((unsigned)f2bf(hnew[1]) << 16))
               | ((u64)((unsigned)f2bf(hnew[2]) | ((unsigned)f2bf(hnew[3]) << 16)) << 32);
        __hip_atomic_store((u64*)(hnxt + (size_t)bx*HSTR + kx), pk,
                           __ATOMIC_RELAXED, __HIP_MEMORY_SCOPE_AGENT);
        if (t >= 160){
          #pragma unroll
          for (int r = 0; r < 4; ++r)
            tout8[(size_t)(bx*TRH_ + kx + r)*8 + (t - 160)] = hnew[r];
        }
      }
      asm volatile("s_waitcnt vmcnt(0)" ::: "memory");
      if (lane == 0)
        __hip_atomic_store(flags + blockIdx.x*16, t + 1,
                           __ATOMIC_RELAXED, __HIP_MEMORY_SCOPE_AGENT);
    }
    if (haspf) xw_ldsq[(t + 1) & 1][prow*12 + pc] = pf;
  }
}

// ---------------- fused TCN tail ----------------
__global__ __launch_bounds__(256) void k_tcn(const float* __restrict__ nout8, const float* __restrict__ tout8,
                 const float* __restrict__ x,
                 const float* __restrict__ W0, const float* __restrict__ b0,
                 const float* __restrict__ W1, const float* __restrict__ b1,
                 const float* __restrict__ W2, const float* __restrict__ b2,
                 const float* __restrict__ oW, const float* __restrict__ ob,
                 float* __restrict__ out){
  __shared__ float w0s[96], b0s[16], w1s[512], b1s[16], w2s[512], b2s[16], ows[16], obs;
  int tid = threadIdx.x;
  for (int l = tid; l < 96; l += 256) w0s[l] = W0[l];
  for (int l = tid; l < 512; l += 256){ w1s[l] = W1[l]; w2s[l] = W2[l]; }
  if (tid < 16){ b0s[tid]=b0[tid]; b1s[tid]=b1[tid]; b2s[tid]=b2[tid]; ows[tid]=oW[tid]; }
  if (tid == 0) obs = ob[0];
  __syncthreads();
  int idx = blockIdx.x*256 + tid;
  if (idx >= B_*N_) return;
  int b = idx / N_, n = idx % N_;
  float s0[8], s1[8], s2[8];
  #pragma unroll
  for (int i = 0; i < 8; ++i){
    s0[i] = nout8[(size_t)idx*8 + i];
    s1[i] = tout8[(size_t)idx*8 + i];
    s2[i] = x[((size_t)b*N_ + n)*T_ + 160 + i];
  }
  float h1[16][4];
  #pragma unroll
  for (int c = 0; c < 16; ++c)
    #pragma unroll
    for (int q = 0; q < 4; ++q){
      int tt = 2*q + 1;
      float v = b0s[c]
        + w0s[c*6+0]*s0[tt-1] + w0s[c*6+1]*s0[tt]
        + w0s[c*6+2]*s1[tt-1] + w0s[c*6+3]*s1[tt]
        + w0s[c*6+4]*s2[tt-1] + w0s[c*6+5]*s2[tt];
      h1[c][q] = eluf(v);
    }
  float h2[16][2];
  #pragma unroll
  for (int c = 0; c < 16; ++c){
    float v3 = b1s[c], v7 = b1s[c];
    #pragma unroll
    for (int i2 = 0; i2 < 16; ++i2){
      v3 += w1s[c*32+i2*2]*h1[i2][0] + w1s[c*32+i2*2+1]*h1[i2][1];
      v7 += w1s[c*32+i2*2]*h1[i2][2] + w1s[c*32+i2*2+1]*h1[i2][3];
    }
    h2[c][0] = eluf(v3); h2[c][1] = eluf(v7);
  }
  float o = obs;
  #pragma unroll
  for (int c = 0; c < 16; ++c){
    float v = b2s[c];
    #pragma unroll
    for (int i2 = 0; i2 < 16; ++i2)
      v += w2s[c*32+i2*2]*h2[i2][0] + w2s[c*32+i2*2+1]*h2[i2][1];
    o += ows[c]*eluf(v);
  }
  out[idx] = o;
}

extern "C" void kernel_launch(void* const* d_in, const int* in_sizes, int n_in,
                              void* d_out, int out_size, void* d_ws, size_t ws_size,
                              hipStream_t stream){
  const float* x       = (const float*)d_in[0];
  const float* mark    = (const float*)d_in[1];
  const float* se_emb  = (const float*)d_in[2];
  const float* se_W1   = (const float*)d_in[3];
  const float* se_b1   = (const float*)d_in[4];
  const float* se_W2   = (const float*)d_in[5];
  const float* se_b2   = (const float*)d_in[6];
  const float* te_emb  = (const float*)d_in[7];
  const float* te_Wih  = (const float*)d_in[8];
  const float* te_Whh  = (const float*)d_in[9];
  const float* te_bih  = (const float*)d_in[10];
  const float* te_bhh  = (const float*)d_in[11];
  const float* gcn_W   = (const float*)d_in[12];
  const float* gcn_b   = (const float*)d_in[13];
  const float* fr_W1   = (const float*)d_in[14];
  const float* fr_b1   = (const float*)d_in[15];
  const float* fr_W2   = (const float*)d_in[16];
  const float* fr_b2   = (const float*)d_in[17];
  const float* tr_Wih  = (const float*)d_in[18];
  const float* tr_Whh  = (const float*)d_in[19];
  const float* tr_bih  = (const float*)d_in[20];
  const float* tr_bhh  = (const float*)d_in[21];
  const float* tcn_W0  = (const float*)d_in[22];
  const float* tcn_b0  = (const float*)d_in[23];
  const float* tcn_W1  = (const float*)d_in[24];
  const float* tcn_b1  = (const float*)d_in[25];
  const float* tcn_W2  = (const float*)d_in[26];
  const float* tcn_b2  = (const float*)d_in[27];
  const float* out_W   = (const float*)d_in[28];
  const float* out_b   = (const float*)d_in[29];
  float* out = (float*)d_out;
  (void)in_sizes; (void)n_in; (void)out_size; (void)ws_size;

  char* ws = (char*)d_ws;
  size_t off = 0;
  auto alloc = [&](size_t bytes)->void*{
    void* p = (void*)(ws + off); off += (bytes + 255) & ~(size_t)255; return p; };
  float* X       = (float*)alloc((size_t)B_*NT_*L_*4);
  u16*   teinB   = (u16*)  alloc((size_t)B_*T_*768*2);
  float* te_xw   = (float*)alloc((size_t)B_*T_*TE3_*4);
  u16*   xwB     = (u16*)  alloc((size_t)B_*T_*TR3_*2);
  u16*   WihB    = (u16*)  alloc((size_t)TR3P*L_*2);
  u16*   WhhB    = (u16*)  alloc((size_t)TR3_*TRH_*2);
  u16*   Xbh     = (u16*)  alloc((size_t)B_*NTP*L_*2);
  u16*   Xbl     = (u16*)  alloc((size_t)B_*NTP*L_*2);
  u16*   Xb2h    = (u16*)  alloc((size_t)B_*NTP*L_*2);
  u16*   Xb2l    = (u16*)  alloc((size_t)B_*NTP*L_*2);
  u16*   hTah    = (u16*)  alloc((size_t)B_*L_*NTP*2);
  u16*   hTal    = (u16*)  alloc((size_t)B_*L_*NTP*2);
  u16*   hTbh    = (u16*)  alloc((size_t)B_*L_*NTP*2);
  u16*   hTbl    = (u16*)  alloc((size_t)B_*L_*NTP*2);
  u16*   WTh     = (u16*)  alloc((size_t)4*4096*2);
  u16*   WTl     = (u16*)  alloc((size_t)4*4096*2);
  u16*   w1seh   = (u16*)  alloc((size_t)64*224*2);
  u16*   w1sel   = (u16*)  alloc((size_t)64*224*2);
  u16*   w2seh   = (u16*)  alloc((size_t)4096*2);
  u16*   w2sel   = (u16*)  alloc((size_t)4096*2);
  u16*   w1frh   = (u16*)  alloc((size_t)176*64*2);
  u16*   w1frl   = (u16*)  alloc((size_t)176*64*2);
  u16*   w2frh   = (u16*)  alloc((size_t)16*192*2);
  u16*   w2frl   = (u16*)  alloc((size_t)16*192*2);
  u16*   wteB    = (u16*)  alloc((size_t)192*768*2);
  u16*   hb0     = (u16*)  alloc((size_t)B_*HSTR*2);      // contiguous hb0|hb1|flags
  u16*   hb1     = (u16*)  alloc((size_t)B_*HSTR*2);
  int*   flags   = (int*)  alloc(8192);
  float* nout8   = (float*)alloc((size_t)B_*N_*8*4);
  float* tout8   = (float*)alloc((size_t)B_*N_*8*4);

  hipMemsetAsync(hb0, 0, (size_t)B_*HSTR*2*2 + 8192, stream);

  // front-end: weight prep + te_in build (no intra-launch dependencies)
  k_front<<<8136, 256, 0, stream>>>(x, mark, te_emb,
      tr_Whh, WhhB, tr_Wih, WihB,
      gcn_W, se_W1, se_W2, fr_W1, fr_W2, te_Wih,
      WTh, WTl, w1seh, w1sel, w2seh, w2sel, w1frh, w1frl, w2frh, w2frl, wteB, teinB);
  // se path (separate launch: consumes weights prepped above)
  k_sem<<<358, 256, 0, stream>>>(x, se_emb, w1seh, w1sel, w2seh, w2sel, se_b1, se_b2, X);
  // te path
  k_texw<<<dim3(84,3), 256, 0, stream>>>(teinB, wteB, te_bih, te_xw);
  k_te_scan<<<B_, 192, 0, stream>>>(te_xw, te_Whh, te_bhh, X);
  // GCN (flash-GCN; iteration-2 Xb comes from gcnf's XR output into a SEPARATE buffer)
  k_xbf<<<dim3(28,2,B_),256,0,stream>>>(X, Xbh, Xbl, hTah, hTal);
  k_gcnf<<<dim3(14,B_),256,0,stream>>>(Xbh, Xbl, hTah, hTal,
      WTh + 0*4096, WTl + 0*4096, gcn_b + 0*64, nullptr, hTbh, hTbl, nullptr, nullptr);
  k_gcnf<<<dim3(14,B_),256,0,stream>>>(Xbh, Xbl, hTbh, hTbl,
      WTh + 1*4096, WTl + 1*4096, gcn_b + 1*64, nullptr, hTah, hTal, Xb2h, Xb2l);
  k_gcnf<<<dim3(14,B_),256,0,stream>>>(Xb2h, Xb2l, hTah, hTal,
      WTh + 2*4096, WTl + 2*4096, gcn_b + 2*64, nullptr, hTbh, hTbl, nullptr, nullptr);
  k_gcnf<<<dim3(14,B_),256,0,stream>>>(Xb2h, Xb2l, hTbh, hTbl,
      WTh + 3*4096, WTl + 3*4096, gcn_b + 3*64, X, hTah, hTal, nullptr, nullptr);
  // merged back-end: fr path + tr input projection
  k_back<<<358 + 84*34, 256, 0, stream>>>(X, w1frh, w1frl, w2frh, w2frl, fr_b1, fr_b2, nout8,
      WihB, tr_bih, xwB);
  // persistent tr-GRU scan
  k_tr_scan<<<TRBLKS,192,0,stream>>>(WhhB, tr_bhh, xwB, hb0, hb1, tout8, flags);
  // fused TCN tail
  k_tcn<<<(B_*N_+255)/256,256,0,stream>>>(nout8, tout8, x,
      tcn_W0, tcn_b0, tcn_W1, tcn_b1, tcn_W2, tcn_b2, out_W, out_b, out);
}